// Round 4
// baseline (452.199 us; speedup 1.0000x reference)
//
#include <hip/hip_runtime.h>
#include <hip/hip_bf16.h>

#define V 10000
#define VP 10112
#define C 1024
#define S 128
#define H 256
#define B 16
#define T 128
#define NR 32      // sumexp replicas
#define LDK 40     // padded LDS row length (u16) for k_em

typedef unsigned short u16;
typedef unsigned int u32;
typedef __bf16 bf16x8 __attribute__((ext_vector_type(8)));
typedef float f32x4 __attribute__((ext_vector_type(4)));

static __device__ __forceinline__ float bf2f(u16 x){ return __uint_as_float(((u32)x)<<16); }
static __device__ __forceinline__ u16 f2bf(float f){ u32 u=__float_as_uint(f); return (u16)((u + 0x7FFFu + ((u>>16)&1u))>>16); }
static __device__ __forceinline__ u32 fenc(float f){ u32 b=__float_as_uint(f); return (b&0x80000000u)? ~b : (b|0x80000000u); }
static __device__ __forceinline__ float fdec(u32 e){ u32 b=(e&0x80000000u)? (e&0x7FFFFFFFu) : ~e; return __uint_as_float(b); }

// dot of two bf16 pairs (packed in u32) into f32 acc
static __device__ __forceinline__ float dot2bf(u32 m, u32 u, float acc){
#if __has_builtin(__builtin_amdgcn_fdot2_f32_bf16)
  typedef __bf16 b2v __attribute__((ext_vector_type(2)));
  union { u32 w; b2v v; } um, uu; um.w = m; uu.w = u;
  return __builtin_amdgcn_fdot2_f32_bf16(um.v, uu.v, acc, false);
#else
  acc = fmaf(__uint_as_float(m<<16), __uint_as_float(u<<16), acc);
  return fmaf(__uint_as_float(m & 0xFFFF0000u), __uint_as_float(u & 0xFFFF0000u), acc);
#endif
}

// ---------------- zero accumulators ----------------
__global__ void k_zero(float* __restrict__ sumexp, u32* __restrict__ wb, float* __restrict__ res){
  int i = threadIdx.x + blockIdx.x*blockDim.x;
  if (i < C*NR) sumexp[i] = 0.f;
  if (i < 2) wb[i] = 0u;
  if (i < B) res[i] = 0.f;
}

// ---------------- MLP: h2 = relu(relu(x@w1+b1)@w2+b2+x) ----------------
#define RPB 8
__global__ __launch_bounds__(256) void k_mlp(
    const float* __restrict__ x, const float* __restrict__ w1, const float* __restrict__ b1,
    const float* __restrict__ w2, const float* __restrict__ b2,
    float* __restrict__ out_f32, u16* __restrict__ out_bf16, float* __restrict__ rn2){
  __shared__ float xr[RPB][H];
  __shared__ float h1r[RPB][H];
  const int j = threadIdx.x;
  const int r0 = blockIdx.x * RPB;
  #pragma unroll
  for (int r=0;r<RPB;r++) xr[r][j] = x[(size_t)(r0+r)*H + j];
  __syncthreads();
  float acc[RPB];
  {
    float bj = b1[j];
    #pragma unroll
    for (int r=0;r<RPB;r++) acc[r]=bj;
    for (int k=0;k<H;k++){
      float w = w1[(size_t)k*H + j];
      #pragma unroll
      for (int r=0;r<RPB;r++) acc[r] = fmaf(xr[r][k], w, acc[r]);
    }
  }
  #pragma unroll
  for (int r=0;r<RPB;r++) h1r[r][j] = fmaxf(acc[r], 0.f);
  __syncthreads();
  {
    float bj = b2[j];
    #pragma unroll
    for (int r=0;r<RPB;r++) acc[r] = bj + xr[r][j];
    for (int k=0;k<H;k++){
      float w = w2[(size_t)k*H + j];
      #pragma unroll
      for (int r=0;r<RPB;r++) acc[r] = fmaf(h1r[r][k], w, acc[r]);
    }
  }
  #pragma unroll
  for (int r=0;r<RPB;r++){
    float h2 = fmaxf(acc[r], 0.f);
    if (out_f32)  out_f32 [(size_t)(r0+r)*H + j] = h2;
    if (out_bf16) out_bf16[(size_t)(r0+r)*H + j] = f2bf(h2);
    acc[r] = h2*h2;
  }
  if (rn2){
    __syncthreads();
    #pragma unroll
    for (int r=0;r<RPB;r++) xr[r][j] = acc[r];
    __syncthreads();
    for (int off=128; off>=1; off>>=1){
      if (j < off){
        #pragma unroll
        for (int r=0;r<RPB;r++) xr[r][j] += xr[r][j+off];
      }
      __syncthreads();
    }
    if (j==0){
      #pragma unroll
      for (int r=0;r<RPB;r++) rn2[r0+r] = xr[r][0];
    }
  }
}

// ---------------- start head + log_softmax over C ----------------
__global__ __launch_bounds__(1024) void k_start(
    const float* __restrict__ h2, const float* __restrict__ wo, const float* __restrict__ bo,
    float* __restrict__ start_lp){
  const int c = threadIdx.x;
  const int lane = c & 63, wid = c >> 6;
  __shared__ float red[16];
  __shared__ float Ms, Zs;
  float acc = bo[0];
  const float* row = h2 + (size_t)c*H;
  for (int k=0;k<H;k+=4){
    float4 hv = *(const float4*)(row+k);
    float4 wv = *(const float4*)(wo+k);
    acc = fmaf(hv.x,wv.x,acc); acc = fmaf(hv.y,wv.y,acc);
    acc = fmaf(hv.z,wv.z,acc); acc = fmaf(hv.w,wv.w,acc);
  }
  float m = acc;
  for (int o=1;o<64;o<<=1) m = fmaxf(m, __shfl_xor(m,o));
  if (lane==0) red[wid]=m;
  __syncthreads();
  if (c==0){ float t=red[0]; for(int i=1;i<16;i++) t=fmaxf(t,red[i]); Ms=t; }
  __syncthreads();
  float M = Ms;
  float e = expf(acc - M);
  float sum = e;
  for (int o=1;o<64;o<<=1) sum += __shfl_xor(sum,o);
  __syncthreads();
  if (lane==0) red[wid]=sum;
  __syncthreads();
  if (c==0){ float t=0.f; for(int i=0;i<16;i++) t+=red[i]; Zs=t; }
  __syncthreads();
  start_lp[c] = acc - (M + logf(Zs));
}

// ---------------- transition head + row softmax -> P (bf16 probs) ----------------
#define RC 8
__global__ __launch_bounds__(256) void k_trans(
    const float* __restrict__ h2, const float* __restrict__ wo, const float* __restrict__ bo,
    u16* __restrict__ P){
  __shared__ float xr[RC][H];
  __shared__ float red[4];
  __shared__ float Ms, Zs;
  const int j = threadIdx.x, lane = j&63, wid = j>>6;
  const int r0 = blockIdx.x*RC;
  #pragma unroll
  for (int r=0;r<RC;r++) xr[r][j] = h2[(size_t)(r0+r)*H + j];
  __syncthreads();
  float acc[4][RC];
  #pragma unroll
  for (int m=0;m<4;m++){
    float bv = bo[j + 256*m];
    #pragma unroll
    for (int r=0;r<RC;r++) acc[m][r]=bv;
  }
  for (int k=0;k<H;k++){
    float w0 = wo[(size_t)k*C + j];
    float w1v = wo[(size_t)k*C + j + 256];
    float w2v = wo[(size_t)k*C + j + 512];
    float w3v = wo[(size_t)k*C + j + 768];
    #pragma unroll
    for (int r=0;r<RC;r++){
      float xv = xr[r][k];
      acc[0][r]=fmaf(xv,w0 ,acc[0][r]);
      acc[1][r]=fmaf(xv,w1v,acc[1][r]);
      acc[2][r]=fmaf(xv,w2v,acc[2][r]);
      acc[3][r]=fmaf(xv,w3v,acc[3][r]);
    }
  }
  for (int r=0;r<RC;r++){
    float mx = fmaxf(fmaxf(acc[0][r],acc[1][r]), fmaxf(acc[2][r],acc[3][r]));
    for (int o=1;o<64;o<<=1) mx = fmaxf(mx, __shfl_xor(mx,o));
    if (lane==0) red[wid]=mx;
    __syncthreads();
    if (j==0) Ms = fmaxf(fmaxf(red[0],red[1]),fmaxf(red[2],red[3]));
    __syncthreads();
    float M = Ms;
    float e0=expf(acc[0][r]-M), e1=expf(acc[1][r]-M), e2=expf(acc[2][r]-M), e3=expf(acc[3][r]-M);
    float sl = e0+e1+e2+e3;
    for (int o=1;o<64;o<<=1) sl += __shfl_xor(sl,o);
    __syncthreads();
    if (lane==0) red[wid]=sl;
    __syncthreads();
    if (j==0) Zs = red[0]+red[1]+red[2]+red[3];
    __syncthreads();
    float inv = 1.f/Zs;
    size_t base = (size_t)(r0+r)*C;
    P[base + j      ] = f2bf(e0*inv);
    P[base + j + 256] = f2bf(e1*inv);
    P[base + j + 512] = f2bf(e2*inv);
    P[base + j + 768] = f2bf(e3*inv);
    __syncthreads();
  }
}

// ---------------- transpose term_wo (H,V) -> wotb (VP,H) bf16, zero-padded ----------------
__global__ __launch_bounds__(256) void k_transpose(const float* __restrict__ wo, u16* __restrict__ wotb){
  __shared__ float tile[32][33];
  int v0 = blockIdx.x*32, k0 = blockIdx.y*32;
  int tx = threadIdx.x, ty = threadIdx.y; // 32 x 8
  for (int i=0;i<32;i+=8){
    int k = k0+ty+i, v = v0+tx;
    tile[ty+i][tx] = (v < V) ? wo[(size_t)k*V + v] : 0.f;
  }
  __syncthreads();
  for (int i=0;i<32;i+=8){
    int v = v0+ty+i, k = k0+tx;
    wotb[(size_t)v*H + k] = f2bf(tile[tx][ty+i]);
  }
}

// ---------------- max wotb row norm & max bias ----------------
__global__ __launch_bounds__(256) void k_wnorm(const u16* __restrict__ wotb, const float* __restrict__ bo,
                                               u32* __restrict__ wmax, u32* __restrict__ bmax){
  const int tid = threadIdx.x, lane = tid&63, wid = tid>>6;
  __shared__ float rn[4]; __shared__ float bb[4];
  int v = blockIdx.x*4 + wid;
  float s = 0.f;
  const u16* r = wotb + (size_t)v*H;
  for (int k=lane;k<H;k+=64){ float x=bf2f(r[k]); s = fmaf(x,x,s); }
  for (int o=1;o<64;o<<=1) s += __shfl_xor(s,o);
  if (lane==0) rn[wid] = sqrtf(s);
  int bi = blockIdx.x*256 + tid;
  float bv = (bi < V) ? bo[bi] : -1e30f;
  for (int o=1;o<64;o<<=1) bv = fmaxf(bv, __shfl_xor(bv,o));
  if (lane==0) bb[wid] = bv;
  __syncthreads();
  if (tid==0){
    float nm = fmaxf(fmaxf(rn[0],rn[1]),fmaxf(rn[2],rn[3]));
    float bm = fmaxf(fmaxf(bb[0],bb[1]),fmaxf(bb[2],bb[3]));
    atomicMax(wmax, fenc(nm));
    atomicMax(bmax, fenc(bm));
  }
}

__global__ void k_shift(const float* __restrict__ rn2, const u32* __restrict__ wb, float* __restrict__ shift){
  int c = threadIdx.x + blockIdx.x*blockDim.x;
  if (c < C) shift[c] = sqrtf(rn2[c]) * 1.005f * fdec(wb[0]) + fdec(wb[1]) + 1.0f;
}

// ---------------- EM = h2_term(C,H) @ wotb(VP,H)^T + bo  (bf16 MFMA, fp32 out) ----------------
__global__ __launch_bounds__(256) void k_em(
    const u16* __restrict__ A, const u16* __restrict__ BT,
    const float* __restrict__ bo, float* __restrict__ EM){
  __shared__ u16 As[128*LDK];
  __shared__ u16 Bs[128*LDK];
  const int tid = threadIdx.x;
  const int lane = tid & 63, wave = tid >> 6;
  const int wm = wave >> 1, wn = wave & 1;
  const int m0 = blockIdx.y * 128, n0 = blockIdx.x * 128;
  const int lr = lane & 15, lg = lane >> 4;
  f32x4 acc[4][4] = {};
  const int sr = tid >> 1, sh = (tid & 1) * 16;
  for (int ks = 0; ks < H; ks += 32){
    const u16* ga = A  + (size_t)(m0 + sr)*H + ks + sh;
    const u16* gb = BT + (size_t)(n0 + sr)*H + ks + sh;
    uint4 a0 = *(const uint4*)ga;
    uint4 a1 = *(const uint4*)(ga + 8);
    uint4 b0 = *(const uint4*)gb;
    uint4 b1 = *(const uint4*)(gb + 8);
    __syncthreads();
    *(uint4*)&As[sr*LDK + sh]     = a0;
    *(uint4*)&As[sr*LDK + sh + 8] = a1;
    *(uint4*)&Bs[sr*LDK + sh]     = b0;
    *(uint4*)&Bs[sr*LDK + sh + 8] = b1;
    __syncthreads();
    bf16x8 af[4], bfr[4];
    #pragma unroll
    for (int m=0;m<4;m++) af[m]  = *(const bf16x8*)&As[(wm*64 + m*16 + lr)*LDK + lg*8];
    #pragma unroll
    for (int n=0;n<4;n++) bfr[n] = *(const bf16x8*)&Bs[(wn*64 + n*16 + lr)*LDK + lg*8];
    #pragma unroll
    for (int m=0;m<4;m++)
      #pragma unroll
      for (int n=0;n<4;n++)
        acc[m][n] = __builtin_amdgcn_mfma_f32_16x16x32_bf16(af[m], bfr[n], acc[m][n], 0,0,0);
  }
  #pragma unroll
  for (int m=0;m<4;m++){
    int r_g = m0 + wm*64 + m*16 + lg*4;
    #pragma unroll
    for (int n=0;n<4;n++){
      int n_g = n0 + wn*64 + n*16 + lr;
      float bv = (n_g < V) ? bo[n_g] : 0.f;
      #pragma unroll
      for (int reg=0; reg<4; reg++){
        EM[(size_t)(r_g + reg)*VP + n_g] = acc[m][n][reg] + bv;
      }
    }
  }
}

// ---------------- gather LT + dedupe + masked LSE partial sums ----------------
__global__ __launch_bounds__(128) void k_gather(
    const int* __restrict__ w2s, const float* __restrict__ EM,
    const float* __restrict__ shift,
    float* __restrict__ LT, float* __restrict__ sumexp){
  const int v = blockIdx.x;
  const int s = threadIdx.x;
  __shared__ u32 bm[C/32];
  if (s < C/32) bm[s] = 0u;
  __syncthreads();
  const int c = w2s[(size_t)v*S + s];
  u32 old = atomicOr(&bm[c>>5], 1u<<(c&31));
  const bool first = ((old >> (c&31)) & 1u) == 0u;
  float val = EM[(size_t)c*VP + v];
  LT[(size_t)v*S + s] = val;
  if (first) atomicAdd(&sumexp[(size_t)(v & (NR-1))*C + c], expf(val - shift[c]));
}

__global__ void k_lse(const float* __restrict__ shift, const float* __restrict__ sumexp, float* __restrict__ lse){
  int c = threadIdx.x + blockIdx.x*blockDim.x;
  if (c < C){
    float s = 0.f;
    for (int r=0;r<NR;r++) s += sumexp[(size_t)r*C + c];
    lse[c] = shift[c] + logf(s);
  }
}

// ---------------- obs[b,t,s] = LT[text,s] - lse[c] ----------------
__global__ __launch_bounds__(128) void k_obs(
    const int* __restrict__ text, const int* __restrict__ w2s,
    const float* __restrict__ LT, const float* __restrict__ lse,
    float* __restrict__ obs){
  const int bt = blockIdx.x;
  const int s = threadIdx.x;
  const int v = text[bt];
  const int c = w2s[(size_t)v*S + s];
  obs[(size_t)bt*S + s] = LT[(size_t)v*S + s] - lse[c];
}

// ---------------- build potS (swizzled) + colS ----------------
// pot[sn][sp] = P[cp[sp], cn[sn]] * exp(obs[b,t+1,sn])
// potS step layout (u16): offset = g*4096 + sn*32 + c*8   (chunk i = g*4+c covers cols 8i..8i+7 of row sn)
// colS[b,t][sp] = sum_sn pot[sn][sp]  (bf16)
__global__ __launch_bounds__(256) void k_pot(
    const int* __restrict__ text, const int* __restrict__ w2s,
    const float* __restrict__ obs,
    const u16* __restrict__ P, u16* __restrict__ potS, u16* __restrict__ colS){
  const int t = blockIdx.x;  // 0..T-2
  const int b = blockIdx.y;
  __shared__ int cp[S], cn[S];
  __shared__ float eo[S];
  __shared__ u32 tileW[S*65];          // u16 tile [sn][sp], row stride 130 u16
  __shared__ float colp[2][S];
  u16* tile16 = (u16*)tileW;
  const int tid = threadIdx.x;
  if (tid < 128){
    cp[tid] = w2s[(size_t)text[b*T + t  ]*S + tid];
    eo[tid] = expf(obs[((size_t)b*T + t + 1)*S + tid]);
  } else {
    cn[tid-128] = w2s[(size_t)text[b*T + t+1]*S + (tid-128)];
  }
  __syncthreads();
  const int sp_half = tid >> 7;
  const int sn = tid & 127;
  const int cnv = cn[sn];
  const float eov = eo[sn];
  for (int it=0; it<64; ++it){
    int sp = it*2 + sp_half;
    tile16[sn*130 + sp] = f2bf(bf2f(P[(size_t)cp[sp]*C + cnv]) * eov);
  }
  __syncthreads();
  // column sums over rows sn
  {
    int sp = tid & 127, half = tid >> 7;
    float s = 0.f;
    for (int r = half*64; r < half*64 + 64; ++r) s += bf2f(tile16[r*130 + sp]);
    colp[half][sp] = s;
  }
  __syncthreads();
  if (tid < 128) colS[((size_t)b*(T-1)+t)*S + tid] = f2bf(colp[0][tid] + colp[1][tid]);
  // swizzled writeout
  u16* dst = potS + ((size_t)b*(T-1) + t)*(S*S);
  #pragma unroll
  for (int k=0;k<8;k++){
    int j = k*256 + tid;
    int c2 = j & 3, sn2 = (j>>2)&127, g = j>>9;
    int i = g*4 + c2;
    const u32* tw = tileW + sn2*65 + i*4;
    uint4 w4; w4.x = tw[0]; w4.y = tw[1]; w4.z = tw[2]; w4.w = tw[3];
    *(uint4*)(dst + (size_t)g*4096 + sn2*32 + c2*8) = w4;
  }
}

// ---------------- sequential forward scan ----------------
// 3 waves: waves 0-1 = 128 row-lanes (1 row each, M in regs, depth-2 prefetch);
// wave 2 = Z via colsum dot (off main critical path). 1 barrier/step.
// evidence = M0 + sum_t log Z_t + log Z_final ; scale applied == scale logged (exact).
#define DOT4(MX, UX) { a0_=dot2bf(MX.x,UX.x,a0_); a1_=dot2bf(MX.y,UX.y,a1_); a2_=dot2bf(MX.z,UX.z,a2_); a3_=dot2bf(MX.w,UX.w,a3_); }

#define LOADM16(MB, ZB, TT) { int tc_ = (TT); if (tc_ > 126) tc_ = 126; \
  if (tid < 128){ \
    const u16* p_ = potSb + (size_t)tc_*16384 + tid*32; \
    MB[0] =*(const uint4*)(p_);        MB[1] =*(const uint4*)(p_+8);        MB[2] =*(const uint4*)(p_+16);        MB[3] =*(const uint4*)(p_+24); \
    MB[4] =*(const uint4*)(p_+4096);   MB[5] =*(const uint4*)(p_+4104);     MB[6] =*(const uint4*)(p_+4112);      MB[7] =*(const uint4*)(p_+4120); \
    MB[8] =*(const uint4*)(p_+8192);   MB[9] =*(const uint4*)(p_+8200);     MB[10]=*(const uint4*)(p_+8208);      MB[11]=*(const uint4*)(p_+8216); \
    MB[12]=*(const uint4*)(p_+12288);  MB[13]=*(const uint4*)(p_+12296);    MB[14]=*(const uint4*)(p_+12304);     MB[15]=*(const uint4*)(p_+12312); \
  } else { \
    ZB = *(const u32*)(colSb + (size_t)tc_*S + (tid & 63)*2); \
  } }

#define STEPS(MB, ZB) { \
  float Z_ = redL[cur]; \
  float sinv_ = __builtin_amdgcn_rcpf(Z_); \
  if (tid < 128){ \
    const uint4* ub_ = &uLds4[cur][0]; \
    float a0_=0.f, a1_=0.f, a2_=0.f, a3_=0.f; \
    uint4 u_; \
    u_=ub_[0];  DOT4(MB[0], u_)  u_=ub_[1];  DOT4(MB[1], u_) \
    u_=ub_[2];  DOT4(MB[2], u_)  u_=ub_[3];  DOT4(MB[3], u_) \
    u_=ub_[4];  DOT4(MB[4], u_)  u_=ub_[5];  DOT4(MB[5], u_) \
    u_=ub_[6];  DOT4(MB[6], u_)  u_=ub_[7];  DOT4(MB[7], u_) \
    u_=ub_[8];  DOT4(MB[8], u_)  u_=ub_[9];  DOT4(MB[9], u_) \
    u_=ub_[10]; DOT4(MB[10],u_)  u_=ub_[11]; DOT4(MB[11],u_) \
    u_=ub_[12]; DOT4(MB[12],u_)  u_=ub_[13]; DOT4(MB[13],u_) \
    u_=ub_[14]; DOT4(MB[14],u_)  u_=ub_[15]; DOT4(MB[15],u_) \
    float w_ = ((a0_+a1_)+(a2_+a3_)) * sinv_; \
    float ot_ = __shfl_xor(w_, 1); \
    float lo_ = (tid&1)? ot_ : w_; \
    float hi_ = (tid&1)? w_ : ot_; \
    u32 pk_; asm("v_cvt_pk_bf16_f32 %0, %1, %2" : "=v"(pk_) : "v"(lo_), "v"(hi_)); \
    if (!(tid&1)) uw32[(cur^1)*64 + (tid>>1)] = pk_; \
  } else { \
    u32 up_ = uw32[cur*64 + (tid & 63)]; \
    float zp_ = dot2bf(ZB, up_, 0.f); \
    zp_ += __shfl_xor(zp_,1);  zp_ += __shfl_xor(zp_,2);  zp_ += __shfl_xor(zp_,4); \
    zp_ += __shfl_xor(zp_,8);  zp_ += __shfl_xor(zp_,16); zp_ += __shfl_xor(zp_,32); \
    if (tid==128) redL[cur^1] = zp_ * sinv_; \
    L += __logf(Z_); \
  } \
  __syncthreads(); \
  cur ^= 1; }

__global__ __launch_bounds__(192, 1) void k_scan(
    const int* __restrict__ text, const int* __restrict__ w2s,
    const float* __restrict__ start_lp, const float* __restrict__ obs,
    const u16* __restrict__ potS, const u16* __restrict__ colS,
    float* __restrict__ res){
  const int b = blockIdx.x;
  const int tid = threadIdx.x;
  __shared__ uint4 uLds4[2][16];   // u as 128 bf16 (64 u32 words) x2 buffers
  __shared__ float redL[2];
  __shared__ float redm[4];
  u32* uw32 = (u32*)uLds4;
  const u16* potSb = potS + (size_t)b*(T-1)*S*S;
  const u16* colSb = colS + (size_t)b*(T-1)*S;
  float L = 0.f;
  float val = -1e30f;
  if (tid < 128){
    int c = w2s[(size_t)text[b*T]*S + tid];
    val = start_lp[c] + obs[(size_t)(b*T)*S + tid];
  }
  {
    float m_ = val;
    for (int o=1;o<64;o<<=1) m_ = fmaxf(m_, __shfl_xor(m_,o));
    if (tid < 128 && (tid&63)==0) redm[tid>>6] = m_;
  }
  __syncthreads();
  const float M0 = fmaxf(redm[0], redm[1]);
  if (tid < 128){
    float u0 = expf(val - M0);
    float ot = __shfl_xor(u0, 1);
    float lo = (tid&1)? ot : u0;
    float hi = (tid&1)? u0 : ot;
    u32 pk; asm("v_cvt_pk_bf16_f32 %0, %1, %2" : "=v"(pk) : "v"(lo), "v"(hi));
    if (!(tid&1)) uw32[tid>>1] = pk;
    float s_ = u0;
    for (int o=1;o<64;o<<=1) s_ += __shfl_xor(s_,o);
    if ((tid&63)==0) redm[2 + (tid>>6)] = s_;
  }
  __syncthreads();
  if (tid==0) redL[0] = redm[2] + redm[3];
  int cur = 0;
  uint4 MA[16], MBf[16], MC[16];
  u32 zA=0, zB=0, zC=0;
  LOADM16(MA, zA, 0)
  LOADM16(MBf, zB, 1)
  LOADM16(MC, zC, 2)
  __syncthreads();   // redL[0] visible
  int t = 0;
  for (int it=0; it<42; ++it){
    STEPS(MA, zA)   LOADM16(MA, zA, t+3)   t++;
    STEPS(MBf, zB)  LOADM16(MBf, zB, t+3)  t++;
    STEPS(MC, zC)   LOADM16(MC, zC, t+3)   t++;
  }
  STEPS(MA, zA)
  float Zf = redL[cur];
  if (tid==128) res[b] = M0 + L + logf(Zf);
}

__global__ void k_final(const float* __restrict__ res, float* __restrict__ out){
  if (threadIdx.x==0){
    float s = 0.f;
    for (int i=0;i<B;i++) s += res[i];
    out[0] = s;
  }
}

extern "C" void kernel_launch(void* const* d_in, const int* in_sizes, int n_in,
                              void* d_out, int out_size, void* d_ws, size_t ws_size,
                              hipStream_t stream){
  const int*   text      = (const int*)d_in[0];
  const int*   w2s       = (const int*)d_in[1];
  const float* start_emb = (const float*)d_in[2];
  const float* start_w1  = (const float*)d_in[3];
  const float* start_b1  = (const float*)d_in[4];
  const float* start_w2  = (const float*)d_in[5];
  const float* start_b2  = (const float*)d_in[6];
  const float* start_wo  = (const float*)d_in[7];
  const float* start_bo  = (const float*)d_in[8];
  const float* state_emb = (const float*)d_in[9];
  const float* trans_w1  = (const float*)d_in[10];
  const float* trans_b1  = (const float*)d_in[11];
  const float* trans_w2  = (const float*)d_in[12];
  const float* trans_b2  = (const float*)d_in[13];
  const float* trans_wo  = (const float*)d_in[14];
  const float* trans_bo  = (const float*)d_in[15];
  const float* pre_emb   = (const float*)d_in[16];
  const float* term_w1   = (const float*)d_in[17];
  const float* term_b1   = (const float*)d_in[18];
  const float* term_w2   = (const float*)d_in[19];
  const float* term_b2   = (const float*)d_in[20];
  const float* term_wo   = (const float*)d_in[21];
  const float* term_bo   = (const float*)d_in[22];

  char* ws = (char*)d_ws;
  size_t off = 0;
  auto alloc = [&](size_t bytes)->char*{ char* p = ws + off; off += (bytes + 255) & ~(size_t)255; return p; };
  float* h2_start = (float*)alloc(sizeof(float)*(size_t)C*H);
  float* h2_trans = (float*)alloc(sizeof(float)*(size_t)C*H);
  u16*   h2_term  = (u16*)  alloc(sizeof(u16)*(size_t)C*H);
  float* rn2      = (float*)alloc(sizeof(float)*C);
  float* start_lp = (float*)alloc(sizeof(float)*C);
  float* shift    = (float*)alloc(sizeof(float)*C);
  float* sumexp   = (float*)alloc(sizeof(float)*(size_t)C*NR);
  float* lse      = (float*)alloc(sizeof(float)*C);
  u32*   wb       = (u32*)  alloc(sizeof(u32)*2);
  float* resb     = (float*)alloc(sizeof(float)*B);
  u16*   P        = (u16*)  alloc(sizeof(u16)*(size_t)C*C);
  u16*   wotb     = (u16*)  alloc(sizeof(u16)*(size_t)VP*H);
  float* LT       = (float*)alloc(sizeof(float)*(size_t)V*S);
  float* obs      = (float*)alloc(sizeof(float)*(size_t)B*T*S);
  u16*   colS     = (u16*)  alloc(sizeof(u16)*(size_t)B*(T-1)*S);
  u16*   potS     = (u16*)  alloc(sizeof(u16)*(size_t)B*(T-1)*S*S);  // >= EM bytes
  float* EM       = (float*)potS;   // aliased: EM dead before k_pot writes potS
  (void)ws_size; (void)in_sizes; (void)n_in; (void)out_size;

  k_zero<<<dim3((C*NR+255)/256), dim3(256), 0, stream>>>(sumexp, wb, resb);
  k_mlp<<<dim3(C/RPB), dim3(256), 0, stream>>>(start_emb, start_w1, start_b1, start_w2, start_b2, h2_start, (u16*)nullptr, (float*)nullptr);
  k_mlp<<<dim3(C/RPB), dim3(256), 0, stream>>>(state_emb, trans_w1, trans_b1, trans_w2, trans_b2, h2_trans, (u16*)nullptr, (float*)nullptr);
  k_mlp<<<dim3(C/RPB), dim3(256), 0, stream>>>(pre_emb, term_w1, term_b1, term_w2, term_b2, (float*)nullptr, h2_term, rn2);
  k_start<<<dim3(1), dim3(1024), 0, stream>>>(h2_start, start_wo, start_bo, start_lp);
  k_trans<<<dim3(C/RC), dim3(256), 0, stream>>>(h2_trans, trans_wo, trans_bo, P);
  k_transpose<<<dim3(VP/32, H/32), dim3(32,8), 0, stream>>>(term_wo, wotb);
  k_wnorm<<<dim3(VP/4), dim3(256), 0, stream>>>(wotb, term_bo, wb, wb+1);
  k_shift<<<dim3((C+255)/256), dim3(256), 0, stream>>>(rn2, wb, shift);
  k_em<<<dim3(VP/128, C/128), dim3(256), 0, stream>>>(h2_term, wotb, term_bo, EM);
  k_gather<<<dim3(V), dim3(128), 0, stream>>>(w2s, EM, shift, LT, sumexp);
  k_lse<<<dim3((C+255)/256), dim3(256), 0, stream>>>(shift, sumexp, lse);
  k_obs<<<dim3(B*T), dim3(128), 0, stream>>>(text, w2s, LT, lse, obs);
  k_pot<<<dim3(T-1, B), dim3(256), 0, stream>>>(text, w2s, obs, P, potS, colS);
  k_scan<<<dim3(B), dim3(192), 0, stream>>>(text, w2s, start_lp, obs, potS, colS, resb);
  k_final<<<dim3(1), dim3(64), 0, stream>>>(resb, (float*)d_out);
}

// Round 5
// 430.071 us; speedup vs baseline: 1.0515x; 1.0515x over previous
//
#include <hip/hip_runtime.h>
#include <hip/hip_bf16.h>

#define V 10000
#define VP 10112
#define C 1024
#define S 128
#define H 256
#define B 16
#define T 128
#define NR 32      // sumexp replicas
#define LDK 40     // padded LDS row length (u16) for k_em

typedef unsigned short u16;
typedef unsigned int u32;
typedef __bf16 bf16x8 __attribute__((ext_vector_type(8)));
typedef float f32x4 __attribute__((ext_vector_type(4)));

static __device__ __forceinline__ float bf2f(u16 x){ return __uint_as_float(((u32)x)<<16); }
static __device__ __forceinline__ u16 f2bf(float f){ u32 u=__float_as_uint(f); return (u16)((u + 0x7FFFu + ((u>>16)&1u))>>16); }
static __device__ __forceinline__ u32 fenc(float f){ u32 b=__float_as_uint(f); return (b&0x80000000u)? ~b : (b|0x80000000u); }
static __device__ __forceinline__ float fdec(u32 e){ u32 b=(e&0x80000000u)? (e&0x7FFFFFFFu) : ~e; return __uint_as_float(b); }

// ---------------- zero accumulators ----------------
__global__ void k_zero(float* __restrict__ sumexp, u32* __restrict__ wb, float* __restrict__ res){
  int i = threadIdx.x + blockIdx.x*blockDim.x;
  if (i < C*NR) sumexp[i] = 0.f;
  if (i < 2) wb[i] = 0u;
  if (i < B) res[i] = 0.f;
}

// ---------------- MLP: h2 = relu(relu(x@w1+b1)@w2+b2+x) ----------------
#define RPB 8
__global__ __launch_bounds__(256) void k_mlp(
    const float* __restrict__ x, const float* __restrict__ w1, const float* __restrict__ b1,
    const float* __restrict__ w2, const float* __restrict__ b2,
    float* __restrict__ out_f32, u16* __restrict__ out_bf16, float* __restrict__ rn2){
  __shared__ float xr[RPB][H];
  __shared__ float h1r[RPB][H];
  const int j = threadIdx.x;
  const int r0 = blockIdx.x * RPB;
  #pragma unroll
  for (int r=0;r<RPB;r++) xr[r][j] = x[(size_t)(r0+r)*H + j];
  __syncthreads();
  float acc[RPB];
  {
    float bj = b1[j];
    #pragma unroll
    for (int r=0;r<RPB;r++) acc[r]=bj;
    for (int k=0;k<H;k++){
      float w = w1[(size_t)k*H + j];
      #pragma unroll
      for (int r=0;r<RPB;r++) acc[r] = fmaf(xr[r][k], w, acc[r]);
    }
  }
  #pragma unroll
  for (int r=0;r<RPB;r++) h1r[r][j] = fmaxf(acc[r], 0.f);
  __syncthreads();
  {
    float bj = b2[j];
    #pragma unroll
    for (int r=0;r<RPB;r++) acc[r] = bj + xr[r][j];
    for (int k=0;k<H;k++){
      float w = w2[(size_t)k*H + j];
      #pragma unroll
      for (int r=0;r<RPB;r++) acc[r] = fmaf(h1r[r][k], w, acc[r]);
    }
  }
  #pragma unroll
  for (int r=0;r<RPB;r++){
    float h2 = fmaxf(acc[r], 0.f);
    if (out_f32)  out_f32 [(size_t)(r0+r)*H + j] = h2;
    if (out_bf16) out_bf16[(size_t)(r0+r)*H + j] = f2bf(h2);
    acc[r] = h2*h2;
  }
  if (rn2){
    __syncthreads();
    #pragma unroll
    for (int r=0;r<RPB;r++) xr[r][j] = acc[r];
    __syncthreads();
    for (int off=128; off>=1; off>>=1){
      if (j < off){
        #pragma unroll
        for (int r=0;r<RPB;r++) xr[r][j] += xr[r][j+off];
      }
      __syncthreads();
    }
    if (j==0){
      #pragma unroll
      for (int r=0;r<RPB;r++) rn2[r0+r] = xr[r][0];
    }
  }
}

// ---------------- start head + log_softmax over C ----------------
__global__ __launch_bounds__(1024) void k_start(
    const float* __restrict__ h2, const float* __restrict__ wo, const float* __restrict__ bo,
    float* __restrict__ start_lp){
  const int c = threadIdx.x;
  const int lane = c & 63, wid = c >> 6;
  __shared__ float red[16];
  __shared__ float Ms, Zs;
  float acc = bo[0];
  const float* row = h2 + (size_t)c*H;
  for (int k=0;k<H;k+=4){
    float4 hv = *(const float4*)(row+k);
    float4 wv = *(const float4*)(wo+k);
    acc = fmaf(hv.x,wv.x,acc); acc = fmaf(hv.y,wv.y,acc);
    acc = fmaf(hv.z,wv.z,acc); acc = fmaf(hv.w,wv.w,acc);
  }
  float m = acc;
  for (int o=1;o<64;o<<=1) m = fmaxf(m, __shfl_xor(m,o));
  if (lane==0) red[wid]=m;
  __syncthreads();
  if (c==0){ float t=red[0]; for(int i=1;i<16;i++) t=fmaxf(t,red[i]); Ms=t; }
  __syncthreads();
  float M = Ms;
  float e = expf(acc - M);
  float sum = e;
  for (int o=1;o<64;o<<=1) sum += __shfl_xor(sum,o);
  __syncthreads();
  if (lane==0) red[wid]=sum;
  __syncthreads();
  if (c==0){ float t=0.f; for(int i=0;i<16;i++) t+=red[i]; Zs=t; }
  __syncthreads();
  start_lp[c] = acc - (M + logf(Zs));
}

// ---------------- transition head + row softmax -> P (bf16 probs) ----------------
#define RC 8
__global__ __launch_bounds__(256) void k_trans(
    const float* __restrict__ h2, const float* __restrict__ wo, const float* __restrict__ bo,
    u16* __restrict__ P){
  __shared__ float xr[RC][H];
  __shared__ float red[4];
  __shared__ float Ms, Zs;
  const int j = threadIdx.x, lane = j&63, wid = j>>6;
  const int r0 = blockIdx.x*RC;
  #pragma unroll
  for (int r=0;r<RC;r++) xr[r][j] = h2[(size_t)(r0+r)*H + j];
  __syncthreads();
  float acc[4][RC];
  #pragma unroll
  for (int m=0;m<4;m++){
    float bv = bo[j + 256*m];
    #pragma unroll
    for (int r=0;r<RC;r++) acc[m][r]=bv;
  }
  for (int k=0;k<H;k++){
    float w0 = wo[(size_t)k*C + j];
    float w1v = wo[(size_t)k*C + j + 256];
    float w2v = wo[(size_t)k*C + j + 512];
    float w3v = wo[(size_t)k*C + j + 768];
    #pragma unroll
    for (int r=0;r<RC;r++){
      float xv = xr[r][k];
      acc[0][r]=fmaf(xv,w0 ,acc[0][r]);
      acc[1][r]=fmaf(xv,w1v,acc[1][r]);
      acc[2][r]=fmaf(xv,w2v,acc[2][r]);
      acc[3][r]=fmaf(xv,w3v,acc[3][r]);
    }
  }
  for (int r=0;r<RC;r++){
    float mx = fmaxf(fmaxf(acc[0][r],acc[1][r]), fmaxf(acc[2][r],acc[3][r]));
    for (int o=1;o<64;o<<=1) mx = fmaxf(mx, __shfl_xor(mx,o));
    if (lane==0) red[wid]=mx;
    __syncthreads();
    if (j==0) Ms = fmaxf(fmaxf(red[0],red[1]),fmaxf(red[2],red[3]));
    __syncthreads();
    float M = Ms;
    float e0=expf(acc[0][r]-M), e1=expf(acc[1][r]-M), e2=expf(acc[2][r]-M), e3=expf(acc[3][r]-M);
    float sl = e0+e1+e2+e3;
    for (int o=1;o<64;o<<=1) sl += __shfl_xor(sl,o);
    __syncthreads();
    if (lane==0) red[wid]=sl;
    __syncthreads();
    if (j==0) Zs = red[0]+red[1]+red[2]+red[3];
    __syncthreads();
    float inv = 1.f/Zs;
    size_t base = (size_t)(r0+r)*C;
    P[base + j      ] = f2bf(e0*inv);
    P[base + j + 256] = f2bf(e1*inv);
    P[base + j + 512] = f2bf(e2*inv);
    P[base + j + 768] = f2bf(e3*inv);
    __syncthreads();
  }
}

// ---------------- transpose term_wo (H,V) -> wotb (VP,H) bf16, zero-padded ----------------
__global__ __launch_bounds__(256) void k_transpose(const float* __restrict__ wo, u16* __restrict__ wotb){
  __shared__ float tile[32][33];
  int v0 = blockIdx.x*32, k0 = blockIdx.y*32;
  int tx = threadIdx.x, ty = threadIdx.y; // 32 x 8
  for (int i=0;i<32;i+=8){
    int k = k0+ty+i, v = v0+tx;
    tile[ty+i][tx] = (v < V) ? wo[(size_t)k*V + v] : 0.f;
  }
  __syncthreads();
  for (int i=0;i<32;i+=8){
    int v = v0+ty+i, k = k0+tx;
    wotb[(size_t)v*H + k] = f2bf(tile[tx][ty+i]);
  }
}

// ---------------- max wotb row norm & max bias ----------------
__global__ __launch_bounds__(256) void k_wnorm(const u16* __restrict__ wotb, const float* __restrict__ bo,
                                               u32* __restrict__ wmax, u32* __restrict__ bmax){
  const int tid = threadIdx.x, lane = tid&63, wid = tid>>6;
  __shared__ float rn[4]; __shared__ float bb[4];
  int v = blockIdx.x*4 + wid;
  float s = 0.f;
  const u16* r = wotb + (size_t)v*H;
  for (int k=lane;k<H;k+=64){ float x=bf2f(r[k]); s = fmaf(x,x,s); }
  for (int o=1;o<64;o<<=1) s += __shfl_xor(s,o);
  if (lane==0) rn[wid] = sqrtf(s);
  int bi = blockIdx.x*256 + tid;
  float bv = (bi < V) ? bo[bi] : -1e30f;
  for (int o=1;o<64;o<<=1) bv = fmaxf(bv, __shfl_xor(bv,o));
  if (lane==0) bb[wid] = bv;
  __syncthreads();
  if (tid==0){
    float nm = fmaxf(fmaxf(rn[0],rn[1]),fmaxf(rn[2],rn[3]));
    float bm = fmaxf(fmaxf(bb[0],bb[1]),fmaxf(bb[2],bb[3]));
    atomicMax(wmax, fenc(nm));
    atomicMax(bmax, fenc(bm));
  }
}

__global__ void k_shift(const float* __restrict__ rn2, const u32* __restrict__ wb, float* __restrict__ shift){
  int c = threadIdx.x + blockIdx.x*blockDim.x;
  if (c < C) shift[c] = sqrtf(rn2[c]) * 1.005f * fdec(wb[0]) + fdec(wb[1]) + 1.0f;
}

// ---------------- EM = h2_term(C,H) @ wotb(VP,H)^T + bo  (bf16 MFMA, fp32 out) ----------------
__global__ __launch_bounds__(256) void k_em(
    const u16* __restrict__ A, const u16* __restrict__ BT,
    const float* __restrict__ bo, float* __restrict__ EM){
  __shared__ u16 As[128*LDK];
  __shared__ u16 Bs[128*LDK];
  const int tid = threadIdx.x;
  const int lane = tid & 63, wave = tid >> 6;
  const int wm = wave >> 1, wn = wave & 1;
  const int m0 = blockIdx.y * 128, n0 = blockIdx.x * 128;
  const int lr = lane & 15, lg = lane >> 4;
  f32x4 acc[4][4] = {};
  const int sr = tid >> 1, sh = (tid & 1) * 16;
  for (int ks = 0; ks < H; ks += 32){
    const u16* ga = A  + (size_t)(m0 + sr)*H + ks + sh;
    const u16* gb = BT + (size_t)(n0 + sr)*H + ks + sh;
    uint4 a0 = *(const uint4*)ga;
    uint4 a1 = *(const uint4*)(ga + 8);
    uint4 b0 = *(const uint4*)gb;
    uint4 b1 = *(const uint4*)(gb + 8);
    __syncthreads();
    *(uint4*)&As[sr*LDK + sh]     = a0;
    *(uint4*)&As[sr*LDK + sh + 8] = a1;
    *(uint4*)&Bs[sr*LDK + sh]     = b0;
    *(uint4*)&Bs[sr*LDK + sh + 8] = b1;
    __syncthreads();
    bf16x8 af[4], bfr[4];
    #pragma unroll
    for (int m=0;m<4;m++) af[m]  = *(const bf16x8*)&As[(wm*64 + m*16 + lr)*LDK + lg*8];
    #pragma unroll
    for (int n=0;n<4;n++) bfr[n] = *(const bf16x8*)&Bs[(wn*64 + n*16 + lr)*LDK + lg*8];
    #pragma unroll
    for (int m=0;m<4;m++)
      #pragma unroll
      for (int n=0;n<4;n++)
        acc[m][n] = __builtin_amdgcn_mfma_f32_16x16x32_bf16(af[m], bfr[n], acc[m][n], 0,0,0);
  }
  #pragma unroll
  for (int m=0;m<4;m++){
    int r_g = m0 + wm*64 + m*16 + lg*4;
    #pragma unroll
    for (int n=0;n<4;n++){
      int n_g = n0 + wn*64 + n*16 + lr;
      float bv = (n_g < V) ? bo[n_g] : 0.f;
      #pragma unroll
      for (int reg=0; reg<4; reg++){
        EM[(size_t)(r_g + reg)*VP + n_g] = acc[m][n][reg] + bv;
      }
    }
  }
}

// ---------------- gather LT + dedupe + masked LSE partial sums ----------------
__global__ __launch_bounds__(128) void k_gather(
    const int* __restrict__ w2s, const float* __restrict__ EM,
    const float* __restrict__ shift,
    float* __restrict__ LT, float* __restrict__ sumexp){
  const int v = blockIdx.x;
  const int s = threadIdx.x;
  __shared__ u32 bm[C/32];
  if (s < C/32) bm[s] = 0u;
  __syncthreads();
  const int c = w2s[(size_t)v*S + s];
  u32 old = atomicOr(&bm[c>>5], 1u<<(c&31));
  const bool first = ((old >> (c&31)) & 1u) == 0u;
  float val = EM[(size_t)c*VP + v];
  LT[(size_t)v*S + s] = val;
  if (first) atomicAdd(&sumexp[(size_t)(v & (NR-1))*C + c], expf(val - shift[c]));
}

__global__ void k_lse(const float* __restrict__ shift, const float* __restrict__ sumexp, float* __restrict__ lse){
  int c = threadIdx.x + blockIdx.x*blockDim.x;
  if (c < C){
    float s = 0.f;
    for (int r=0;r<NR;r++) s += sumexp[(size_t)r*C + c];
    lse[c] = shift[c] + logf(s);
  }
}

// ---------------- obs[b,t,s] = LT[text,s] - lse[c] ----------------
__global__ __launch_bounds__(128) void k_obs(
    const int* __restrict__ text, const int* __restrict__ w2s,
    const float* __restrict__ LT, const float* __restrict__ lse,
    float* __restrict__ obs){
  const int bt = blockIdx.x;
  const int s = threadIdx.x;
  const int v = text[bt];
  const int c = w2s[(size_t)v*S + s];
  obs[(size_t)bt*S + s] = LT[(size_t)v*S + s] - lse[c];
}

// ---------------- build level-0 tiles ----------------
// tile_t[sn][sp] = P[cp[sp], cn[sn]] * exp(obs[b,t+1,sn]) * (t==0 ? a0[sp] : 1)
// t==127: identity. Orientation: t odd -> row-major [sn][sp] (A-role);
// t even -> transposed [sp][sn] (B-role for MFMA B^T fragment).
__global__ __launch_bounds__(256) void k_pot(
    const int* __restrict__ text, const int* __restrict__ w2s,
    const float* __restrict__ start_lp, const float* __restrict__ obs,
    const u16* __restrict__ P, u16* __restrict__ pot){
  const int t = blockIdx.x;  // 0..127
  const int b = blockIdx.y;
  const int tid = threadIdx.x;
  u16* dst = pot + ((size_t)b*128 + t)*(S*S);
  if (t == 127){
    #pragma unroll
    for (int k=0;k<8;k++){
      int e0 = (k*256 + tid)*8;
      int row = e0>>7, c0 = e0&127;
      union { uint4 w; u16 h[8]; } u;
      u.w = make_uint4(0,0,0,0);
      int d = row - c0;
      if (d >= 0 && d < 8) u.h[d] = 0x3F80u;  // 1.0 bf16
      *(uint4*)(dst + e0) = u.w;
    }
    return;
  }
  __shared__ int cp[S], cn[S];
  __shared__ float eo[S];
  __shared__ float a0[S];
  __shared__ u32 tileW[S*65];          // u16 tile [sn][sp], row stride 130 u16
  u16* tile16 = (u16*)tileW;
  if (tid < 128){
    int cpv = w2s[(size_t)text[b*T + t]*S + tid];
    cp[tid] = cpv;
    a0[tid] = (t==0) ? expf(start_lp[cpv] + obs[(size_t)(b*T)*S + tid]) : 1.0f;
    eo[tid] = expf(obs[((size_t)b*T + t + 1)*S + tid]);
  } else {
    cn[tid-128] = w2s[(size_t)text[b*T + t+1]*S + (tid-128)];
  }
  __syncthreads();
  const int sp_half = tid >> 7;
  const int sn = tid & 127;
  const int cnv = cn[sn];
  const float eov = eo[sn];
  for (int it=0; it<64; ++it){
    int sp = it*2 + sp_half;
    tile16[sn*130 + sp] = f2bf(bf2f(P[(size_t)cp[sp]*C + cnv]) * eov * a0[sp]);
  }
  __syncthreads();
  if (t & 1){
    #pragma unroll
    for (int ii=0; ii<8; ++ii){
      int i0 = (ii*256 + tid)*8;
      int sn2 = i0>>7, sp2 = i0&127;
      const u32* tw = tileW + sn2*65 + (sp2>>1);
      uint4 w4; w4.x = tw[0]; w4.y = tw[1]; w4.z = tw[2]; w4.w = tw[3];
      *(uint4*)(dst + i0) = w4;
    }
  } else {
    #pragma unroll
    for (int ii=0; ii<8; ++ii){
      int i0 = (ii*256 + tid)*8;
      int sp2 = i0>>7, sn0 = i0&127;
      union { uint4 w; u16 h[8]; } u;
      #pragma unroll
      for (int j=0;j<8;j++) u.h[j] = tile16[(sn0+j)*130 + sp2];
      *(uint4*)(dst + i0) = u.w;
    }
  }
}

// ---------------- tree pair-product: out[j] = in[2j+1] . in[2j] ----------------
// in[odd] stored row-major [i][k]; in[even] stored transposed [j][k] (= B^T frags).
// out[j]: j odd -> row-major; j even -> transposed. Rescale by max, log to scales.
__global__ __launch_bounds__(256) void k_pair(
    const u16* __restrict__ in, u16* __restrict__ out,
    float* __restrict__ scales, int nin, int soff){
  const int j = blockIdx.x;
  const int b = blockIdx.y;
  const int nout = nin >> 1;
  const u16* Ag = in + ((size_t)b*nin + 2*j+1)*(S*S);
  const u16* Bg = in + ((size_t)b*nin + 2*j  )*(S*S);
  u16* Cg = out + ((size_t)b*nout + j)*(S*S);
  const int tid = threadIdx.x;
  const int lane = tid & 63, wave = tid >> 6;
  const int wm = wave >> 1, wn = wave & 1;
  const int lr = lane & 15, lg = lane >> 4;
  f32x4 acc[4][4] = {};
  #pragma unroll
  for (int kc=0; kc<4; ++kc){
    bf16x8 af[4], bfr[4];
    #pragma unroll
    for (int m=0;m<4;m++) af[m]  = *(const bf16x8*)(Ag + (size_t)(wm*64+m*16+lr)*128 + kc*32 + lg*8);
    #pragma unroll
    for (int n=0;n<4;n++) bfr[n] = *(const bf16x8*)(Bg + (size_t)(wn*64+n*16+lr)*128 + kc*32 + lg*8);
    #pragma unroll
    for (int m=0;m<4;m++)
      #pragma unroll
      for (int n=0;n<4;n++)
        acc[m][n] = __builtin_amdgcn_mfma_f32_16x16x32_bf16(af[m], bfr[n], acc[m][n], 0,0,0);
  }
  __shared__ float red[4];
  float mx = 0.f;
  #pragma unroll
  for (int m=0;m<4;m++)
    #pragma unroll
    for (int n=0;n<4;n++)
      #pragma unroll
      for (int r=0;r<4;r++) mx = fmaxf(mx, acc[m][n][r]);
  for (int o=1;o<64;o<<=1) mx = fmaxf(mx, __shfl_xor(mx,o));
  if (lane==0) red[wave] = mx;
  __syncthreads();
  mx = fmaxf(fmaxf(red[0],red[1]), fmaxf(red[2],red[3]));
  const float sc = 1.0f / mx;
  if (tid==0) scales[(size_t)b*127 + soff + j] = logf(mx);
  if (j & 1){
    // row-major C[row][col]
    #pragma unroll
    for (int m=0;m<4;m++){
      int rg = wm*64 + m*16 + lg*4;
      #pragma unroll
      for (int n=0;n<4;n++){
        int cg = wn*64 + n*16 + lr;
        #pragma unroll
        for (int r=0;r<4;r++) Cg[(size_t)(rg+r)*128 + cg] = f2bf(acc[m][n][r]*sc);
      }
    }
  } else {
    // transposed C^T[col][row] — 4 contiguous rows per fragment -> 8B stores
    #pragma unroll
    for (int m=0;m<4;m++){
      int rg = wm*64 + m*16 + lg*4;
      #pragma unroll
      for (int n=0;n<4;n++){
        int cg = wn*64 + n*16 + lr;
        float v0=acc[m][n][0]*sc, v1=acc[m][n][1]*sc, v2=acc[m][n][2]*sc, v3=acc[m][n][3]*sc;
        u32 p0, p1;
        asm("v_cvt_pk_bf16_f32 %0, %1, %2" : "=v"(p0) : "v"(v0), "v"(v1));
        asm("v_cvt_pk_bf16_f32 %0, %1, %2" : "=v"(p1) : "v"(v2), "v"(v3));
        *(uint2*)(Cg + (size_t)cg*128 + rg) = make_uint2(p0, p1);
      }
    }
  }
}

// ---------------- final: res[b] = log(sum all entries of final tile) + sum(scales) ----------------
__global__ __launch_bounds__(256) void k_fin(
    const u16* __restrict__ fin, const float* __restrict__ scales, float* __restrict__ res){
  const int b = blockIdx.x;
  const int tid = threadIdx.x, lane = tid & 63, wid = tid >> 6;
  __shared__ float red[8];
  const u16* p = fin + (size_t)b*(S*S);
  float s = 0.f;
  #pragma unroll
  for (int i=0;i<8;i++){
    uint4 w = *(const uint4*)(p + (i*256+tid)*8);
    s += bf2f((u16)(w.x&0xFFFFu)) + bf2f((u16)(w.x>>16))
       + bf2f((u16)(w.y&0xFFFFu)) + bf2f((u16)(w.y>>16))
       + bf2f((u16)(w.z&0xFFFFu)) + bf2f((u16)(w.z>>16))
       + bf2f((u16)(w.w&0xFFFFu)) + bf2f((u16)(w.w>>16));
  }
  for (int o=1;o<64;o<<=1) s += __shfl_xor(s,o);
  if (lane==0) red[wid] = s;
  float sl = (tid < 127) ? scales[(size_t)b*127 + tid] : 0.f;
  for (int o=1;o<64;o<<=1) sl += __shfl_xor(sl,o);
  if (lane==0) red[4+wid] = sl;
  __syncthreads();
  if (tid==0){
    float tot = red[0]+red[1]+red[2]+red[3];
    float ssum = red[4]+red[5]+red[6]+red[7];
    res[b] = logf(tot) + ssum;
  }
}

__global__ void k_final(const float* __restrict__ res, float* __restrict__ out){
  if (threadIdx.x==0){
    float s = 0.f;
    for (int i=0;i<B;i++) s += res[i];
    out[0] = s;
  }
}

extern "C" void kernel_launch(void* const* d_in, const int* in_sizes, int n_in,
                              void* d_out, int out_size, void* d_ws, size_t ws_size,
                              hipStream_t stream){
  const int*   text      = (const int*)d_in[0];
  const int*   w2s       = (const int*)d_in[1];
  const float* start_emb = (const float*)d_in[2];
  const float* start_w1  = (const float*)d_in[3];
  const float* start_b1  = (const float*)d_in[4];
  const float* start_w2  = (const float*)d_in[5];
  const float* start_b2  = (const float*)d_in[6];
  const float* start_wo  = (const float*)d_in[7];
  const float* start_bo  = (const float*)d_in[8];
  const float* state_emb = (const float*)d_in[9];
  const float* trans_w1  = (const float*)d_in[10];
  const float* trans_b1  = (const float*)d_in[11];
  const float* trans_w2  = (const float*)d_in[12];
  const float* trans_b2  = (const float*)d_in[13];
  const float* trans_wo  = (const float*)d_in[14];
  const float* trans_bo  = (const float*)d_in[15];
  const float* pre_emb   = (const float*)d_in[16];
  const float* term_w1   = (const float*)d_in[17];
  const float* term_b1   = (const float*)d_in[18];
  const float* term_w2   = (const float*)d_in[19];
  const float* term_b2   = (const float*)d_in[20];
  const float* term_wo   = (const float*)d_in[21];
  const float* term_bo   = (const float*)d_in[22];

  char* ws = (char*)d_ws;
  size_t off = 0;
  auto alloc = [&](size_t bytes)->char*{ char* p = ws + off; off += (bytes + 255) & ~(size_t)255; return p; };
  float* h2_start = (float*)alloc(sizeof(float)*(size_t)C*H);
  float* h2_trans = (float*)alloc(sizeof(float)*(size_t)C*H);
  u16*   h2_term  = (u16*)  alloc(sizeof(u16)*(size_t)C*H);
  float* rn2      = (float*)alloc(sizeof(float)*C);
  float* start_lp = (float*)alloc(sizeof(float)*C);
  float* shift    = (float*)alloc(sizeof(float)*C);
  float* sumexp   = (float*)alloc(sizeof(float)*(size_t)C*NR);
  float* lse      = (float*)alloc(sizeof(float)*C);
  u32*   wb       = (u32*)  alloc(sizeof(u32)*2);
  float* resb     = (float*)alloc(sizeof(float)*B);
  float* scales   = (float*)alloc(sizeof(float)*(size_t)B*127);
  u16*   P        = (u16*)  alloc(sizeof(u16)*(size_t)C*C);
  u16*   wotb     = (u16*)  alloc(sizeof(u16)*(size_t)VP*H);
  float* LT       = (float*)alloc(sizeof(float)*(size_t)V*S);
  float* obs      = (float*)alloc(sizeof(float)*(size_t)B*T*S);
  u16*   potS     = (u16*)  alloc(sizeof(u16)*(size_t)B*128*S*S);   // level-0 tiles (>= EM bytes)
  u16*   treeA    = (u16*)  alloc(sizeof(u16)*(size_t)B*64*S*S);
  u16*   treeB    = (u16*)  alloc(sizeof(u16)*(size_t)B*32*S*S);
  float* EM       = (float*)potS;   // aliased: EM dead before k_pot writes potS
  (void)ws_size; (void)in_sizes; (void)n_in; (void)out_size;

  k_zero<<<dim3((C*NR+255)/256), dim3(256), 0, stream>>>(sumexp, wb, resb);
  k_mlp<<<dim3(C/RPB), dim3(256), 0, stream>>>(start_emb, start_w1, start_b1, start_w2, start_b2, h2_start, (u16*)nullptr, (float*)nullptr);
  k_mlp<<<dim3(C/RPB), dim3(256), 0, stream>>>(state_emb, trans_w1, trans_b1, trans_w2, trans_b2, h2_trans, (u16*)nullptr, (float*)nullptr);
  k_mlp<<<dim3(C/RPB), dim3(256), 0, stream>>>(pre_emb, term_w1, term_b1, term_w2, term_b2, (float*)nullptr, h2_term, rn2);
  k_start<<<dim3(1), dim3(1024), 0, stream>>>(h2_start, start_wo, start_bo, start_lp);
  k_trans<<<dim3(C/RC), dim3(256), 0, stream>>>(h2_trans, trans_wo, trans_bo, P);
  k_transpose<<<dim3(VP/32, H/32), dim3(32,8), 0, stream>>>(term_wo, wotb);
  k_wnorm<<<dim3(VP/4), dim3(256), 0, stream>>>(wotb, term_bo, wb, wb+1);
  k_shift<<<dim3((C+255)/256), dim3(256), 0, stream>>>(rn2, wb, shift);
  k_em<<<dim3(VP/128, C/128), dim3(256), 0, stream>>>(h2_term, wotb, term_bo, EM);
  k_gather<<<dim3(V), dim3(128), 0, stream>>>(w2s, EM, shift, LT, sumexp);
  k_lse<<<dim3((C+255)/256), dim3(256), 0, stream>>>(shift, sumexp, lse);
  k_obs<<<dim3(B*T), dim3(128), 0, stream>>>(text, w2s, LT, lse, obs);
  k_pot<<<dim3(128, B), dim3(256), 0, stream>>>(text, w2s, start_lp, obs, P, potS);

  // product tree: 128 -> 64 -> 32 -> 16 -> 8 -> 4 -> 2 -> 1
  {
    u16* lin = potS;
    u16* bufs[2] = { treeA, treeB };
    int nin = 128, soff = 0, cur = 0;
    while (nin > 1){
      int nout = nin >> 1;
      k_pair<<<dim3(nout, B), dim3(256), 0, stream>>>(lin, bufs[cur], scales, nin, soff);
      lin = bufs[cur];
      cur ^= 1;
      soff += nout;
      nin = nout;
    }
    k_fin<<<dim3(B), dim3(256), 0, stream>>>(lin, scales, resb);
  }
  k_final<<<dim3(1), dim3(64), 0, stream>>>(resb, (float*)d_out);
}

// Round 6
// 403.879 us; speedup vs baseline: 1.1196x; 1.0648x over previous
//
#include <hip/hip_runtime.h>
#include <hip/hip_bf16.h>

#define V 10000
#define VP 10112
#define C 1024
#define S 128
#define H 256
#define B 16
#define T 128
#define NR 32      // sumexp replicas
#define LDK 40     // padded LDS row length (u16) for k_gemm

typedef unsigned short u16;
typedef unsigned int u32;
typedef __bf16 bf16x8 __attribute__((ext_vector_type(8)));
typedef float f32x4 __attribute__((ext_vector_type(4)));

static __device__ __forceinline__ float bf2f(u16 x){ return __uint_as_float(((u32)x)<<16); }
static __device__ __forceinline__ u16 f2bf(float f){ u32 u=__float_as_uint(f); return (u16)((u + 0x7FFFu + ((u>>16)&1u))>>16); }
static __device__ __forceinline__ u32 fenc(float f){ u32 b=__float_as_uint(f); return (b&0x80000000u)? ~b : (b|0x80000000u); }
static __device__ __forceinline__ float fdec(u32 e){ u32 b=(e&0x80000000u)? (e&0x7FFFFFFFu) : ~e; return __uint_as_float(b); }

// ---------------- zero accumulators ----------------
__global__ void k_zero(float* __restrict__ sumexp, u32* __restrict__ wb, float* __restrict__ res){
  int i = threadIdx.x + blockIdx.x*blockDim.x;
  if (i < C*NR) sumexp[i] = 0.f;
  if (i < 2) wb[i] = 0u;
  if (i < B) res[i] = 0.f;
}

// ---------------- MLP: h2 = relu(relu(x@w1+b1)@w2+b2+x) ----------------
#define RPB 8
__global__ __launch_bounds__(256) void k_mlp(
    const float* __restrict__ x, const float* __restrict__ w1, const float* __restrict__ b1,
    const float* __restrict__ w2, const float* __restrict__ b2,
    float* __restrict__ out_f32, u16* __restrict__ out_bf16, float* __restrict__ rn2){
  __shared__ float xr[RPB][H];
  __shared__ float h1r[RPB][H];
  const int j = threadIdx.x;
  const int r0 = blockIdx.x * RPB;
  #pragma unroll
  for (int r=0;r<RPB;r++) xr[r][j] = x[(size_t)(r0+r)*H + j];
  __syncthreads();
  float acc[RPB];
  {
    float bj = b1[j];
    #pragma unroll
    for (int r=0;r<RPB;r++) acc[r]=bj;
    for (int k=0;k<H;k++){
      float w = w1[(size_t)k*H + j];
      #pragma unroll
      for (int r=0;r<RPB;r++) acc[r] = fmaf(xr[r][k], w, acc[r]);
    }
  }
  #pragma unroll
  for (int r=0;r<RPB;r++) h1r[r][j] = fmaxf(acc[r], 0.f);
  __syncthreads();
  {
    float bj = b2[j];
    #pragma unroll
    for (int r=0;r<RPB;r++) acc[r] = bj + xr[r][j];
    for (int k=0;k<H;k++){
      float w = w2[(size_t)k*H + j];
      #pragma unroll
      for (int r=0;r<RPB;r++) acc[r] = fmaf(h1r[r][k], w, acc[r]);
    }
  }
  #pragma unroll
  for (int r=0;r<RPB;r++){
    float h2 = fmaxf(acc[r], 0.f);
    if (out_f32)  out_f32 [(size_t)(r0+r)*H + j] = h2;
    if (out_bf16) out_bf16[(size_t)(r0+r)*H + j] = f2bf(h2);
    acc[r] = h2*h2;
  }
  if (rn2){
    __syncthreads();
    #pragma unroll
    for (int r=0;r<RPB;r++) xr[r][j] = acc[r];
    __syncthreads();
    for (int off=128; off>=1; off>>=1){
      if (j < off){
        #pragma unroll
        for (int r=0;r<RPB;r++) xr[r][j] += xr[r][j+off];
      }
      __syncthreads();
    }
    if (j==0){
      #pragma unroll
      for (int r=0;r<RPB;r++) rn2[r0+r] = xr[r][0];
    }
  }
}

// ---------------- start head + log_softmax over C ----------------
__global__ __launch_bounds__(1024) void k_start(
    const float* __restrict__ h2, const float* __restrict__ wo, const float* __restrict__ bo,
    float* __restrict__ start_lp){
  const int c = threadIdx.x;
  const int lane = c & 63, wid = c >> 6;
  __shared__ float red[16];
  __shared__ float Ms, Zs;
  float acc = bo[0];
  const float* row = h2 + (size_t)c*H;
  for (int k=0;k<H;k+=4){
    float4 hv = *(const float4*)(row+k);
    float4 wv = *(const float4*)(wo+k);
    acc = fmaf(hv.x,wv.x,acc); acc = fmaf(hv.y,wv.y,acc);
    acc = fmaf(hv.z,wv.z,acc); acc = fmaf(hv.w,wv.w,acc);
  }
  float m = acc;
  for (int o=1;o<64;o<<=1) m = fmaxf(m, __shfl_xor(m,o));
  if (lane==0) red[wid]=m;
  __syncthreads();
  if (c==0){ float t=red[0]; for(int i=1;i<16;i++) t=fmaxf(t,red[i]); Ms=t; }
  __syncthreads();
  float M = Ms;
  float e = expf(acc - M);
  float sum = e;
  for (int o=1;o<64;o<<=1) sum += __shfl_xor(sum,o);
  __syncthreads();
  if (lane==0) red[wid]=sum;
  __syncthreads();
  if (c==0){ float t=0.f; for(int i=0;i<16;i++) t+=red[i]; Zs=t; }
  __syncthreads();
  start_lp[c] = acc - (M + logf(Zs));
}

// ---------------- transpose src (H,N) f32 -> dst (NP,H) bf16, zero-padded ----------------
__global__ __launch_bounds__(256) void k_transpose(const float* __restrict__ src, u16* __restrict__ dst, int N){
  __shared__ float tile[32][33];
  int v0 = blockIdx.x*32, k0 = blockIdx.y*32;
  int tx = threadIdx.x, ty = threadIdx.y; // 32 x 8
  for (int i=0;i<32;i+=8){
    int k = k0+ty+i, v = v0+tx;
    tile[ty+i][tx] = (v < N) ? src[(size_t)k*N + v] : 0.f;
  }
  __syncthreads();
  for (int i=0;i<32;i+=8){
    int v = v0+ty+i, k = k0+tx;
    dst[(size_t)v*H + k] = f2bf(tile[tx][ty+i]);
  }
}

// ---------------- max wotb row norm & max bias ----------------
__global__ __launch_bounds__(256) void k_wnorm(const u16* __restrict__ wotb, const float* __restrict__ bo,
                                               u32* __restrict__ wmax, u32* __restrict__ bmax){
  const int tid = threadIdx.x, lane = tid&63, wid = tid>>6;
  __shared__ float rn[4]; __shared__ float bb[4];
  int v = blockIdx.x*4 + wid;
  float s = 0.f;
  const u16* r = wotb + (size_t)v*H;
  for (int k=lane;k<H;k+=64){ float x=bf2f(r[k]); s = fmaf(x,x,s); }
  for (int o=1;o<64;o<<=1) s += __shfl_xor(s,o);
  if (lane==0) rn[wid] = sqrtf(s);
  int bi = blockIdx.x*256 + tid;
  float bv = (bi < V) ? bo[bi] : -1e30f;
  for (int o=1;o<64;o<<=1) bv = fmaxf(bv, __shfl_xor(bv,o));
  if (lane==0) bb[wid] = bv;
  __syncthreads();
  if (tid==0){
    float nm = fmaxf(fmaxf(rn[0],rn[1]),fmaxf(rn[2],rn[3]));
    float bm = fmaxf(fmaxf(bb[0],bb[1]),fmaxf(bb[2],bb[3]));
    atomicMax(wmax, fenc(nm));
    atomicMax(bmax, fenc(bm));
  }
}

__global__ void k_shift(const float* __restrict__ rn2, const u32* __restrict__ wb, float* __restrict__ shift){
  int c = threadIdx.x + blockIdx.x*blockDim.x;
  if (c < C) shift[c] = sqrtf(rn2[c]) * 1.005f * fdec(wb[0]) + fdec(wb[1]) + 1.0f;
}

// ---------------- generic 128x128-tile MFMA GEMM: out = A(M,H) @ BT(N,H)^T + bias ----------------
// BIAS_ROW=1: bias[r] (guarded r<biasBound); BIAS_ROW=0: bias[col]. FP16OUT: bf16 vs f32.
template<int BIAS_ROW, int BF16OUT>
__global__ __launch_bounds__(256) void k_gemm(
    const u16* __restrict__ A, const u16* __restrict__ BT,
    const float* __restrict__ bias, int biasBound,
    void* __restrict__ outp, int ldout){
  __shared__ u16 As[128*LDK];
  __shared__ u16 Bs[128*LDK];
  const int tid = threadIdx.x;
  const int lane = tid & 63, wave = tid >> 6;
  const int wm = wave >> 1, wn = wave & 1;
  const int m0 = blockIdx.y * 128, n0 = blockIdx.x * 128;
  const int lr = lane & 15, lg = lane >> 4;
  f32x4 acc[4][4] = {};
  const int sr = tid >> 1, sh = (tid & 1) * 16;
  for (int ks = 0; ks < H; ks += 32){
    const u16* ga = A  + (size_t)(m0 + sr)*H + ks + sh;
    const u16* gb = BT + (size_t)(n0 + sr)*H + ks + sh;
    uint4 a0 = *(const uint4*)ga;
    uint4 a1 = *(const uint4*)(ga + 8);
    uint4 b0 = *(const uint4*)gb;
    uint4 b1 = *(const uint4*)(gb + 8);
    __syncthreads();
    *(uint4*)&As[sr*LDK + sh]     = a0;
    *(uint4*)&As[sr*LDK + sh + 8] = a1;
    *(uint4*)&Bs[sr*LDK + sh]     = b0;
    *(uint4*)&Bs[sr*LDK + sh + 8] = b1;
    __syncthreads();
    bf16x8 af[4], bfr[4];
    #pragma unroll
    for (int m=0;m<4;m++) af[m]  = *(const bf16x8*)&As[(wm*64 + m*16 + lr)*LDK + lg*8];
    #pragma unroll
    for (int n=0;n<4;n++) bfr[n] = *(const bf16x8*)&Bs[(wn*64 + n*16 + lr)*LDK + lg*8];
    #pragma unroll
    for (int m=0;m<4;m++)
      #pragma unroll
      for (int n=0;n<4;n++)
        acc[m][n] = __builtin_amdgcn_mfma_f32_16x16x32_bf16(af[m], bfr[n], acc[m][n], 0,0,0);
  }
  #pragma unroll
  for (int m=0;m<4;m++){
    int r_g = m0 + wm*64 + m*16 + lg*4;
    #pragma unroll
    for (int n=0;n<4;n++){
      int n_g = n0 + wn*64 + n*16 + lr;
      float bcol = BIAS_ROW ? 0.f : bias[n_g];
      #pragma unroll
      for (int reg=0; reg<4; reg++){
        int r = r_g + reg;
        float bv = BIAS_ROW ? ((r < biasBound) ? bias[r] : 0.f) : bcol;
        float val = acc[m][n][reg] + bv;
        if (BF16OUT) ((u16*)outp)[(size_t)r*ldout + n_g] = f2bf(val);
        else         ((float*)outp)[(size_t)r*ldout + n_g] = val;
      }
    }
  }
}

// ---------------- row softmax: TL (C,C) f32 -> P (C,C) bf16 ----------------
__global__ __launch_bounds__(256) void k_softmax(const float* __restrict__ TL, u16* __restrict__ P){
  const int c = blockIdx.x;
  const int tid = threadIdx.x, lane = tid & 63, wid = tid >> 6;
  __shared__ float red[4];
  __shared__ float Ms, Zs;
  float4 v = ((const float4*)(TL + (size_t)c*C))[tid];
  float m = fmaxf(fmaxf(v.x,v.y), fmaxf(v.z,v.w));
  for (int o=1;o<64;o<<=1) m = fmaxf(m, __shfl_xor(m,o));
  if (lane==0) red[wid] = m;
  __syncthreads();
  if (tid==0) Ms = fmaxf(fmaxf(red[0],red[1]), fmaxf(red[2],red[3]));
  __syncthreads();
  float M = Ms;
  float e0 = expf(v.x-M), e1 = expf(v.y-M), e2 = expf(v.z-M), e3 = expf(v.w-M);
  float s = (e0+e1)+(e2+e3);
  for (int o=1;o<64;o<<=1) s += __shfl_xor(s,o);
  if (lane==0) red[wid] = s;
  __syncthreads();
  if (tid==0) Zs = red[0]+red[1]+red[2]+red[3];
  __syncthreads();
  float inv = 1.f/Zs;
  u32 lo = (u32)f2bf(e0*inv) | ((u32)f2bf(e1*inv)<<16);
  u32 hi = (u32)f2bf(e2*inv) | ((u32)f2bf(e3*inv)<<16);
  *(uint2*)(P + (size_t)c*C + tid*4) = make_uint2(lo, hi);
}

// ---------------- dedupe + masked LSE partial sums (EM is bf16 [v][c]) ----------------
__global__ __launch_bounds__(128) void k_gather(
    const int* __restrict__ w2s, const u16* __restrict__ EM,
    const float* __restrict__ shift, float* __restrict__ sumexp){
  const int v = blockIdx.x;
  const int s = threadIdx.x;
  __shared__ u32 bm[C/32];
  if (s < C/32) bm[s] = 0u;
  __syncthreads();
  const int c = w2s[(size_t)v*S + s];
  u32 old = atomicOr(&bm[c>>5], 1u<<(c&31));
  const bool first = ((old >> (c&31)) & 1u) == 0u;
  float val = bf2f(EM[(size_t)v*C + c]);
  if (first) atomicAdd(&sumexp[(size_t)(v & (NR-1))*C + c], expf(val - shift[c]));
}

__global__ void k_lse(const float* __restrict__ shift, const float* __restrict__ sumexp, float* __restrict__ lse){
  int c = threadIdx.x + blockIdx.x*blockDim.x;
  if (c < C){
    float s = 0.f;
    for (int r=0;r<NR;r++) s += sumexp[(size_t)r*C + c];
    lse[c] = shift[c] + logf(s);
  }
}

// ---------------- obs[b,t,s] = EM[text,c] - lse[c] ----------------
__global__ __launch_bounds__(128) void k_obs(
    const int* __restrict__ text, const int* __restrict__ w2s,
    const u16* __restrict__ EM, const float* __restrict__ lse,
    float* __restrict__ obs){
  const int bt = blockIdx.x;
  const int s = threadIdx.x;
  const int v = text[bt];
  const int c = w2s[(size_t)v*S + s];
  obs[(size_t)bt*S + s] = bf2f(EM[(size_t)v*C + c]) - lse[c];
}

// ---------------- build level-0 tiles ----------------
// tile_t[sn][sp] = P[cp[sp], cn[sn]] * exp(obs[b,t+1,sn]) * (t==0 ? a0[sp] : 1)
// t==127: identity. t odd -> row-major [sn][sp] (A-role); t even -> transposed (B-role).
__global__ __launch_bounds__(256) void k_pot(
    const int* __restrict__ text, const int* __restrict__ w2s,
    const float* __restrict__ start_lp, const float* __restrict__ obs,
    const u16* __restrict__ P, u16* __restrict__ pot){
  const int t = blockIdx.x;  // 0..127
  const int b = blockIdx.y;
  const int tid = threadIdx.x;
  u16* dst = pot + ((size_t)b*128 + t)*(S*S);
  if (t == 127){
    #pragma unroll
    for (int k=0;k<8;k++){
      int e0 = (k*256 + tid)*8;
      int row = e0>>7, c0 = e0&127;
      union { uint4 w; u16 h[8]; } u;
      u.w = make_uint4(0,0,0,0);
      int d = row - c0;
      if (d >= 0 && d < 8) u.h[d] = 0x3F80u;  // 1.0 bf16
      *(uint4*)(dst + e0) = u.w;
    }
    return;
  }
  __shared__ int cp[S], cn[S];
  __shared__ float eo[S];
  __shared__ float a0[S];
  __shared__ u32 tileW[S*65];          // u16 tile [sn][sp], row stride 130 u16
  u16* tile16 = (u16*)tileW;
  if (tid < 128){
    int cpv = w2s[(size_t)text[b*T + t]*S + tid];
    cp[tid] = cpv;
    a0[tid] = (t==0) ? expf(start_lp[cpv] + obs[(size_t)(b*T)*S + tid]) : 1.0f;
    eo[tid] = expf(obs[((size_t)b*T + t + 1)*S + tid]);
  } else {
    cn[tid-128] = w2s[(size_t)text[b*T + t+1]*S + (tid-128)];
  }
  __syncthreads();
  const int sp_half = tid >> 7;
  const int sn = tid & 127;
  const int cnv = cn[sn];
  const float eov = eo[sn];
  for (int it=0; it<64; ++it){
    int sp = it*2 + sp_half;
    tile16[sn*130 + sp] = f2bf(bf2f(P[(size_t)cp[sp]*C + cnv]) * eov * a0[sp]);
  }
  __syncthreads();
  if (t & 1){
    #pragma unroll
    for (int ii=0; ii<8; ++ii){
      int i0 = (ii*256 + tid)*8;
      int sn2 = i0>>7, sp2 = i0&127;
      const u32* tw = tileW + sn2*65 + (sp2>>1);
      uint4 w4; w4.x = tw[0]; w4.y = tw[1]; w4.z = tw[2]; w4.w = tw[3];
      *(uint4*)(dst + i0) = w4;
    }
  } else {
    #pragma unroll
    for (int ii=0; ii<8; ++ii){
      int i0 = (ii*256 + tid)*8;
      int sp2 = i0>>7, sn0 = i0&127;
      union { uint4 w; u16 h[8]; } u;
      #pragma unroll
      for (int j=0;j<8;j++) u.h[j] = tile16[(sn0+j)*130 + sp2];
      *(uint4*)(dst + i0) = u.w;
    }
  }
}

// ---------------- tree pair-product: out[j] = in[2j+1] . in[2j] ----------------
__global__ __launch_bounds__(256) void k_pair(
    const u16* __restrict__ in, u16* __restrict__ out,
    float* __restrict__ scales, int nin, int soff){
  const int j = blockIdx.x;
  const int b = blockIdx.y;
  const int nout = nin >> 1;
  const u16* Ag = in + ((size_t)b*nin + 2*j+1)*(S*S);
  const u16* Bg = in + ((size_t)b*nin + 2*j  )*(S*S);
  u16* Cg = out + ((size_t)b*nout + j)*(S*S);
  const int tid = threadIdx.x;
  const int lane = tid & 63, wave = tid >> 6;
  const int wm = wave >> 1, wn = wave & 1;
  const int lr = lane & 15, lg = lane >> 4;
  f32x4 acc[4][4] = {};
  #pragma unroll
  for (int kc=0; kc<4; ++kc){
    bf16x8 af[4], bfr[4];
    #pragma unroll
    for (int m=0;m<4;m++) af[m]  = *(const bf16x8*)(Ag + (size_t)(wm*64+m*16+lr)*128 + kc*32 + lg*8);
    #pragma unroll
    for (int n=0;n<4;n++) bfr[n] = *(const bf16x8*)(Bg + (size_t)(wn*64+n*16+lr)*128 + kc*32 + lg*8);
    #pragma unroll
    for (int m=0;m<4;m++)
      #pragma unroll
      for (int n=0;n<4;n++)
        acc[m][n] = __builtin_amdgcn_mfma_f32_16x16x32_bf16(af[m], bfr[n], acc[m][n], 0,0,0);
  }
  __shared__ float red[4];
  float mx = 0.f;
  #pragma unroll
  for (int m=0;m<4;m++)
    #pragma unroll
    for (int n=0;n<4;n++)
      #pragma unroll
      for (int r=0;r<4;r++) mx = fmaxf(mx, acc[m][n][r]);
  for (int o=1;o<64;o<<=1) mx = fmaxf(mx, __shfl_xor(mx,o));
  if (lane==0) red[wave] = mx;
  __syncthreads();
  mx = fmaxf(fmaxf(red[0],red[1]), fmaxf(red[2],red[3]));
  const float sc = 1.0f / mx;
  if (tid==0) scales[(size_t)b*127 + soff + j] = logf(mx);
  if (j & 1){
    #pragma unroll
    for (int m=0;m<4;m++){
      int rg = wm*64 + m*16 + lg*4;
      #pragma unroll
      for (int n=0;n<4;n++){
        int cg = wn*64 + n*16 + lr;
        #pragma unroll
        for (int r=0;r<4;r++) Cg[(size_t)(rg+r)*128 + cg] = f2bf(acc[m][n][r]*sc);
      }
    }
  } else {
    #pragma unroll
    for (int m=0;m<4;m++){
      int rg = wm*64 + m*16 + lg*4;
      #pragma unroll
      for (int n=0;n<4;n++){
        int cg = wn*64 + n*16 + lr;
        float v0=acc[m][n][0]*sc, v1=acc[m][n][1]*sc, v2=acc[m][n][2]*sc, v3=acc[m][n][3]*sc;
        u32 p0, p1;
        asm("v_cvt_pk_bf16_f32 %0, %1, %2" : "=v"(p0) : "v"(v0), "v"(v1));
        asm("v_cvt_pk_bf16_f32 %0, %1, %2" : "=v"(p1) : "v"(v2), "v"(v3));
        *(uint2*)(Cg + (size_t)cg*128 + rg) = make_uint2(p0, p1);
      }
    }
  }
}

// ---------------- final: res[b] = log(sum entries) + sum(scales) ----------------
__global__ __launch_bounds__(256) void k_fin(
    const u16* __restrict__ fin, const float* __restrict__ scales, float* __restrict__ res){
  const int b = blockIdx.x;
  const int tid = threadIdx.x, lane = tid & 63, wid = tid >> 6;
  __shared__ float red[8];
  const u16* p = fin + (size_t)b*(S*S);
  float s = 0.f;
  #pragma unroll
  for (int i=0;i<8;i++){
    uint4 w = *(const uint4*)(p + (i*256+tid)*8);
    s += bf2f((u16)(w.x&0xFFFFu)) + bf2f((u16)(w.x>>16))
       + bf2f((u16)(w.y&0xFFFFu)) + bf2f((u16)(w.y>>16))
       + bf2f((u16)(w.z&0xFFFFu)) + bf2f((u16)(w.z>>16))
       + bf2f((u16)(w.w&0xFFFFu)) + bf2f((u16)(w.w>>16));
  }
  for (int o=1;o<64;o<<=1) s += __shfl_xor(s,o);
  if (lane==0) red[wid] = s;
  float sl = (tid < 127) ? scales[(size_t)b*127 + tid] : 0.f;
  for (int o=1;o<64;o<<=1) sl += __shfl_xor(sl,o);
  if (lane==0) red[4+wid] = sl;
  __syncthreads();
  if (tid==0){
    float tot = red[0]+red[1]+red[2]+red[3];
    float ssum = red[4]+red[5]+red[6]+red[7];
    res[b] = logf(tot) + ssum;
  }
}

__global__ void k_final(const float* __restrict__ res, float* __restrict__ out){
  if (threadIdx.x==0){
    float s = 0.f;
    for (int i=0;i<B;i++) s += res[i];
    out[0] = s;
  }
}

extern "C" void kernel_launch(void* const* d_in, const int* in_sizes, int n_in,
                              void* d_out, int out_size, void* d_ws, size_t ws_size,
                              hipStream_t stream){
  const int*   text      = (const int*)d_in[0];
  const int*   w2s       = (const int*)d_in[1];
  const float* start_emb = (const float*)d_in[2];
  const float* start_w1  = (const float*)d_in[3];
  const float* start_b1  = (const float*)d_in[4];
  const float* start_w2  = (const float*)d_in[5];
  const float* start_b2  = (const float*)d_in[6];
  const float* start_wo  = (const float*)d_in[7];
  const float* start_bo  = (const float*)d_in[8];
  const float* state_emb = (const float*)d_in[9];
  const float* trans_w1  = (const float*)d_in[10];
  const float* trans_b1  = (const float*)d_in[11];
  const float* trans_w2  = (const float*)d_in[12];
  const float* trans_b2  = (const float*)d_in[13];
  const float* trans_wo  = (const float*)d_in[14];
  const float* trans_bo  = (const float*)d_in[15];
  const float* pre_emb   = (const float*)d_in[16];
  const float* term_w1   = (const float*)d_in[17];
  const float* term_b1   = (const float*)d_in[18];
  const float* term_w2   = (const float*)d_in[19];
  const float* term_b2   = (const float*)d_in[20];
  const float* term_wo   = (const float*)d_in[21];
  const float* term_bo   = (const float*)d_in[22];

  char* ws = (char*)d_ws;
  size_t off = 0;
  auto alloc = [&](size_t bytes)->char*{ char* p = ws + off; off += (bytes + 255) & ~(size_t)255; return p; };
  float* h2_start = (float*)alloc(sizeof(float)*(size_t)C*H);
  u16*   h2_transb= (u16*)  alloc(sizeof(u16)*(size_t)C*H);
  u16*   h2_term  = (u16*)  alloc(sizeof(u16)*(size_t)C*H);
  float* rn2      = (float*)alloc(sizeof(float)*C);
  float* start_lp = (float*)alloc(sizeof(float)*C);
  float* shift    = (float*)alloc(sizeof(float)*C);
  float* sumexp   = (float*)alloc(sizeof(float)*(size_t)C*NR);
  float* lse      = (float*)alloc(sizeof(float)*C);
  u32*   wb       = (u32*)  alloc(sizeof(u32)*2);
  float* resb     = (float*)alloc(sizeof(float)*B);
  float* scales   = (float*)alloc(sizeof(float)*(size_t)B*127);
  u16*   P        = (u16*)  alloc(sizeof(u16)*(size_t)C*C);
  u16*   wotb     = (u16*)  alloc(sizeof(u16)*(size_t)VP*H);
  u16*   wottr    = (u16*)  alloc(sizeof(u16)*(size_t)C*H);
  float* obs      = (float*)alloc(sizeof(float)*(size_t)B*T*S);
  u16*   potS     = (u16*)  alloc(sizeof(u16)*(size_t)B*128*S*S);   // level-0 tiles
  u16*   treeA    = (u16*)  alloc(sizeof(u16)*(size_t)B*64*S*S);
  u16*   treeB    = (u16*)  alloc(sizeof(u16)*(size_t)B*32*S*S);
  u16*   EM       = (u16*)potS;    // bf16 EM [VP][C] (20.7MB), dead before k_pot writes potS
  float* TL       = (float*)treeA; // f32 TL [C][C] (4MB), dead before tree level 1 writes treeA
  (void)ws_size; (void)in_sizes; (void)n_in; (void)out_size;

  k_zero<<<dim3((C*NR+255)/256), dim3(256), 0, stream>>>(sumexp, wb, resb);
  k_mlp<<<dim3(C/RPB), dim3(256), 0, stream>>>(start_emb, start_w1, start_b1, start_w2, start_b2, h2_start, (u16*)nullptr, (float*)nullptr);
  k_mlp<<<dim3(C/RPB), dim3(256), 0, stream>>>(state_emb, trans_w1, trans_b1, trans_w2, trans_b2, (float*)nullptr, h2_transb, (float*)nullptr);
  k_mlp<<<dim3(C/RPB), dim3(256), 0, stream>>>(pre_emb, term_w1, term_b1, term_w2, term_b2, (float*)nullptr, h2_term, rn2);
  k_start<<<dim3(1), dim3(1024), 0, stream>>>(h2_start, start_wo, start_bo, start_lp);
  k_transpose<<<dim3(VP/32, H/32), dim3(32,8), 0, stream>>>(term_wo, wotb, V);
  k_transpose<<<dim3(C/32, H/32), dim3(32,8), 0, stream>>>(trans_wo, wottr, C);
  k_wnorm<<<dim3(VP/4), dim3(256), 0, stream>>>(wotb, term_bo, wb, wb+1);
  k_shift<<<dim3((C+255)/256), dim3(256), 0, stream>>>(rn2, wb, shift);
  // transition logits (f32) + row softmax -> P
  k_gemm<0,0><<<dim3(C/128, C/128), dim3(256), 0, stream>>>(h2_transb, wottr, trans_bo, C, TL, C);
  k_softmax<<<dim3(C), dim3(256), 0, stream>>>(TL, P);
  // emission logits EM[v][c] bf16, row bias bo[v]
  k_gemm<1,1><<<dim3(C/128, VP/128), dim3(256), 0, stream>>>(wotb, h2_term, term_bo, V, EM, C);
  k_gather<<<dim3(V), dim3(128), 0, stream>>>(w2s, EM, shift, sumexp);
  k_lse<<<dim3((C+255)/256), dim3(256), 0, stream>>>(shift, sumexp, lse);
  k_obs<<<dim3(B*T), dim3(128), 0, stream>>>(text, w2s, EM, lse, obs);
  k_pot<<<dim3(128, B), dim3(256), 0, stream>>>(text, w2s, start_lp, obs, P, potS);

  // product tree: 128 -> 64 -> 32 -> 16 -> 8 -> 4 -> 2 -> 1
  {
    u16* lin = potS;
    u16* bufs[2] = { treeA, treeB };
    int nin = 128, soff = 0, cur = 0;
    while (nin > 1){
      int nout = nin >> 1;
      k_pair<<<dim3(nout, B), dim3(256), 0, stream>>>(lin, bufs[cur], scales, nin, soff);
      lin = bufs[cur];
      cur ^= 1;
      soff += nout;
      nin = nout;
    }
    k_fin<<<dim3(B), dim3(256), 0, stream>>>(lin, scales, resb);
  }
  k_final<<<dim3(1), dim3(64), 0, stream>>>(resb, (float*)d_out);
}

// Round 7
// 340.100 us; speedup vs baseline: 1.3296x; 1.1875x over previous
//
#include <hip/hip_runtime.h>
#include <hip/hip_bf16.h>

#define V 10000
#define VP 10112
#define C 1024
#define S 128
#define H 256
#define B 16
#define T 128
#define NR 32      // sumexp replicas
#define LDK 40     // padded LDS row length (u16) for k_gemm

typedef unsigned short u16;
typedef unsigned int u32;
typedef __bf16 bf16x8 __attribute__((ext_vector_type(8)));
typedef float f32x4 __attribute__((ext_vector_type(4)));

static __device__ __forceinline__ float bf2f(u16 x){ return __uint_as_float(((u32)x)<<16); }
static __device__ __forceinline__ u16 f2bf(float f){ u32 u=__float_as_uint(f); return (u16)((u + 0x7FFFu + ((u>>16)&1u))>>16); }
static __device__ __forceinline__ u32 fenc(float f){ u32 b=__float_as_uint(f); return (b&0x80000000u)? ~b : (b|0x80000000u); }
static __device__ __forceinline__ float fdec(u32 e){ u32 b=(e&0x80000000u)? (e&0x7FFFFFFFu) : ~e; return __uint_as_float(b); }

// ---------------- zero accumulators ----------------
__global__ void k_zero(float* __restrict__ sumexp, u32* __restrict__ wb, float* __restrict__ res){
  int i = threadIdx.x + blockIdx.x*blockDim.x;
  if (i < C*NR) sumexp[i] = 0.f;
  if (i < 2) wb[i] = 0u;
  if (i < B) res[i] = 0.f;
}

// ---------------- batched f32 -> bf16 convert (3 embeddings, C*H each) ----------------
struct Cvt3 { const float* s0; const float* s1; const float* s2; u16* d0; u16* d1; u16* d2; };
__global__ __launch_bounds__(256) void k_cvt3(Cvt3 a){
  const float* s = (blockIdx.y==0)? a.s0 : (blockIdx.y==1)? a.s1 : a.s2;
  u16* d = (blockIdx.y==0)? a.d0 : (blockIdx.y==1)? a.d1 : a.d2;
  int i = (blockIdx.x*256 + threadIdx.x)*8;
  float4 x0 = *(const float4*)(s+i);
  float4 x1 = *(const float4*)(s+i+4);
  u16 h[8] = {f2bf(x0.x),f2bf(x0.y),f2bf(x0.z),f2bf(x0.w),f2bf(x1.x),f2bf(x1.y),f2bf(x1.z),f2bf(x1.w)};
  *(uint4*)(d+i) = *(uint4*)h;
}

// ---------------- transpose src (H,N) f32 -> dst (NP,H) bf16, zero-padded ----------------
__global__ __launch_bounds__(256) void k_transpose(const float* __restrict__ src, u16* __restrict__ dst, int N){
  __shared__ float tile[32][33];
  int v0 = blockIdx.x*32, k0 = blockIdx.y*32;
  int tx = threadIdx.x, ty = threadIdx.y; // 32 x 8
  for (int i=0;i<32;i+=8){
    int k = k0+ty+i, v = v0+tx;
    tile[ty+i][tx] = (v < N) ? src[(size_t)k*N + v] : 0.f;
  }
  __syncthreads();
  for (int i=0;i<32;i+=8){
    int v = v0+ty+i, k = k0+tx;
    dst[(size_t)v*H + k] = f2bf(tile[tx][ty+i]);
  }
}

// ---------------- batched transpose of six (H,H) f32 weights -> bf16 [j][k] ----------------
struct T6 { const float* s[6]; u16* d[6]; };
__global__ __launch_bounds__(256) void k_transpose6(T6 a){
  const float* src = a.s[blockIdx.z];
  u16* dst = a.d[blockIdx.z];
  __shared__ float tile[32][33];
  int v0 = blockIdx.x*32, k0 = blockIdx.y*32;
  int tx = threadIdx.x, ty = threadIdx.y; // 32 x 8
  for (int i=0;i<32;i+=8){
    int k = k0+ty+i, v = v0+tx;
    tile[ty+i][tx] = src[(size_t)k*H + v];
  }
  __syncthreads();
  for (int i=0;i<32;i+=8){
    int v = v0+ty+i, k = k0+tx;
    dst[(size_t)v*H + k] = f2bf(tile[tx][ty+i]);
  }
}

// ---------------- batched MLP layer (3 MLPs via blockIdx.z), 128x128 MFMA tile ----------------
// out = relu(A @ W^T + bias (+ resid)), all bf16 in/out, f32 accum. A:(C,H), W:(H,H) [j][k].
struct M3 { const u16* A[3]; const u16* W[3]; const float* bias[3]; const u16* R[3]; u16* O[3]; };
template<int RESID>
__global__ __launch_bounds__(256) void k_mlpg(M3 a){
  const int z = blockIdx.z;
  const u16* A  = a.A[z];
  const u16* BT = a.W[z];
  const float* bias = a.bias[z];
  const u16* Rm = a.R[z];
  u16* O = a.O[z];
  __shared__ u16 As[128*LDK];
  __shared__ u16 Bs[128*LDK];
  const int tid = threadIdx.x;
  const int lane = tid & 63, wave = tid >> 6;
  const int wm = wave >> 1, wn = wave & 1;
  const int m0 = blockIdx.y * 128, n0 = blockIdx.x * 128;
  const int lr = lane & 15, lg = lane >> 4;
  f32x4 acc[4][4] = {};
  const int sr = tid >> 1, sh = (tid & 1) * 16;
  for (int ks = 0; ks < H; ks += 32){
    const u16* ga = A  + (size_t)(m0 + sr)*H + ks + sh;
    const u16* gb = BT + (size_t)(n0 + sr)*H + ks + sh;
    uint4 a0 = *(const uint4*)ga;
    uint4 a1 = *(const uint4*)(ga + 8);
    uint4 b0 = *(const uint4*)gb;
    uint4 b1 = *(const uint4*)(gb + 8);
    __syncthreads();
    *(uint4*)&As[sr*LDK + sh]     = a0;
    *(uint4*)&As[sr*LDK + sh + 8] = a1;
    *(uint4*)&Bs[sr*LDK + sh]     = b0;
    *(uint4*)&Bs[sr*LDK + sh + 8] = b1;
    __syncthreads();
    bf16x8 af[4], bfr[4];
    #pragma unroll
    for (int m=0;m<4;m++) af[m]  = *(const bf16x8*)&As[(wm*64 + m*16 + lr)*LDK + lg*8];
    #pragma unroll
    for (int n=0;n<4;n++) bfr[n] = *(const bf16x8*)&Bs[(wn*64 + n*16 + lr)*LDK + lg*8];
    #pragma unroll
    for (int m=0;m<4;m++)
      #pragma unroll
      for (int n=0;n<4;n++)
        acc[m][n] = __builtin_amdgcn_mfma_f32_16x16x32_bf16(af[m], bfr[n], acc[m][n], 0,0,0);
  }
  #pragma unroll
  for (int m=0;m<4;m++){
    int r_g = m0 + wm*64 + m*16 + lg*4;
    #pragma unroll
    for (int n=0;n<4;n++){
      int n_g = n0 + wn*64 + n*16 + lr;
      float bv = bias[n_g];
      #pragma unroll
      for (int reg=0; reg<4; reg++){
        int r = r_g + reg;
        float val = acc[m][n][reg] + bv;
        if (RESID) val += bf2f(Rm[(size_t)r*H + n_g]);
        val = fmaxf(val, 0.f);
        O[(size_t)r*H + n_g] = f2bf(val);
      }
    }
  }
}

// ---------------- start head + log_softmax over C (bf16 h2) ----------------
__global__ __launch_bounds__(1024) void k_start(
    const u16* __restrict__ h2, const float* __restrict__ wo, const float* __restrict__ bo,
    float* __restrict__ start_lp){
  const int c = threadIdx.x;
  const int lane = c & 63, wid = c >> 6;
  __shared__ float red[16];
  __shared__ float Ms, Zs;
  float acc = bo[0];
  const u16* row = h2 + (size_t)c*H;
  for (int k=0;k<H;k+=8){
    uint4 hv = *(const uint4*)(row+k);
    float4 w0 = *(const float4*)(wo+k);
    float4 w1 = *(const float4*)(wo+k+4);
    acc = fmaf(bf2f((u16)(hv.x&0xFFFFu)), w0.x, acc);
    acc = fmaf(bf2f((u16)(hv.x>>16)),     w0.y, acc);
    acc = fmaf(bf2f((u16)(hv.y&0xFFFFu)), w0.z, acc);
    acc = fmaf(bf2f((u16)(hv.y>>16)),     w0.w, acc);
    acc = fmaf(bf2f((u16)(hv.z&0xFFFFu)), w1.x, acc);
    acc = fmaf(bf2f((u16)(hv.z>>16)),     w1.y, acc);
    acc = fmaf(bf2f((u16)(hv.w&0xFFFFu)), w1.z, acc);
    acc = fmaf(bf2f((u16)(hv.w>>16)),     w1.w, acc);
  }
  float m = acc;
  for (int o=1;o<64;o<<=1) m = fmaxf(m, __shfl_xor(m,o));
  if (lane==0) red[wid]=m;
  __syncthreads();
  if (c==0){ float t=red[0]; for(int i=1;i<16;i++) t=fmaxf(t,red[i]); Ms=t; }
  __syncthreads();
  float M = Ms;
  float e = expf(acc - M);
  float sum = e;
  for (int o=1;o<64;o<<=1) sum += __shfl_xor(sum,o);
  __syncthreads();
  if (lane==0) red[wid]=sum;
  __syncthreads();
  if (c==0){ float t=0.f; for(int i=0;i<16;i++) t+=red[i]; Zs=t; }
  __syncthreads();
  start_lp[c] = acc - (M + logf(Zs));
}

// ---------------- max wotb row norm & max bias: 64 blocks, 1 atomic pair per block ----------------
__global__ __launch_bounds__(256) void k_wnorm(const u16* __restrict__ wotb, const float* __restrict__ bo,
                                               u32* __restrict__ wmax, u32* __restrict__ bmax){
  const int tid = threadIdx.x, lane = tid&63, wid = tid>>6;
  __shared__ float rn[4], bb[4];
  float n2max = 0.f;
  for (int v = blockIdx.x*4 + wid; v < VP; v += 64*4){
    const u16* r = wotb + (size_t)v*H;
    float s = 0.f;
    for (int k=lane;k<H;k+=64){ float x=bf2f(r[k]); s = fmaf(x,x,s); }
    for (int o=1;o<64;o<<=1) s += __shfl_xor(s,o);
    n2max = fmaxf(n2max, s);
  }
  int bi = blockIdx.x*256 + tid;
  float bv = (bi < V) ? bo[bi] : -1e30f;
  for (int o=1;o<64;o<<=1) bv = fmaxf(bv, __shfl_xor(bv,o));
  if (lane==0){ rn[wid] = n2max; bb[wid] = bv; }
  __syncthreads();
  if (tid==0){
    float nm = sqrtf(fmaxf(fmaxf(rn[0],rn[1]),fmaxf(rn[2],rn[3])));
    float bm = fmaxf(fmaxf(bb[0],bb[1]),fmaxf(bb[2],bb[3]));
    atomicMax(wmax, fenc(nm));
    atomicMax(bmax, fenc(bm));
  }
}

// ---------------- shift[c] = ||h2_term[c]|| * wmax + bmax + 1 (wave per row, rn2 inline) ----------------
__global__ __launch_bounds__(256) void k_shift(const u16* __restrict__ h2b, const u32* __restrict__ wb,
                                               float* __restrict__ shift){
  const int c = blockIdx.x*4 + (threadIdx.x>>6);
  const int lane = threadIdx.x & 63;
  const u16* r = h2b + (size_t)c*H;
  float s = 0.f;
  for (int k=lane;k<H;k+=64){ float x=bf2f(r[k]); s = fmaf(x,x,s); }
  for (int o=1;o<64;o<<=1) s += __shfl_xor(s,o);
  if (lane==0) shift[c] = sqrtf(s) * fdec(wb[0]) + fdec(wb[1]) + 1.0f;
}

// ---------------- generic 128x128-tile MFMA GEMM: out = A(M,H) @ BT(N,H)^T + bias ----------------
template<int BIAS_ROW, int BF16OUT>
__global__ __launch_bounds__(256) void k_gemm(
    const u16* __restrict__ A, const u16* __restrict__ BT,
    const float* __restrict__ bias, int biasBound,
    void* __restrict__ outp, int ldout){
  __shared__ u16 As[128*LDK];
  __shared__ u16 Bs[128*LDK];
  const int tid = threadIdx.x;
  const int lane = tid & 63, wave = tid >> 6;
  const int wm = wave >> 1, wn = wave & 1;
  const int m0 = blockIdx.y * 128, n0 = blockIdx.x * 128;
  const int lr = lane & 15, lg = lane >> 4;
  f32x4 acc[4][4] = {};
  const int sr = tid >> 1, sh = (tid & 1) * 16;
  for (int ks = 0; ks < H; ks += 32){
    const u16* ga = A  + (size_t)(m0 + sr)*H + ks + sh;
    const u16* gb = BT + (size_t)(n0 + sr)*H + ks + sh;
    uint4 a0 = *(const uint4*)ga;
    uint4 a1 = *(const uint4*)(ga + 8);
    uint4 b0 = *(const uint4*)gb;
    uint4 b1 = *(const uint4*)(gb + 8);
    __syncthreads();
    *(uint4*)&As[sr*LDK + sh]     = a0;
    *(uint4*)&As[sr*LDK + sh + 8] = a1;
    *(uint4*)&Bs[sr*LDK + sh]     = b0;
    *(uint4*)&Bs[sr*LDK + sh + 8] = b1;
    __syncthreads();
    bf16x8 af[4], bfr[4];
    #pragma unroll
    for (int m=0;m<4;m++) af[m]  = *(const bf16x8*)&As[(wm*64 + m*16 + lr)*LDK + lg*8];
    #pragma unroll
    for (int n=0;n<4;n++) bfr[n] = *(const bf16x8*)&Bs[(wn*64 + n*16 + lr)*LDK + lg*8];
    #pragma unroll
    for (int m=0;m<4;m++)
      #pragma unroll
      for (int n=0;n<4;n++)
        acc[m][n] = __builtin_amdgcn_mfma_f32_16x16x32_bf16(af[m], bfr[n], acc[m][n], 0,0,0);
  }
  #pragma unroll
  for (int m=0;m<4;m++){
    int r_g = m0 + wm*64 + m*16 + lg*4;
    #pragma unroll
    for (int n=0;n<4;n++){
      int n_g = n0 + wn*64 + n*16 + lr;
      float bcol = BIAS_ROW ? 0.f : bias[n_g];
      #pragma unroll
      for (int reg=0; reg<4; reg++){
        int r = r_g + reg;
        float bv = BIAS_ROW ? ((r < biasBound) ? bias[r] : 0.f) : bcol;
        float val = acc[m][n][reg] + bv;
        if (BF16OUT) ((u16*)outp)[(size_t)r*ldout + n_g] = f2bf(val);
        else         ((float*)outp)[(size_t)r*ldout + n_g] = val;
      }
    }
  }
}

// ---------------- row softmax: TL (C,C) f32 -> P (C,C) bf16 ----------------
__global__ __launch_bounds__(256) void k_softmax(const float* __restrict__ TL, u16* __restrict__ P){
  const int c = blockIdx.x;
  const int tid = threadIdx.x, lane = tid & 63, wid = tid >> 6;
  __shared__ float red[4];
  __shared__ float Ms, Zs;
  float4 v = ((const float4*)(TL + (size_t)c*C))[tid];
  float m = fmaxf(fmaxf(v.x,v.y), fmaxf(v.z,v.w));
  for (int o=1;o<64;o<<=1) m = fmaxf(m, __shfl_xor(m,o));
  if (lane==0) red[wid] = m;
  __syncthreads();
  if (tid==0) Ms = fmaxf(fmaxf(red[0],red[1]), fmaxf(red[2],red[3]));
  __syncthreads();
  float M = Ms;
  float e0 = expf(v.x-M), e1 = expf(v.y-M), e2 = expf(v.z-M), e3 = expf(v.w-M);
  float s = (e0+e1)+(e2+e3);
  for (int o=1;o<64;o<<=1) s += __shfl_xor(s,o);
  if (lane==0) red[wid] = s;
  __syncthreads();
  if (tid==0) Zs = red[0]+red[1]+red[2]+red[3];
  __syncthreads();
  float inv = 1.f/Zs;
  u32 lo = (u32)f2bf(e0*inv) | ((u32)f2bf(e1*inv)<<16);
  u32 hi = (u32)f2bf(e2*inv) | ((u32)f2bf(e3*inv)<<16);
  *(uint2*)(P + (size_t)c*C + tid*4) = make_uint2(lo, hi);
}

// ---------------- dedupe + masked LSE partial sums (EM is bf16 [v][c]) ----------------
__global__ __launch_bounds__(128) void k_gather(
    const int* __restrict__ w2s, const u16* __restrict__ EM,
    const float* __restrict__ shift, float* __restrict__ sumexp){
  const int v = blockIdx.x;
  const int s = threadIdx.x;
  __shared__ u32 bm[C/32];
  if (s < C/32) bm[s] = 0u;
  __syncthreads();
  const int c = w2s[(size_t)v*S + s];
  u32 old = atomicOr(&bm[c>>5], 1u<<(c&31));
  const bool first = ((old >> (c&31)) & 1u) == 0u;
  float val = bf2f(EM[(size_t)v*C + c]);
  if (first) atomicAdd(&sumexp[(size_t)(v & (NR-1))*C + c], expf(val - shift[c]));
}

__global__ void k_lse(const float* __restrict__ shift, const float* __restrict__ sumexp, float* __restrict__ lse){
  int c = threadIdx.x + blockIdx.x*blockDim.x;
  if (c < C){
    float s = 0.f;
    for (int r=0;r<NR;r++) s += sumexp[(size_t)r*C + c];
    lse[c] = shift[c] + logf(s);
  }
}

// ---------------- obs[b,t,s] = EM[text,c] - lse[c] ----------------
__global__ __launch_bounds__(128) void k_obs(
    const int* __restrict__ text, const int* __restrict__ w2s,
    const u16* __restrict__ EM, const float* __restrict__ lse,
    float* __restrict__ obs){
  const int bt = blockIdx.x;
  const int s = threadIdx.x;
  const int v = text[bt];
  const int c = w2s[(size_t)v*S + s];
  obs[(size_t)bt*S + s] = bf2f(EM[(size_t)v*C + c]) - lse[c];
}

// ---------------- build level-0 tiles ----------------
__global__ __launch_bounds__(256) void k_pot(
    const int* __restrict__ text, const int* __restrict__ w2s,
    const float* __restrict__ start_lp, const float* __restrict__ obs,
    const u16* __restrict__ P, u16* __restrict__ pot){
  const int t = blockIdx.x;  // 0..127
  const int b = blockIdx.y;
  const int tid = threadIdx.x;
  u16* dst = pot + ((size_t)b*128 + t)*(S*S);
  if (t == 127){
    #pragma unroll
    for (int k=0;k<8;k++){
      int e0 = (k*256 + tid)*8;
      int row = e0>>7, c0 = e0&127;
      union { uint4 w; u16 h[8]; } u;
      u.w = make_uint4(0,0,0,0);
      int d = row - c0;
      if (d >= 0 && d < 8) u.h[d] = 0x3F80u;  // 1.0 bf16
      *(uint4*)(dst + e0) = u.w;
    }
    return;
  }
  __shared__ int cp[S], cn[S];
  __shared__ float eo[S];
  __shared__ float a0[S];
  __shared__ u32 tileW[S*65];          // u16 tile [sn][sp], row stride 130 u16
  u16* tile16 = (u16*)tileW;
  if (tid < 128){
    int cpv = w2s[(size_t)text[b*T + t]*S + tid];
    cp[tid] = cpv;
    a0[tid] = (t==0) ? expf(start_lp[cpv] + obs[(size_t)(b*T)*S + tid]) : 1.0f;
    eo[tid] = expf(obs[((size_t)b*T + t + 1)*S + tid]);
  } else {
    cn[tid-128] = w2s[(size_t)text[b*T + t+1]*S + (tid-128)];
  }
  __syncthreads();
  const int sp_half = tid >> 7;
  const int sn = tid & 127;
  const int cnv = cn[sn];
  const float eov = eo[sn];
  for (int it=0; it<64; ++it){
    int sp = it*2 + sp_half;
    tile16[sn*130 + sp] = f2bf(bf2f(P[(size_t)cp[sp]*C + cnv]) * eov * a0[sp]);
  }
  __syncthreads();
  if (t & 1){
    #pragma unroll
    for (int ii=0; ii<8; ++ii){
      int i0 = (ii*256 + tid)*8;
      int sn2 = i0>>7, sp2 = i0&127;
      const u32* tw = tileW + sn2*65 + (sp2>>1);
      uint4 w4; w4.x = tw[0]; w4.y = tw[1]; w4.z = tw[2]; w4.w = tw[3];
      *(uint4*)(dst + i0) = w4;
    }
  } else {
    #pragma unroll
    for (int ii=0; ii<8; ++ii){
      int i0 = (ii*256 + tid)*8;
      int sp2 = i0>>7, sn0 = i0&127;
      union { uint4 w; u16 h[8]; } u;
      #pragma unroll
      for (int j=0;j<8;j++) u.h[j] = tile16[(sn0+j)*130 + sp2];
      *(uint4*)(dst + i0) = u.w;
    }
  }
}

// ---------------- tree pair-product: out[j] = in[2j+1] . in[2j] ----------------
__global__ __launch_bounds__(256) void k_pair(
    const u16* __restrict__ in, u16* __restrict__ out,
    float* __restrict__ scales, int nin, int soff){
  const int j = blockIdx.x;
  const int b = blockIdx.y;
  const int nout = nin >> 1;
  const u16* Ag = in + ((size_t)b*nin + 2*j+1)*(S*S);
  const u16* Bg = in + ((size_t)b*nin + 2*j  )*(S*S);
  u16* Cg = out + ((size_t)b*nout + j)*(S*S);
  const int tid = threadIdx.x;
  const int lane = tid & 63, wave = tid >> 6;
  const int wm = wave >> 1, wn = wave & 1;
  const int lr = lane & 15, lg = lane >> 4;
  f32x4 acc[4][4] = {};
  #pragma unroll
  for (int kc=0; kc<4; ++kc){
    bf16x8 af[4], bfr[4];
    #pragma unroll
    for (int m=0;m<4;m++) af[m]  = *(const bf16x8*)(Ag + (size_t)(wm*64+m*16+lr)*128 + kc*32 + lg*8);
    #pragma unroll
    for (int n=0;n<4;n++) bfr[n] = *(const bf16x8*)(Bg + (size_t)(wn*64+n*16+lr)*128 + kc*32 + lg*8);
    #pragma unroll
    for (int m=0;m<4;m++)
      #pragma unroll
      for (int n=0;n<4;n++)
        acc[m][n] = __builtin_amdgcn_mfma_f32_16x16x32_bf16(af[m], bfr[n], acc[m][n], 0,0,0);
  }
  __shared__ float red[4];
  float mx = 0.f;
  #pragma unroll
  for (int m=0;m<4;m++)
    #pragma unroll
    for (int n=0;n<4;n++)
      #pragma unroll
      for (int r=0;r<4;r++) mx = fmaxf(mx, acc[m][n][r]);
  for (int o=1;o<64;o<<=1) mx = fmaxf(mx, __shfl_xor(mx,o));
  if (lane==0) red[wave] = mx;
  __syncthreads();
  mx = fmaxf(fmaxf(red[0],red[1]), fmaxf(red[2],red[3]));
  const float sc = 1.0f / mx;
  if (tid==0) scales[(size_t)b*127 + soff + j] = logf(mx);
  if (j & 1){
    #pragma unroll
    for (int m=0;m<4;m++){
      int rg = wm*64 + m*16 + lg*4;
      #pragma unroll
      for (int n=0;n<4;n++){
        int cg = wn*64 + n*16 + lr;
        #pragma unroll
        for (int r=0;r<4;r++) Cg[(size_t)(rg+r)*128 + cg] = f2bf(acc[m][n][r]*sc);
      }
    }
  } else {
    #pragma unroll
    for (int m=0;m<4;m++){
      int rg = wm*64 + m*16 + lg*4;
      #pragma unroll
      for (int n=0;n<4;n++){
        int cg = wn*64 + n*16 + lr;
        float v0=acc[m][n][0]*sc, v1=acc[m][n][1]*sc, v2=acc[m][n][2]*sc, v3=acc[m][n][3]*sc;
        u32 p0, p1;
        asm("v_cvt_pk_bf16_f32 %0, %1, %2" : "=v"(p0) : "v"(v0), "v"(v1));
        asm("v_cvt_pk_bf16_f32 %0, %1, %2" : "=v"(p1) : "v"(v2), "v"(v3));
        *(uint2*)(Cg + (size_t)cg*128 + rg) = make_uint2(p0, p1);
      }
    }
  }
}

// ---------------- final: res[b] = log(sum entries) + sum(scales) ----------------
__global__ __launch_bounds__(256) void k_fin(
    const u16* __restrict__ fin, const float* __restrict__ scales, float* __restrict__ res){
  const int b = blockIdx.x;
  const int tid = threadIdx.x, lane = tid & 63, wid = tid >> 6;
  __shared__ float red[8];
  const u16* p = fin + (size_t)b*(S*S);
  float s = 0.f;
  #pragma unroll
  for (int i=0;i<8;i++){
    uint4 w = *(const uint4*)(p + (i*256+tid)*8);
    s += bf2f((u16)(w.x&0xFFFFu)) + bf2f((u16)(w.x>>16))
       + bf2f((u16)(w.y&0xFFFFu)) + bf2f((u16)(w.y>>16))
       + bf2f((u16)(w.z&0xFFFFu)) + bf2f((u16)(w.z>>16))
       + bf2f((u16)(w.w&0xFFFFu)) + bf2f((u16)(w.w>>16));
  }
  for (int o=1;o<64;o<<=1) s += __shfl_xor(s,o);
  if (lane==0) red[wid] = s;
  float sl = (tid < 127) ? scales[(size_t)b*127 + tid] : 0.f;
  for (int o=1;o<64;o<<=1) sl += __shfl_xor(sl,o);
  if (lane==0) red[4+wid] = sl;
  __syncthreads();
  if (tid==0){
    float tot = red[0]+red[1]+red[2]+red[3];
    float ssum = red[4]+red[5]+red[6]+red[7];
    res[b] = logf(tot) + ssum;
  }
}

__global__ void k_final(const float* __restrict__ res, float* __restrict__ out){
  if (threadIdx.x==0){
    float s = 0.f;
    for (int i=0;i<B;i++) s += res[i];
    out[0] = s;
  }
}

extern "C" void kernel_launch(void* const* d_in, const int* in_sizes, int n_in,
                              void* d_out, int out_size, void* d_ws, size_t ws_size,
                              hipStream_t stream){
  const int*   text      = (const int*)d_in[0];
  const int*   w2s       = (const int*)d_in[1];
  const float* start_emb = (const float*)d_in[2];
  const float* start_w1  = (const float*)d_in[3];
  const float* start_b1  = (const float*)d_in[4];
  const float* start_w2  = (const float*)d_in[5];
  const float* start_b2  = (const float*)d_in[6];
  const float* start_wo  = (const float*)d_in[7];
  const float* start_bo  = (const float*)d_in[8];
  const float* state_emb = (const float*)d_in[9];
  const float* trans_w1  = (const float*)d_in[10];
  const float* trans_b1  = (const float*)d_in[11];
  const float* trans_w2  = (const float*)d_in[12];
  const float* trans_b2  = (const float*)d_in[13];
  const float* trans_wo  = (const float*)d_in[14];
  const float* trans_bo  = (const float*)d_in[15];
  const float* pre_emb   = (const float*)d_in[16];
  const float* term_w1   = (const float*)d_in[17];
  const float* term_b1   = (const float*)d_in[18];
  const float* term_w2   = (const float*)d_in[19];
  const float* term_b2   = (const float*)d_in[20];
  const float* term_wo   = (const float*)d_in[21];
  const float* term_bo   = (const float*)d_in[22];

  char* ws = (char*)d_ws;
  size_t off = 0;
  auto alloc = [&](size_t bytes)->char*{ char* p = ws + off; off += (bytes + 255) & ~(size_t)255; return p; };
  u16*   embb     = (u16*)  alloc(sizeof(u16)*3*(size_t)C*H);
  u16*   h1b      = (u16*)  alloc(sizeof(u16)*3*(size_t)C*H);
  u16*   h2b      = (u16*)  alloc(sizeof(u16)*3*(size_t)C*H);
  u16*   wt       = (u16*)  alloc(sizeof(u16)*6*(size_t)H*H);
  float* start_lp = (float*)alloc(sizeof(float)*C);
  float* shift    = (float*)alloc(sizeof(float)*C);
  float* sumexp   = (float*)alloc(sizeof(float)*(size_t)C*NR);
  float* lse      = (float*)alloc(sizeof(float)*C);
  u32*   wb       = (u32*)  alloc(sizeof(u32)*2);
  float* resb     = (float*)alloc(sizeof(float)*B);
  float* scales   = (float*)alloc(sizeof(float)*(size_t)B*127);
  u16*   P        = (u16*)  alloc(sizeof(u16)*(size_t)C*C);
  u16*   wotb     = (u16*)  alloc(sizeof(u16)*(size_t)VP*H);
  u16*   wottr    = (u16*)  alloc(sizeof(u16)*(size_t)C*H);
  float* obs      = (float*)alloc(sizeof(float)*(size_t)B*T*S);
  u16*   potS     = (u16*)  alloc(sizeof(u16)*(size_t)B*128*S*S);   // level-0 tiles
  u16*   treeA    = (u16*)  alloc(sizeof(u16)*(size_t)B*64*S*S);
  u16*   treeB    = (u16*)  alloc(sizeof(u16)*(size_t)B*32*S*S);
  u16*   EM       = (u16*)potS;    // bf16 EM [VP][C], dead before k_pot writes potS
  float* TL       = (float*)treeA; // f32 TL [C][C], dead before tree level 1 writes treeA
  (void)ws_size; (void)in_sizes; (void)n_in; (void)out_size;

  u16* embb0 = embb, *embb1 = embb + (size_t)C*H, *embb2 = embb + 2*(size_t)C*H;
  u16* h1b0 = h1b, *h1b1 = h1b + (size_t)C*H, *h1b2 = h1b + 2*(size_t)C*H;
  u16* h2b0 = h2b, *h2b1 = h2b + (size_t)C*H, *h2b2 = h2b + 2*(size_t)C*H;

  k_zero<<<dim3((C*NR+255)/256), dim3(256), 0, stream>>>(sumexp, wb, resb);

  Cvt3 cv; cv.s0 = start_emb; cv.s1 = state_emb; cv.s2 = pre_emb;
  cv.d0 = embb0; cv.d1 = embb1; cv.d2 = embb2;
  k_cvt3<<<dim3(C*H/(256*8), 3), dim3(256), 0, stream>>>(cv);

  T6 t6;
  t6.s[0]=start_w1; t6.s[1]=start_w2; t6.s[2]=trans_w1; t6.s[3]=trans_w2; t6.s[4]=term_w1; t6.s[5]=term_w2;
  for (int i=0;i<6;i++) t6.d[i] = wt + (size_t)i*H*H;
  k_transpose6<<<dim3(H/32, H/32, 6), dim3(32,8), 0, stream>>>(t6);

  M3 l1;
  l1.A[0]=embb0; l1.A[1]=embb1; l1.A[2]=embb2;
  l1.W[0]=wt;    l1.W[1]=wt+2*(size_t)H*H; l1.W[2]=wt+4*(size_t)H*H;
  l1.bias[0]=start_b1; l1.bias[1]=trans_b1; l1.bias[2]=term_b1;
  l1.R[0]=l1.R[1]=l1.R[2]=nullptr;
  l1.O[0]=h1b0; l1.O[1]=h1b1; l1.O[2]=h1b2;
  k_mlpg<0><<<dim3(H/128, C/128, 3), dim3(256), 0, stream>>>(l1);

  M3 l2;
  l2.A[0]=h1b0; l2.A[1]=h1b1; l2.A[2]=h1b2;
  l2.W[0]=wt+(size_t)H*H; l2.W[1]=wt+3*(size_t)H*H; l2.W[2]=wt+5*(size_t)H*H;
  l2.bias[0]=start_b2; l2.bias[1]=trans_b2; l2.bias[2]=term_b2;
  l2.R[0]=embb0; l2.R[1]=embb1; l2.R[2]=embb2;
  l2.O[0]=h2b0; l2.O[1]=h2b1; l2.O[2]=h2b2;
  k_mlpg<1><<<dim3(H/128, C/128, 3), dim3(256), 0, stream>>>(l2);

  k_start<<<dim3(1), dim3(1024), 0, stream>>>(h2b0, start_wo, start_bo, start_lp);
  k_transpose<<<dim3(VP/32, H/32), dim3(32,8), 0, stream>>>(term_wo, wotb, V);
  k_transpose<<<dim3(C/32, H/32), dim3(32,8), 0, stream>>>(trans_wo, wottr, C);
  k_wnorm<<<dim3(64), dim3(256), 0, stream>>>(wotb, term_bo, wb, wb+1);
  k_shift<<<dim3(C/4), dim3(256), 0, stream>>>(h2b2, wb, shift);
  // transition logits (f32) + row softmax -> P
  k_gemm<0,0><<<dim3(C/128, C/128), dim3(256), 0, stream>>>(h2b1, wottr, trans_bo, C, TL, C);
  k_softmax<<<dim3(C), dim3(256), 0, stream>>>(TL, P);
  // emission logits EM[v][c] bf16, row bias bo[v]
  k_gemm<1,1><<<dim3(C/128, VP/128), dim3(256), 0, stream>>>(wotb, h2b2, term_bo, V, EM, C);
  k_gather<<<dim3(V), dim3(128), 0, stream>>>(w2s, EM, shift, sumexp);
  k_lse<<<dim3((C+255)/256), dim3(256), 0, stream>>>(shift, sumexp, lse);
  k_obs<<<dim3(B*T), dim3(128), 0, stream>>>(text, w2s, EM, lse, obs);
  k_pot<<<dim3(128, B), dim3(256), 0, stream>>>(text, w2s, start_lp, obs, P, potS);

  // product tree: 128 -> 64 -> 32 -> 16 -> 8 -> 4 -> 2 -> 1
  {
    u16* lin = potS;
    u16* bufs[2] = { treeA, treeB };
    int nin = 128, soff = 0, cur = 0;
    while (nin > 1){
      int nout = nin >> 1;
      k_pair<<<dim3(nout, B), dim3(256), 0, stream>>>(lin, bufs[cur], scales, nin, soff);
      lin = bufs[cur];
      cur ^= 1;
      soff += nout;
      nin = nout;
    }
    k_fin<<<dim3(B), dim3(256), 0, stream>>>(lin, scales, resb);
  }
  k_final<<<dim3(1), dim3(64), 0, stream>>>(resb, (float*)d_out);
}

// Round 8
// 318.765 us; speedup vs baseline: 1.4186x; 1.0669x over previous
//
#include <hip/hip_runtime.h>
#include <hip/hip_bf16.h>

#define V 10000
#define VP 10112
#define C 1024
#define S 128
#define H 256
#define B 16
#define T 128
#define NR 64      // colsum row-chunks (replicas)
#define CHUNK 158  // VP / NR
#define LDK 40     // padded LDS row length (u16) for k_gemm

typedef unsigned short u16;
typedef unsigned int u32;
typedef __bf16 bf16x8 __attribute__((ext_vector_type(8)));
typedef float f32x4 __attribute__((ext_vector_type(4)));

static __device__ __forceinline__ float bf2f(u16 x){ return __uint_as_float(((u32)x)<<16); }
static __device__ __forceinline__ u16 f2bf(float f){ u32 u=__float_as_uint(f); return (u16)((u + 0x7FFFu + ((u>>16)&1u))>>16); }
static __device__ __forceinline__ u32 fenc(float f){ u32 b=__float_as_uint(f); return (b&0x80000000u)? ~b : (b|0x80000000u); }
static __device__ __forceinline__ float fdec(u32 e){ u32 b=(e&0x80000000u)? (e&0x7FFFFFFFu) : ~e; return __uint_as_float(b); }

// ---------------- zero small accumulators ----------------
__global__ void k_zero(u32* __restrict__ wb, float* __restrict__ res){
  int i = threadIdx.x;
  if (i < 2) wb[i] = 0u;
  if (i < B) res[i] = 0.f;
}

// ---------------- batched f32 -> bf16 convert (3 embeddings, C*H each) ----------------
struct Cvt3 { const float* s0; const float* s1; const float* s2; u16* d0; u16* d1; u16* d2; };
__global__ __launch_bounds__(256) void k_cvt3(Cvt3 a){
  const float* s = (blockIdx.y==0)? a.s0 : (blockIdx.y==1)? a.s1 : a.s2;
  u16* d = (blockIdx.y==0)? a.d0 : (blockIdx.y==1)? a.d1 : a.d2;
  int i = (blockIdx.x*256 + threadIdx.x)*8;
  float4 x0 = *(const float4*)(s+i);
  float4 x1 = *(const float4*)(s+i+4);
  u16 h[8] = {f2bf(x0.x),f2bf(x0.y),f2bf(x0.z),f2bf(x0.w),f2bf(x1.x),f2bf(x1.y),f2bf(x1.z),f2bf(x1.w)};
  *(uint4*)(d+i) = *(uint4*)h;
}

// ---------------- transpose src (H,N) f32 -> dst (NP,H) bf16, zero-padded ----------------
__global__ __launch_bounds__(256) void k_transpose(const float* __restrict__ src, u16* __restrict__ dst, int N){
  __shared__ float tile[32][33];
  int v0 = blockIdx.x*32, k0 = blockIdx.y*32;
  int tx = threadIdx.x, ty = threadIdx.y; // 32 x 8
  for (int i=0;i<32;i+=8){
    int k = k0+ty+i, v = v0+tx;
    tile[ty+i][tx] = (v < N) ? src[(size_t)k*N + v] : 0.f;
  }
  __syncthreads();
  for (int i=0;i<32;i+=8){
    int v = v0+ty+i, k = k0+tx;
    dst[(size_t)v*H + k] = f2bf(tile[tx][ty+i]);
  }
}

// ---------------- batched transpose of six (H,H) f32 weights -> bf16 [j][k] ----------------
struct T6 { const float* s[6]; u16* d[6]; };
__global__ __launch_bounds__(256) void k_transpose6(T6 a){
  const float* src = a.s[blockIdx.z];
  u16* dst = a.d[blockIdx.z];
  __shared__ float tile[32][33];
  int v0 = blockIdx.x*32, k0 = blockIdx.y*32;
  int tx = threadIdx.x, ty = threadIdx.y; // 32 x 8
  for (int i=0;i<32;i+=8){
    int k = k0+ty+i, v = v0+tx;
    tile[ty+i][tx] = src[(size_t)k*H + v];
  }
  __syncthreads();
  for (int i=0;i<32;i+=8){
    int v = v0+ty+i, k = k0+tx;
    dst[(size_t)v*H + k] = f2bf(tile[tx][ty+i]);
  }
}

// ---------------- batched MLP layer (3 MLPs via blockIdx.z), 128x128 MFMA tile ----------------
struct M3 { const u16* A[3]; const u16* W[3]; const float* bias[3]; const u16* R[3]; u16* O[3]; };
template<int RESID>
__global__ __launch_bounds__(256) void k_mlpg(M3 a){
  const int z = blockIdx.z;
  const u16* A  = a.A[z];
  const u16* BT = a.W[z];
  const float* bias = a.bias[z];
  const u16* Rm = a.R[z];
  u16* O = a.O[z];
  __shared__ u16 As[128*LDK];
  __shared__ u16 Bs[128*LDK];
  const int tid = threadIdx.x;
  const int lane = tid & 63, wave = tid >> 6;
  const int wm = wave >> 1, wn = wave & 1;
  const int m0 = blockIdx.y * 128, n0 = blockIdx.x * 128;
  const int lr = lane & 15, lg = lane >> 4;
  f32x4 acc[4][4] = {};
  const int sr = tid >> 1, sh = (tid & 1) * 16;
  for (int ks = 0; ks < H; ks += 32){
    const u16* ga = A  + (size_t)(m0 + sr)*H + ks + sh;
    const u16* gb = BT + (size_t)(n0 + sr)*H + ks + sh;
    uint4 a0 = *(const uint4*)ga;
    uint4 a1 = *(const uint4*)(ga + 8);
    uint4 b0 = *(const uint4*)gb;
    uint4 b1 = *(const uint4*)(gb + 8);
    __syncthreads();
    *(uint4*)&As[sr*LDK + sh]     = a0;
    *(uint4*)&As[sr*LDK + sh + 8] = a1;
    *(uint4*)&Bs[sr*LDK + sh]     = b0;
    *(uint4*)&Bs[sr*LDK + sh + 8] = b1;
    __syncthreads();
    bf16x8 af[4], bfr[4];
    #pragma unroll
    for (int m=0;m<4;m++) af[m]  = *(const bf16x8*)&As[(wm*64 + m*16 + lr)*LDK + lg*8];
    #pragma unroll
    for (int n=0;n<4;n++) bfr[n] = *(const bf16x8*)&Bs[(wn*64 + n*16 + lr)*LDK + lg*8];
    #pragma unroll
    for (int m=0;m<4;m++)
      #pragma unroll
      for (int n=0;n<4;n++)
        acc[m][n] = __builtin_amdgcn_mfma_f32_16x16x32_bf16(af[m], bfr[n], acc[m][n], 0,0,0);
  }
  #pragma unroll
  for (int m=0;m<4;m++){
    int r_g = m0 + wm*64 + m*16 + lg*4;
    #pragma unroll
    for (int n=0;n<4;n++){
      int n_g = n0 + wn*64 + n*16 + lr;
      float bv = bias[n_g];
      #pragma unroll
      for (int reg=0; reg<4; reg++){
        int r = r_g + reg;
        float val = acc[m][n][reg] + bv;
        if (RESID) val += bf2f(Rm[(size_t)r*H + n_g]);
        val = fmaxf(val, 0.f);
        O[(size_t)r*H + n_g] = f2bf(val);
      }
    }
  }
}

// ---------------- start head + log_softmax over C (bf16 h2) ----------------
__global__ __launch_bounds__(1024) void k_start(
    const u16* __restrict__ h2, const float* __restrict__ wo, const float* __restrict__ bo,
    float* __restrict__ start_lp){
  const int c = threadIdx.x;
  const int lane = c & 63, wid = c >> 6;
  __shared__ float red[16];
  __shared__ float Ms, Zs;
  float acc = bo[0];
  const u16* row = h2 + (size_t)c*H;
  for (int k=0;k<H;k+=8){
    uint4 hv = *(const uint4*)(row+k);
    float4 w0 = *(const float4*)(wo+k);
    float4 w1 = *(const float4*)(wo+k+4);
    acc = fmaf(bf2f((u16)(hv.x&0xFFFFu)), w0.x, acc);
    acc = fmaf(bf2f((u16)(hv.x>>16)),     w0.y, acc);
    acc = fmaf(bf2f((u16)(hv.y&0xFFFFu)), w0.z, acc);
    acc = fmaf(bf2f((u16)(hv.y>>16)),     w0.w, acc);
    acc = fmaf(bf2f((u16)(hv.z&0xFFFFu)), w1.x, acc);
    acc = fmaf(bf2f((u16)(hv.z>>16)),     w1.y, acc);
    acc = fmaf(bf2f((u16)(hv.w&0xFFFFu)), w1.z, acc);
    acc = fmaf(bf2f((u16)(hv.w>>16)),     w1.w, acc);
  }
  float m = acc;
  for (int o=1;o<64;o<<=1) m = fmaxf(m, __shfl_xor(m,o));
  if (lane==0) red[wid]=m;
  __syncthreads();
  if (c==0){ float t=red[0]; for(int i=1;i<16;i++) t=fmaxf(t,red[i]); Ms=t; }
  __syncthreads();
  float M = Ms;
  float e = expf(acc - M);
  float sum = e;
  for (int o=1;o<64;o<<=1) sum += __shfl_xor(sum,o);
  __syncthreads();
  if (lane==0) red[wid]=sum;
  __syncthreads();
  if (c==0){ float t=0.f; for(int i=0;i<16;i++) t+=red[i]; Zs=t; }
  __syncthreads();
  start_lp[c] = acc - (M + logf(Zs));
}

// ---------------- max wotb row norm & max bias: 64 blocks, 1 atomic pair per block ----------------
__global__ __launch_bounds__(256) void k_wnorm(const u16* __restrict__ wotb, const float* __restrict__ bo,
                                               u32* __restrict__ wmax, u32* __restrict__ bmax){
  const int tid = threadIdx.x, lane = tid&63, wid = tid>>6;
  __shared__ float rn[4], bb[4];
  float n2max = 0.f;
  for (int v = blockIdx.x*4 + wid; v < VP; v += 64*4){
    const u16* r = wotb + (size_t)v*H;
    float s = 0.f;
    for (int k=lane;k<H;k+=64){ float x=bf2f(r[k]); s = fmaf(x,x,s); }
    for (int o=1;o<64;o<<=1) s += __shfl_xor(s,o);
    n2max = fmaxf(n2max, s);
  }
  int bi = blockIdx.x*256 + tid;
  float bv = (bi < V) ? bo[bi] : -1e30f;
  for (int o=1;o<64;o<<=1) bv = fmaxf(bv, __shfl_xor(bv,o));
  if (lane==0){ rn[wid] = n2max; bb[wid] = bv; }
  __syncthreads();
  if (tid==0){
    float nm = sqrtf(fmaxf(fmaxf(rn[0],rn[1]),fmaxf(rn[2],rn[3])));
    float bm = fmaxf(fmaxf(bb[0],bb[1]),fmaxf(bb[2],bb[3]));
    atomicMax(wmax, fenc(nm));
    atomicMax(bmax, fenc(bm));
  }
}

// ---------------- shift[c] = ||h2_term[c]|| * wmax + bmax + 1 ----------------
__global__ __launch_bounds__(256) void k_shift(const u16* __restrict__ h2b, const u32* __restrict__ wb,
                                               float* __restrict__ shift){
  const int c = blockIdx.x*4 + (threadIdx.x>>6);
  const int lane = threadIdx.x & 63;
  const u16* r = h2b + (size_t)c*H;
  float s = 0.f;
  for (int k=lane;k<H;k+=64){ float x=bf2f(r[k]); s = fmaf(x,x,s); }
  for (int o=1;o<64;o<<=1) s += __shfl_xor(s,o);
  if (lane==0) shift[c] = sqrtf(s) * fdec(wb[0]) + fdec(wb[1]) + 1.0f;
}

// ---------------- generic 128x128-tile MFMA GEMM: out = A(M,H) @ BT(N,H)^T + bias ----------------
template<int BIAS_ROW, int BF16OUT>
__global__ __launch_bounds__(256) void k_gemm(
    const u16* __restrict__ A, const u16* __restrict__ BT,
    const float* __restrict__ bias, int biasBound,
    void* __restrict__ outp, int ldout){
  __shared__ u16 As[128*LDK];
  __shared__ u16 Bs[128*LDK];
  const int tid = threadIdx.x;
  const int lane = tid & 63, wave = tid >> 6;
  const int wm = wave >> 1, wn = wave & 1;
  const int m0 = blockIdx.y * 128, n0 = blockIdx.x * 128;
  const int lr = lane & 15, lg = lane >> 4;
  f32x4 acc[4][4] = {};
  const int sr = tid >> 1, sh = (tid & 1) * 16;
  for (int ks = 0; ks < H; ks += 32){
    const u16* ga = A  + (size_t)(m0 + sr)*H + ks + sh;
    const u16* gb = BT + (size_t)(n0 + sr)*H + ks + sh;
    uint4 a0 = *(const uint4*)ga;
    uint4 a1 = *(const uint4*)(ga + 8);
    uint4 b0 = *(const uint4*)gb;
    uint4 b1 = *(const uint4*)(gb + 8);
    __syncthreads();
    *(uint4*)&As[sr*LDK + sh]     = a0;
    *(uint4*)&As[sr*LDK + sh + 8] = a1;
    *(uint4*)&Bs[sr*LDK + sh]     = b0;
    *(uint4*)&Bs[sr*LDK + sh + 8] = b1;
    __syncthreads();
    bf16x8 af[4], bfr[4];
    #pragma unroll
    for (int m=0;m<4;m++) af[m]  = *(const bf16x8*)&As[(wm*64 + m*16 + lr)*LDK + lg*8];
    #pragma unroll
    for (int n=0;n<4;n++) bfr[n] = *(const bf16x8*)&Bs[(wn*64 + n*16 + lr)*LDK + lg*8];
    #pragma unroll
    for (int m=0;m<4;m++)
      #pragma unroll
      for (int n=0;n<4;n++)
        acc[m][n] = __builtin_amdgcn_mfma_f32_16x16x32_bf16(af[m], bfr[n], acc[m][n], 0,0,0);
  }
  #pragma unroll
  for (int m=0;m<4;m++){
    int r_g = m0 + wm*64 + m*16 + lg*4;
    #pragma unroll
    for (int n=0;n<4;n++){
      int n_g = n0 + wn*64 + n*16 + lr;
      float bcol = BIAS_ROW ? 0.f : bias[n_g];
      #pragma unroll
      for (int reg=0; reg<4; reg++){
        int r = r_g + reg;
        float bv = BIAS_ROW ? ((r < biasBound) ? bias[r] : 0.f) : bcol;
        float val = acc[m][n][reg] + bv;
        if (BF16OUT) ((u16*)outp)[(size_t)r*ldout + n_g] = f2bf(val);
        else         ((float*)outp)[(size_t)r*ldout + n_g] = val;
      }
    }
  }
}

// ---------------- row softmax: TL (C,C) f32 -> P (C,C) bf16 ----------------
__global__ __launch_bounds__(256) void k_softmax(const float* __restrict__ TL, u16* __restrict__ P){
  const int c = blockIdx.x;
  const int tid = threadIdx.x, lane = tid & 63, wid = tid >> 6;
  __shared__ float red[4];
  __shared__ float Ms, Zs;
  float4 v = ((const float4*)(TL + (size_t)c*C))[tid];
  float m = fmaxf(fmaxf(v.x,v.y), fmaxf(v.z,v.w));
  for (int o=1;o<64;o<<=1) m = fmaxf(m, __shfl_xor(m,o));
  if (lane==0) red[wid] = m;
  __syncthreads();
  if (tid==0) Ms = fmaxf(fmaxf(red[0],red[1]), fmaxf(red[2],red[3]));
  __syncthreads();
  float M = Ms;
  float e0 = expf(v.x-M), e1 = expf(v.y-M), e2 = expf(v.z-M), e3 = expf(v.w-M);
  float s = (e0+e1)+(e2+e3);
  for (int o=1;o<64;o<<=1) s += __shfl_xor(s,o);
  if (lane==0) red[wid] = s;
  __syncthreads();
  if (tid==0) Zs = red[0]+red[1]+red[2]+red[3];
  __syncthreads();
  float inv = 1.f/Zs;
  u32 lo = (u32)f2bf(e0*inv) | ((u32)f2bf(e1*inv)<<16);
  u32 hi = (u32)f2bf(e2*inv) | ((u32)f2bf(e3*inv)<<16);
  *(uint2*)(P + (size_t)c*C + tid*4) = make_uint2(lo, hi);
}

// ---------------- scatter D[v][c] = exp(EM[v][c] - shift[c]) (bf16, idempotent dedupe) ----------------
__global__ __launch_bounds__(256) void k_scatter(
    const int* __restrict__ w2s, const u16* __restrict__ EM,
    const float* __restrict__ shift, u16* __restrict__ D){
  int idx = blockIdx.x*256 + threadIdx.x;   // over V*S
  int v = idx >> 7;
  const int c = w2s[idx];
  float val = bf2f(EM[(size_t)v*C + c]);
  D[(size_t)v*C + c] = f2bf(expf(val - shift[c]));
}

// ---------------- column-sum of D over row chunks -> sumexp[chunk*C + c] ----------------
__global__ __launch_bounds__(256) void k_colsum(const u16* __restrict__ D, float* __restrict__ sumexp){
  const int c = blockIdx.x*256 + threadIdx.x;
  const int v0 = blockIdx.y*CHUNK;
  float s = 0.f;
  const u16* p = D + (size_t)v0*C + c;
  #pragma unroll 2
  for (int i=0;i<CHUNK;i++){ s += bf2f(p[0]); p += C; }
  sumexp[(size_t)blockIdx.y*C + c] = s;
}

__global__ void k_lse(const float* __restrict__ shift, const float* __restrict__ sumexp, float* __restrict__ lse){
  int c = threadIdx.x + blockIdx.x*blockDim.x;
  if (c < C){
    float s = 0.f;
    for (int r=0;r<NR;r++) s += sumexp[(size_t)r*C + c];
    lse[c] = shift[c] + logf(s);
  }
}

// ---------------- obs[b,t,s] = EM[text,c] - lse[c] ----------------
__global__ __launch_bounds__(128) void k_obs(
    const int* __restrict__ text, const int* __restrict__ w2s,
    const u16* __restrict__ EM, const float* __restrict__ lse,
    float* __restrict__ obs){
  const int bt = blockIdx.x;
  const int s = threadIdx.x;
  const int v = text[bt];
  const int c = w2s[(size_t)v*S + s];
  obs[(size_t)bt*S + s] = bf2f(EM[(size_t)v*C + c]) - lse[c];
}

// ---------------- build level-0 tiles ----------------
__global__ __launch_bounds__(256) void k_pot(
    const int* __restrict__ text, const int* __restrict__ w2s,
    const float* __restrict__ start_lp, const float* __restrict__ obs,
    const u16* __restrict__ P, u16* __restrict__ pot){
  const int t = blockIdx.x;  // 0..127
  const int b = blockIdx.y;
  const int tid = threadIdx.x;
  u16* dst = pot + ((size_t)b*128 + t)*(S*S);
  if (t == 127){
    #pragma unroll
    for (int k=0;k<8;k++){
      int e0 = (k*256 + tid)*8;
      int row = e0>>7, c0 = e0&127;
      union { uint4 w; u16 h[8]; } u;
      u.w = make_uint4(0,0,0,0);
      int d = row - c0;
      if (d >= 0 && d < 8) u.h[d] = 0x3F80u;  // 1.0 bf16
      *(uint4*)(dst + e0) = u.w;
    }
    return;
  }
  __shared__ int cp[S], cn[S];
  __shared__ float eo[S];
  __shared__ float a0[S];
  __shared__ u32 tileW[S*65];          // u16 tile [sn][sp], row stride 130 u16
  u16* tile16 = (u16*)tileW;
  if (tid < 128){
    int cpv = w2s[(size_t)text[b*T + t]*S + tid];
    cp[tid] = cpv;
    a0[tid] = (t==0) ? expf(start_lp[cpv] + obs[(size_t)(b*T)*S + tid]) : 1.0f;
    eo[tid] = expf(obs[((size_t)b*T + t + 1)*S + tid]);
  } else {
    cn[tid-128] = w2s[(size_t)text[b*T + t+1]*S + (tid-128)];
  }
  __syncthreads();
  const int sp_half = tid >> 7;
  const int sn = tid & 127;
  const int cnv = cn[sn];
  const float eov = eo[sn];
  for (int it=0; it<64; ++it){
    int sp = it*2 + sp_half;
    tile16[sn*130 + sp] = f2bf(bf2f(P[(size_t)cp[sp]*C + cnv]) * eov * a0[sp]);
  }
  __syncthreads();
  if (t & 1){
    #pragma unroll
    for (int ii=0; ii<8; ++ii){
      int i0 = (ii*256 + tid)*8;
      int sn2 = i0>>7, sp2 = i0&127;
      const u32* tw = tileW + sn2*65 + (sp2>>1);
      uint4 w4; w4.x = tw[0]; w4.y = tw[1]; w4.z = tw[2]; w4.w = tw[3];
      *(uint4*)(dst + i0) = w4;
    }
  } else {
    #pragma unroll
    for (int ii=0; ii<8; ++ii){
      int i0 = (ii*256 + tid)*8;
      int sp2 = i0>>7, sn0 = i0&127;
      union { uint4 w; u16 h[8]; } u;
      #pragma unroll
      for (int j=0;j<8;j++) u.h[j] = tile16[(sn0+j)*130 + sp2];
      *(uint4*)(dst + i0) = u.w;
    }
  }
}

// ---------------- tree pair-product: out[j] = in[2j+1] . in[2j] ----------------
__global__ __launch_bounds__(256) void k_pair(
    const u16* __restrict__ in, u16* __restrict__ out,
    float* __restrict__ scales, int nin, int soff){
  const int j = blockIdx.x;
  const int b = blockIdx.y;
  const int nout = nin >> 1;
  const u16* Ag = in + ((size_t)b*nin + 2*j+1)*(S*S);
  const u16* Bg = in + ((size_t)b*nin + 2*j  )*(S*S);
  u16* Cg = out + ((size_t)b*nout + j)*(S*S);
  const int tid = threadIdx.x;
  const int lane = tid & 63, wave = tid >> 6;
  const int wm = wave >> 1, wn = wave & 1;
  const int lr = lane & 15, lg = lane >> 4;
  f32x4 acc[4][4] = {};
  #pragma unroll
  for (int kc=0; kc<4; ++kc){
    bf16x8 af[4], bfr[4];
    #pragma unroll
    for (int m=0;m<4;m++) af[m]  = *(const bf16x8*)(Ag + (size_t)(wm*64+m*16+lr)*128 + kc*32 + lg*8);
    #pragma unroll
    for (int n=0;n<4;n++) bfr[n] = *(const bf16x8*)(Bg + (size_t)(wn*64+n*16+lr)*128 + kc*32 + lg*8);
    #pragma unroll
    for (int m=0;m<4;m++)
      #pragma unroll
      for (int n=0;n<4;n++)
        acc[m][n] = __builtin_amdgcn_mfma_f32_16x16x32_bf16(af[m], bfr[n], acc[m][n], 0,0,0);
  }
  __shared__ float red[4];
  float mx = 0.f;
  #pragma unroll
  for (int m=0;m<4;m++)
    #pragma unroll
    for (int n=0;n<4;n++)
      #pragma unroll
      for (int r=0;r<4;r++) mx = fmaxf(mx, acc[m][n][r]);
  for (int o=1;o<64;o<<=1) mx = fmaxf(mx, __shfl_xor(mx,o));
  if (lane==0) red[wave] = mx;
  __syncthreads();
  mx = fmaxf(fmaxf(red[0],red[1]), fmaxf(red[2],red[3]));
  const float sc = 1.0f / mx;
  if (tid==0) scales[(size_t)b*127 + soff + j] = logf(mx);
  if (j & 1){
    #pragma unroll
    for (int m=0;m<4;m++){
      int rg = wm*64 + m*16 + lg*4;
      #pragma unroll
      for (int n=0;n<4;n++){
        int cg = wn*64 + n*16 + lr;
        #pragma unroll
        for (int r=0;r<4;r++) Cg[(size_t)(rg+r)*128 + cg] = f2bf(acc[m][n][r]*sc);
      }
    }
  } else {
    #pragma unroll
    for (int m=0;m<4;m++){
      int rg = wm*64 + m*16 + lg*4;
      #pragma unroll
      for (int n=0;n<4;n++){
        int cg = wn*64 + n*16 + lr;
        float v0=acc[m][n][0]*sc, v1=acc[m][n][1]*sc, v2=acc[m][n][2]*sc, v3=acc[m][n][3]*sc;
        u32 p0, p1;
        asm("v_cvt_pk_bf16_f32 %0, %1, %2" : "=v"(p0) : "v"(v0), "v"(v1));
        asm("v_cvt_pk_bf16_f32 %0, %1, %2" : "=v"(p1) : "v"(v2), "v"(v3));
        *(uint2*)(Cg + (size_t)cg*128 + rg) = make_uint2(p0, p1);
      }
    }
  }
}

// ---------------- final: res[b] = log(sum entries) + sum(scales) ----------------
__global__ __launch_bounds__(256) void k_fin(
    const u16* __restrict__ fin, const float* __restrict__ scales, float* __restrict__ res){
  const int b = blockIdx.x;
  const int tid = threadIdx.x, lane = tid & 63, wid = tid >> 6;
  __shared__ float red[8];
  const u16* p = fin + (size_t)b*(S*S);
  float s = 0.f;
  #pragma unroll
  for (int i=0;i<8;i++){
    uint4 w = *(const uint4*)(p + (i*256+tid)*8);
    s += bf2f((u16)(w.x&0xFFFFu)) + bf2f((u16)(w.x>>16))
       + bf2f((u16)(w.y&0xFFFFu)) + bf2f((u16)(w.y>>16))
       + bf2f((u16)(w.z&0xFFFFu)) + bf2f((u16)(w.z>>16))
       + bf2f((u16)(w.w&0xFFFFu)) + bf2f((u16)(w.w>>16));
  }
  for (int o=1;o<64;o<<=1) s += __shfl_xor(s,o);
  if (lane==0) red[wid] = s;
  float sl = (tid < 127) ? scales[(size_t)b*127 + tid] : 0.f;
  for (int o=1;o<64;o<<=1) sl += __shfl_xor(sl,o);
  if (lane==0) red[4+wid] = sl;
  __syncthreads();
  if (tid==0){
    float tot = red[0]+red[1]+red[2]+red[3];
    float ssum = red[4]+red[5]+red[6]+red[7];
    res[b] = logf(tot) + ssum;
  }
}

__global__ void k_final(const float* __restrict__ res, float* __restrict__ out){
  if (threadIdx.x==0){
    float s = 0.f;
    for (int i=0;i<B;i++) s += res[i];
    out[0] = s;
  }
}

extern "C" void kernel_launch(void* const* d_in, const int* in_sizes, int n_in,
                              void* d_out, int out_size, void* d_ws, size_t ws_size,
                              hipStream_t stream){
  const int*   text      = (const int*)d_in[0];
  const int*   w2s       = (const int*)d_in[1];
  const float* start_emb = (const float*)d_in[2];
  const float* start_w1  = (const float*)d_in[3];
  const float* start_b1  = (const float*)d_in[4];
  const float* start_w2  = (const float*)d_in[5];
  const float* start_b2  = (const float*)d_in[6];
  const float* start_wo  = (const float*)d_in[7];
  const float* start_bo  = (const float*)d_in[8];
  const float* state_emb = (const float*)d_in[9];
  const float* trans_w1  = (const float*)d_in[10];
  const float* trans_b1  = (const float*)d_in[11];
  const float* trans_w2  = (const float*)d_in[12];
  const float* trans_b2  = (const float*)d_in[13];
  const float* trans_wo  = (const float*)d_in[14];
  const float* trans_bo  = (const float*)d_in[15];
  const float* pre_emb   = (const float*)d_in[16];
  const float* term_w1   = (const float*)d_in[17];
  const float* term_b1   = (const float*)d_in[18];
  const float* term_w2   = (const float*)d_in[19];
  const float* term_b2   = (const float*)d_in[20];
  const float* term_wo   = (const float*)d_in[21];
  const float* term_bo   = (const float*)d_in[22];

  char* ws = (char*)d_ws;
  size_t off = 0;
  auto alloc = [&](size_t bytes)->char*{ char* p = ws + off; off += (bytes + 255) & ~(size_t)255; return p; };
  u16*   embb     = (u16*)  alloc(sizeof(u16)*3*(size_t)C*H);
  u16*   h1b      = (u16*)  alloc(sizeof(u16)*3*(size_t)C*H);
  u16*   h2b      = (u16*)  alloc(sizeof(u16)*3*(size_t)C*H);
  u16*   wt       = (u16*)  alloc(sizeof(u16)*6*(size_t)H*H);
  float* start_lp = (float*)alloc(sizeof(float)*C);
  float* shift    = (float*)alloc(sizeof(float)*C);
  float* sumexp   = (float*)alloc(sizeof(float)*(size_t)C*NR);
  float* lse      = (float*)alloc(sizeof(float)*C);
  u32*   wb       = (u32*)  alloc(sizeof(u32)*2);
  float* resb     = (float*)alloc(sizeof(float)*B);
  float* scales   = (float*)alloc(sizeof(float)*(size_t)B*127);
  u16*   P        = (u16*)  alloc(sizeof(u16)*(size_t)C*C);
  u16*   wotb     = (u16*)  alloc(sizeof(u16)*(size_t)VP*H);
  u16*   wottr    = (u16*)  alloc(sizeof(u16)*(size_t)C*H);
  float* obs      = (float*)alloc(sizeof(float)*(size_t)B*T*S);
  u16*   potS     = (u16*)  alloc(sizeof(u16)*(size_t)B*128*S*S);   // level-0 tiles
  u16*   treeA    = (u16*)  alloc(sizeof(u16)*(size_t)B*64*S*S);
  u16*   treeB    = (u16*)  alloc(sizeof(u16)*(size_t)B*32*S*S);
  u16*   EM       = (u16*)potS;    // bf16 EM [VP][C], dead before k_pot writes potS
  float* TL       = (float*)treeA; // f32 TL [C][C] = 4MB, dead before tree level 1
  u16*   D        = (u16*)((char*)treeA + sizeof(float)*(size_t)C*C); // bf16 [VP][C] = 20.7MB, in treeA[4MB..24.7MB)
  (void)ws_size; (void)in_sizes; (void)n_in; (void)out_size;

  u16* embb0 = embb, *embb1 = embb + (size_t)C*H, *embb2 = embb + 2*(size_t)C*H;
  u16* h1b0 = h1b, *h1b1 = h1b + (size_t)C*H, *h1b2 = h1b + 2*(size_t)C*H;
  u16* h2b0 = h2b, *h2b1 = h2b + (size_t)C*H, *h2b2 = h2b + 2*(size_t)C*H;

  k_zero<<<dim3(1), dim3(64), 0, stream>>>(wb, resb);
  hipMemsetAsync(D, 0, sizeof(u16)*(size_t)VP*C, stream);

  Cvt3 cv; cv.s0 = start_emb; cv.s1 = state_emb; cv.s2 = pre_emb;
  cv.d0 = embb0; cv.d1 = embb1; cv.d2 = embb2;
  k_cvt3<<<dim3(C*H/(256*8), 3), dim3(256), 0, stream>>>(cv);

  T6 t6;
  t6.s[0]=start_w1; t6.s[1]=start_w2; t6.s[2]=trans_w1; t6.s[3]=trans_w2; t6.s[4]=term_w1; t6.s[5]=term_w2;
  for (int i=0;i<6;i++) t6.d[i] = wt + (size_t)i*H*H;
  k_transpose6<<<dim3(H/32, H/32, 6), dim3(32,8), 0, stream>>>(t6);

  M3 l1;
  l1.A[0]=embb0; l1.A[1]=embb1; l1.A[2]=embb2;
  l1.W[0]=wt;    l1.W[1]=wt+2*(size_t)H*H; l1.W[2]=wt+4*(size_t)H*H;
  l1.bias[0]=start_b1; l1.bias[1]=trans_b1; l1.bias[2]=term_b1;
  l1.R[0]=l1.R[1]=l1.R[2]=nullptr;
  l1.O[0]=h1b0; l1.O[1]=h1b1; l1.O[2]=h1b2;
  k_mlpg<0><<<dim3(H/128, C/128, 3), dim3(256), 0, stream>>>(l1);

  M3 l2;
  l2.A[0]=h1b0; l2.A[1]=h1b1; l2.A[2]=h1b2;
  l2.W[0]=wt+(size_t)H*H; l2.W[1]=wt+3*(size_t)H*H; l2.W[2]=wt+5*(size_t)H*H;
  l2.bias[0]=start_b2; l2.bias[1]=trans_b2; l2.bias[2]=term_b2;
  l2.R[0]=embb0; l2.R[1]=embb1; l2.R[2]=embb2;
  l2.O[0]=h2b0; l2.O[1]=h2b1; l2.O[2]=h2b2;
  k_mlpg<1><<<dim3(H/128, C/128, 3), dim3(256), 0, stream>>>(l2);

  k_start<<<dim3(1), dim3(1024), 0, stream>>>(h2b0, start_wo, start_bo, start_lp);
  k_transpose<<<dim3(VP/32, H/32), dim3(32,8), 0, stream>>>(term_wo, wotb, V);
  k_transpose<<<dim3(C/32, H/32), dim3(32,8), 0, stream>>>(trans_wo, wottr, C);
  k_wnorm<<<dim3(64), dim3(256), 0, stream>>>(wotb, term_bo, wb, wb+1);
  k_shift<<<dim3(C/4), dim3(256), 0, stream>>>(h2b2, wb, shift);
  // transition logits (f32) + row softmax -> P
  k_gemm<0,0><<<dim3(C/128, C/128), dim3(256), 0, stream>>>(h2b1, wottr, trans_bo, C, TL, C);
  k_softmax<<<dim3(C), dim3(256), 0, stream>>>(TL, P);
  // emission logits EM[v][c] bf16, row bias bo[v]
  k_gemm<1,1><<<dim3(C/128, VP/128), dim3(256), 0, stream>>>(wotb, h2b2, term_bo, V, EM, C);
  // masked LSE via idempotent scatter + dense colsum (no atomics)
  k_scatter<<<dim3(V*S/256), dim3(256), 0, stream>>>(w2s, EM, shift, D);
  k_colsum<<<dim3(C/256, NR), dim3(256), 0, stream>>>(D, sumexp);
  k_lse<<<dim3((C+255)/256), dim3(256), 0, stream>>>(shift, sumexp, lse);
  k_obs<<<dim3(B*T), dim3(128), 0, stream>>>(text, w2s, EM, lse, obs);
  k_pot<<<dim3(128, B), dim3(256), 0, stream>>>(text, w2s, start_lp, obs, P, potS);

  // product tree: 128 -> 64 -> 32 -> 16 -> 8 -> 4 -> 2 -> 1
  {
    u16* lin = potS;
    u16* bufs[2] = { treeA, treeB };
    int nin = 128, soff = 0, cur = 0;
    while (nin > 1){
      int nout = nin >> 1;
      k_pair<<<dim3(nout, B), dim3(256), 0, stream>>>(lin, bufs[cur], scales, nin, soff);
      lin = bufs[cur];
      cur ^= 1;
      soff += nout;
      nin = nout;
    }
    k_fin<<<dim3(B), dim3(256), 0, stream>>>(lin, scales, resb);
  }
  k_final<<<dim3(1), dim3(64), 0, stream>>>(resb, (float*)d_out);
}

// Round 9
// 294.125 us; speedup vs baseline: 1.5374x; 1.0838x over previous
//
#include <hip/hip_runtime.h>
#include <hip/hip_bf16.h>

#define V 10000
#define VP 10112
#define C 1024
#define S 128
#define H 256
#define B 16
#define T 128
#define NR 64      // colsum/colmax row-chunks (replicas)
#define CHUNK 158  // VP / NR
#define LDK 40     // padded LDS row length (u16) for k_gemm

typedef unsigned short u16;
typedef unsigned int u32;
typedef __bf16 bf16x8 __attribute__((ext_vector_type(8)));
typedef float f32x4 __attribute__((ext_vector_type(4)));

static __device__ __forceinline__ float bf2f(u16 x){ return __uint_as_float(((u32)x)<<16); }
static __device__ __forceinline__ u16 f2bf(float f){ u32 u=__float_as_uint(f); return (u16)((u + 0x7FFFu + ((u>>16)&1u))>>16); }

// ---------------- batched f32 -> bf16 convert (3 embeddings, C*H each) ----------------
struct Cvt3 { const float* s0; const float* s1; const float* s2; u16* d0; u16* d1; u16* d2; };
__global__ __launch_bounds__(256) void k_cvt3(Cvt3 a){
  const float* s = (blockIdx.y==0)? a.s0 : (blockIdx.y==1)? a.s1 : a.s2;
  u16* d = (blockIdx.y==0)? a.d0 : (blockIdx.y==1)? a.d1 : a.d2;
  int i = (blockIdx.x*256 + threadIdx.x)*8;
  float4 x0 = *(const float4*)(s+i);
  float4 x1 = *(const float4*)(s+i+4);
  u16 h[8] = {f2bf(x0.x),f2bf(x0.y),f2bf(x0.z),f2bf(x0.w),f2bf(x1.x),f2bf(x1.y),f2bf(x1.z),f2bf(x1.w)};
  *(uint4*)(d+i) = *(uint4*)h;
}

// ---------------- transpose src (H,N) f32 -> dst (NP,H) bf16, zero-padded ----------------
__global__ __launch_bounds__(256) void k_transpose(const float* __restrict__ src, u16* __restrict__ dst, int N){
  __shared__ float tile[32][33];
  int v0 = blockIdx.x*32, k0 = blockIdx.y*32;
  int tx = threadIdx.x, ty = threadIdx.y; // 32 x 8
  for (int i=0;i<32;i+=8){
    int k = k0+ty+i, v = v0+tx;
    tile[ty+i][tx] = (v < N) ? src[(size_t)k*N + v] : 0.f;
  }
  __syncthreads();
  for (int i=0;i<32;i+=8){
    int v = v0+ty+i, k = k0+tx;
    dst[(size_t)v*H + k] = f2bf(tile[tx][ty+i]);
  }
}

// ---------------- batched transpose of six (H,H) f32 weights -> bf16 [j][k] ----------------
struct T6 { const float* s[6]; u16* d[6]; };
__global__ __launch_bounds__(256) void k_transpose6(T6 a){
  const float* src = a.s[blockIdx.z];
  u16* dst = a.d[blockIdx.z];
  __shared__ float tile[32][33];
  int v0 = blockIdx.x*32, k0 = blockIdx.y*32;
  int tx = threadIdx.x, ty = threadIdx.y; // 32 x 8
  for (int i=0;i<32;i+=8){
    int k = k0+ty+i, v = v0+tx;
    tile[ty+i][tx] = src[(size_t)k*H + v];
  }
  __syncthreads();
  for (int i=0;i<32;i+=8){
    int v = v0+ty+i, k = k0+tx;
    dst[(size_t)v*H + k] = f2bf(tile[tx][ty+i]);
  }
}

// ---------------- batched MLP layer (3 MLPs via blockIdx.z), 128x128 MFMA tile ----------------
struct M3 { const u16* A[3]; const u16* W[3]; const float* bias[3]; const u16* R[3]; u16* O[3]; };
template<int RESID>
__global__ __launch_bounds__(256) void k_mlpg(M3 a){
  const int z = blockIdx.z;
  const u16* A  = a.A[z];
  const u16* BT = a.W[z];
  const float* bias = a.bias[z];
  const u16* Rm = a.R[z];
  u16* O = a.O[z];
  __shared__ u16 As[128*LDK];
  __shared__ u16 Bs[128*LDK];
  const int tid = threadIdx.x;
  const int lane = tid & 63, wave = tid >> 6;
  const int wm = wave >> 1, wn = wave & 1;
  const int m0 = blockIdx.y * 128, n0 = blockIdx.x * 128;
  const int lr = lane & 15, lg = lane >> 4;
  f32x4 acc[4][4] = {};
  const int sr = tid >> 1, sh = (tid & 1) * 16;
  for (int ks = 0; ks < H; ks += 32){
    const u16* ga = A  + (size_t)(m0 + sr)*H + ks + sh;
    const u16* gb = BT + (size_t)(n0 + sr)*H + ks + sh;
    uint4 a0 = *(const uint4*)ga;
    uint4 a1 = *(const uint4*)(ga + 8);
    uint4 b0 = *(const uint4*)gb;
    uint4 b1 = *(const uint4*)(gb + 8);
    __syncthreads();
    *(uint4*)&As[sr*LDK + sh]     = a0;
    *(uint4*)&As[sr*LDK + sh + 8] = a1;
    *(uint4*)&Bs[sr*LDK + sh]     = b0;
    *(uint4*)&Bs[sr*LDK + sh + 8] = b1;
    __syncthreads();
    bf16x8 af[4], bfr[4];
    #pragma unroll
    for (int m=0;m<4;m++) af[m]  = *(const bf16x8*)&As[(wm*64 + m*16 + lr)*LDK + lg*8];
    #pragma unroll
    for (int n=0;n<4;n++) bfr[n] = *(const bf16x8*)&Bs[(wn*64 + n*16 + lr)*LDK + lg*8];
    #pragma unroll
    for (int m=0;m<4;m++)
      #pragma unroll
      for (int n=0;n<4;n++)
        acc[m][n] = __builtin_amdgcn_mfma_f32_16x16x32_bf16(af[m], bfr[n], acc[m][n], 0,0,0);
  }
  #pragma unroll
  for (int m=0;m<4;m++){
    int r_g = m0 + wm*64 + m*16 + lg*4;
    #pragma unroll
    for (int n=0;n<4;n++){
      int n_g = n0 + wn*64 + n*16 + lr;
      float bv = bias[n_g];
      #pragma unroll
      for (int reg=0; reg<4; reg++){
        int r = r_g + reg;
        float val = acc[m][n][reg] + bv;
        if (RESID) val += bf2f(Rm[(size_t)r*H + n_g]);
        val = fmaxf(val, 0.f);
        O[(size_t)r*H + n_g] = f2bf(val);
      }
    }
  }
}

// ---------------- start head + log_softmax over C (bf16 h2) ----------------
__global__ __launch_bounds__(1024) void k_start(
    const u16* __restrict__ h2, const float* __restrict__ wo, const float* __restrict__ bo,
    float* __restrict__ start_lp){
  const int c = threadIdx.x;
  const int lane = c & 63, wid = c >> 6;
  __shared__ float red[16];
  __shared__ float Ms, Zs;
  float acc = bo[0];
  const u16* row = h2 + (size_t)c*H;
  for (int k=0;k<H;k+=8){
    uint4 hv = *(const uint4*)(row+k);
    float4 w0 = *(const float4*)(wo+k);
    float4 w1 = *(const float4*)(wo+k+4);
    acc = fmaf(bf2f((u16)(hv.x&0xFFFFu)), w0.x, acc);
    acc = fmaf(bf2f((u16)(hv.x>>16)),     w0.y, acc);
    acc = fmaf(bf2f((u16)(hv.y&0xFFFFu)), w0.z, acc);
    acc = fmaf(bf2f((u16)(hv.y>>16)),     w0.w, acc);
    acc = fmaf(bf2f((u16)(hv.z&0xFFFFu)), w1.x, acc);
    acc = fmaf(bf2f((u16)(hv.z>>16)),     w1.y, acc);
    acc = fmaf(bf2f((u16)(hv.w&0xFFFFu)), w1.z, acc);
    acc = fmaf(bf2f((u16)(hv.w>>16)),     w1.w, acc);
  }
  float m = acc;
  for (int o=1;o<64;o<<=1) m = fmaxf(m, __shfl_xor(m,o));
  if (lane==0) red[wid]=m;
  __syncthreads();
  if (c==0){ float t=red[0]; for(int i=1;i<16;i++) t=fmaxf(t,red[i]); Ms=t; }
  __syncthreads();
  float M = Ms;
  float e = expf(acc - M);
  float sum = e;
  for (int o=1;o<64;o<<=1) sum += __shfl_xor(sum,o);
  __syncthreads();
  if (lane==0) red[wid]=sum;
  __syncthreads();
  if (c==0){ float t=0.f; for(int i=0;i<16;i++) t+=red[i]; Zs=t; }
  __syncthreads();
  start_lp[c] = acc - (M + logf(Zs));
}

// ---------------- generic 128x128-tile MFMA GEMM: out = A(M,H) @ BT(N,H)^T + bias ----------------
template<int BIAS_ROW, int BF16OUT>
__global__ __launch_bounds__(256) void k_gemm(
    const u16* __restrict__ A, const u16* __restrict__ BT,
    const float* __restrict__ bias, int biasBound,
    void* __restrict__ outp, int ldout){
  __shared__ u16 As[128*LDK];
  __shared__ u16 Bs[128*LDK];
  const int tid = threadIdx.x;
  const int lane = tid & 63, wave = tid >> 6;
  const int wm = wave >> 1, wn = wave & 1;
  const int m0 = blockIdx.y * 128, n0 = blockIdx.x * 128;
  const int lr = lane & 15, lg = lane >> 4;
  f32x4 acc[4][4] = {};
  const int sr = tid >> 1, sh = (tid & 1) * 16;
  for (int ks = 0; ks < H; ks += 32){
    const u16* ga = A  + (size_t)(m0 + sr)*H + ks + sh;
    const u16* gb = BT + (size_t)(n0 + sr)*H + ks + sh;
    uint4 a0 = *(const uint4*)ga;
    uint4 a1 = *(const uint4*)(ga + 8);
    uint4 b0 = *(const uint4*)gb;
    uint4 b1 = *(const uint4*)(gb + 8);
    __syncthreads();
    *(uint4*)&As[sr*LDK + sh]     = a0;
    *(uint4*)&As[sr*LDK + sh + 8] = a1;
    *(uint4*)&Bs[sr*LDK + sh]     = b0;
    *(uint4*)&Bs[sr*LDK + sh + 8] = b1;
    __syncthreads();
    bf16x8 af[4], bfr[4];
    #pragma unroll
    for (int m=0;m<4;m++) af[m]  = *(const bf16x8*)&As[(wm*64 + m*16 + lr)*LDK + lg*8];
    #pragma unroll
    for (int n=0;n<4;n++) bfr[n] = *(const bf16x8*)&Bs[(wn*64 + n*16 + lr)*LDK + lg*8];
    #pragma unroll
    for (int m=0;m<4;m++)
      #pragma unroll
      for (int n=0;n<4;n++)
        acc[m][n] = __builtin_amdgcn_mfma_f32_16x16x32_bf16(af[m], bfr[n], acc[m][n], 0,0,0);
  }
  #pragma unroll
  for (int m=0;m<4;m++){
    int r_g = m0 + wm*64 + m*16 + lg*4;
    #pragma unroll
    for (int n=0;n<4;n++){
      int n_g = n0 + wn*64 + n*16 + lr;
      float bcol = BIAS_ROW ? 0.f : bias[n_g];
      #pragma unroll
      for (int reg=0; reg<4; reg++){
        int r = r_g + reg;
        float bv = BIAS_ROW ? ((r < biasBound) ? bias[r] : 0.f) : bcol;
        float val = acc[m][n][reg] + bv;
        if (BF16OUT) ((u16*)outp)[(size_t)r*ldout + n_g] = f2bf(val);
        else         ((float*)outp)[(size_t)r*ldout + n_g] = val;
      }
    }
  }
}

// ---------------- row softmax: TL (C,C) f32 -> P (C,C) bf16 ----------------
__global__ __launch_bounds__(256) void k_softmax(const float* __restrict__ TL, u16* __restrict__ P){
  const int c = blockIdx.x;
  const int tid = threadIdx.x, lane = tid & 63, wid = tid >> 6;
  __shared__ float red[4];
  __shared__ float Ms, Zs;
  float4 v = ((const float4*)(TL + (size_t)c*C))[tid];
  float m = fmaxf(fmaxf(v.x,v.y), fmaxf(v.z,v.w));
  for (int o=1;o<64;o<<=1) m = fmaxf(m, __shfl_xor(m,o));
  if (lane==0) red[wid] = m;
  __syncthreads();
  if (tid==0) Ms = fmaxf(fmaxf(red[0],red[1]), fmaxf(red[2],red[3]));
  __syncthreads();
  float M = Ms;
  float e0 = expf(v.x-M), e1 = expf(v.y-M), e2 = expf(v.z-M), e3 = expf(v.w-M);
  float s = (e0+e1)+(e2+e3);
  for (int o=1;o<64;o<<=1) s += __shfl_xor(s,o);
  if (lane==0) red[wid] = s;
  __syncthreads();
  if (tid==0) Zs = red[0]+red[1]+red[2]+red[3];
  __syncthreads();
  float inv = 1.f/Zs;
  u32 lo = (u32)f2bf(e0*inv) | ((u32)f2bf(e1*inv)<<16);
  u32 hi = (u32)f2bf(e2*inv) | ((u32)f2bf(e3*inv)<<16);
  *(uint2*)(P + (size_t)c*C + tid*4) = make_uint2(lo, hi);
}

// ---------------- partial column-max of EM over row chunks ----------------
__global__ __launch_bounds__(256) void k_colmax(const u16* __restrict__ EM, float* __restrict__ shiftp){
  const int c = blockIdx.x*256 + threadIdx.x;
  const int v0 = blockIdx.y*CHUNK;
  float m = -1e30f;
  const u16* p = EM + (size_t)v0*C + c;
  #pragma unroll 2
  for (int i=0;i<CHUNK;i++){ m = fmaxf(m, bf2f(p[0])); p += C; }
  shiftp[(size_t)blockIdx.y*C + c] = m;
}

// ---------------- combine partials: shift[c] = max_r shiftp[r][c] (exact colmax) ----------------
__global__ void k_shiftc(const float* __restrict__ shiftp, float* __restrict__ shift){
  int c = threadIdx.x + blockIdx.x*blockDim.x;
  if (c < C){
    float m = -1e30f;
    for (int r=0;r<NR;r++) m = fmaxf(m, shiftp[(size_t)r*C + c]);
    shift[c] = m;
  }
}

// ---------------- scatter D[v][c] = exp(EM[v][c] - shift[c]) (bf16, idempotent dedupe) ----------------
__global__ __launch_bounds__(256) void k_scatter(
    const int* __restrict__ w2s, const u16* __restrict__ EM,
    const float* __restrict__ shift, u16* __restrict__ D){
  int idx = blockIdx.x*256 + threadIdx.x;   // over V*S
  int v = idx >> 7;
  const int c = w2s[idx];
  float val = bf2f(EM[(size_t)v*C + c]);
  D[(size_t)v*C + c] = f2bf(expf(val - shift[c]));
}

// ---------------- column-sum of D over row chunks -> sumexp[chunk*C + c] ----------------
__global__ __launch_bounds__(256) void k_colsum(const u16* __restrict__ D, float* __restrict__ sumexp){
  const int c = blockIdx.x*256 + threadIdx.x;
  const int v0 = blockIdx.y*CHUNK;
  float s = 0.f;
  const u16* p = D + (size_t)v0*C + c;
  #pragma unroll 2
  for (int i=0;i<CHUNK;i++){ s += bf2f(p[0]); p += C; }
  sumexp[(size_t)blockIdx.y*C + c] = s;
}

__global__ void k_lse(const float* __restrict__ shift, const float* __restrict__ sumexp, float* __restrict__ lse){
  int c = threadIdx.x + blockIdx.x*blockDim.x;
  if (c < C){
    float s = 0.f;
    for (int r=0;r<NR;r++) s += sumexp[(size_t)r*C + c];
    lse[c] = shift[c] + logf(s);
  }
}

// ---------------- obs[b,t,s] = EM[text,c] - lse[c] ----------------
__global__ __launch_bounds__(128) void k_obs(
    const int* __restrict__ text, const int* __restrict__ w2s,
    const u16* __restrict__ EM, const float* __restrict__ lse,
    float* __restrict__ obs){
  const int bt = blockIdx.x;
  const int s = threadIdx.x;
  const int v = text[bt];
  const int c = w2s[(size_t)v*S + s];
  obs[(size_t)bt*S + s] = bf2f(EM[(size_t)v*C + c]) - lse[c];
}

// ---------------- build level-0 tiles ----------------
__global__ __launch_bounds__(256) void k_pot(
    const int* __restrict__ text, const int* __restrict__ w2s,
    const float* __restrict__ start_lp, const float* __restrict__ obs,
    const u16* __restrict__ P, u16* __restrict__ pot){
  const int t = blockIdx.x;  // 0..127
  const int b = blockIdx.y;
  const int tid = threadIdx.x;
  u16* dst = pot + ((size_t)b*128 + t)*(S*S);
  if (t == 127){
    #pragma unroll
    for (int k=0;k<8;k++){
      int e0 = (k*256 + tid)*8;
      int row = e0>>7, c0 = e0&127;
      union { uint4 w; u16 h[8]; } u;
      u.w = make_uint4(0,0,0,0);
      int d = row - c0;
      if (d >= 0 && d < 8) u.h[d] = 0x3F80u;  // 1.0 bf16
      *(uint4*)(dst + e0) = u.w;
    }
    return;
  }
  __shared__ int cp[S], cn[S];
  __shared__ float eo[S];
  __shared__ float a0[S];
  __shared__ u32 tileW[S*65];          // u16 tile [sn][sp], row stride 130 u16
  u16* tile16 = (u16*)tileW;
  if (tid < 128){
    int cpv = w2s[(size_t)text[b*T + t]*S + tid];
    cp[tid] = cpv;
    a0[tid] = (t==0) ? expf(start_lp[cpv] + obs[(size_t)(b*T)*S + tid]) : 1.0f;
    eo[tid] = expf(obs[((size_t)b*T + t + 1)*S + tid]);
  } else {
    cn[tid-128] = w2s[(size_t)text[b*T + t+1]*S + (tid-128)];
  }
  __syncthreads();
  const int sp_half = tid >> 7;
  const int sn = tid & 127;
  const int cnv = cn[sn];
  const float eov = eo[sn];
  for (int it=0; it<64; ++it){
    int sp = it*2 + sp_half;
    tile16[sn*130 + sp] = f2bf(bf2f(P[(size_t)cp[sp]*C + cnv]) * eov * a0[sp]);
  }
  __syncthreads();
  if (t & 1){
    #pragma unroll
    for (int ii=0; ii<8; ++ii){
      int i0 = (ii*256 + tid)*8;
      int sn2 = i0>>7, sp2 = i0&127;
      const u32* tw = tileW + sn2*65 + (sp2>>1);
      uint4 w4; w4.x = tw[0]; w4.y = tw[1]; w4.z = tw[2]; w4.w = tw[3];
      *(uint4*)(dst + i0) = w4;
    }
  } else {
    #pragma unroll
    for (int ii=0; ii<8; ++ii){
      int i0 = (ii*256 + tid)*8;
      int sp2 = i0>>7, sn0 = i0&127;
      union { uint4 w; u16 h[8]; } u;
      #pragma unroll
      for (int j=0;j<8;j++) u.h[j] = tile16[(sn0+j)*130 + sp2];
      *(uint4*)(dst + i0) = u.w;
    }
  }
}

// ---------------- tree pair-product: out[j] = in[2j+1] . in[2j] ----------------
__global__ __launch_bounds__(256) void k_pair(
    const u16* __restrict__ in, u16* __restrict__ out,
    float* __restrict__ scales, int nin, int soff){
  const int j = blockIdx.x;
  const int b = blockIdx.y;
  const int nout = nin >> 1;
  const u16* Ag = in + ((size_t)b*nin + 2*j+1)*(S*S);
  const u16* Bg = in + ((size_t)b*nin + 2*j  )*(S*S);
  u16* Cg = out + ((size_t)b*nout + j)*(S*S);
  const int tid = threadIdx.x;
  const int lane = tid & 63, wave = tid >> 6;
  const int wm = wave >> 1, wn = wave & 1;
  const int lr = lane & 15, lg = lane >> 4;
  f32x4 acc[4][4] = {};
  #pragma unroll
  for (int kc=0; kc<4; ++kc){
    bf16x8 af[4], bfr[4];
    #pragma unroll
    for (int m=0;m<4;m++) af[m]  = *(const bf16x8*)(Ag + (size_t)(wm*64+m*16+lr)*128 + kc*32 + lg*8);
    #pragma unroll
    for (int n=0;n<4;n++) bfr[n] = *(const bf16x8*)(Bg + (size_t)(wn*64+n*16+lr)*128 + kc*32 + lg*8);
    #pragma unroll
    for (int m=0;m<4;m++)
      #pragma unroll
      for (int n=0;n<4;n++)
        acc[m][n] = __builtin_amdgcn_mfma_f32_16x16x32_bf16(af[m], bfr[n], acc[m][n], 0,0,0);
  }
  __shared__ float red[4];
  float mx = 0.f;
  #pragma unroll
  for (int m=0;m<4;m++)
    #pragma unroll
    for (int n=0;n<4;n++)
      #pragma unroll
      for (int r=0;r<4;r++) mx = fmaxf(mx, acc[m][n][r]);
  for (int o=1;o<64;o<<=1) mx = fmaxf(mx, __shfl_xor(mx,o));
  if (lane==0) red[wave] = mx;
  __syncthreads();
  mx = fmaxf(fmaxf(red[0],red[1]), fmaxf(red[2],red[3]));
  const float sc = 1.0f / mx;
  if (tid==0) scales[(size_t)b*127 + soff + j] = logf(mx);
  if (j & 1){
    #pragma unroll
    for (int m=0;m<4;m++){
      int rg = wm*64 + m*16 + lg*4;
      #pragma unroll
      for (int n=0;n<4;n++){
        int cg = wn*64 + n*16 + lr;
        #pragma unroll
        for (int r=0;r<4;r++) Cg[(size_t)(rg+r)*128 + cg] = f2bf(acc[m][n][r]*sc);
      }
    }
  } else {
    #pragma unroll
    for (int m=0;m<4;m++){
      int rg = wm*64 + m*16 + lg*4;
      #pragma unroll
      for (int n=0;n<4;n++){
        int cg = wn*64 + n*16 + lr;
        float v0=acc[m][n][0]*sc, v1=acc[m][n][1]*sc, v2=acc[m][n][2]*sc, v3=acc[m][n][3]*sc;
        u32 p0, p1;
        asm("v_cvt_pk_bf16_f32 %0, %1, %2" : "=v"(p0) : "v"(v0), "v"(v1));
        asm("v_cvt_pk_bf16_f32 %0, %1, %2" : "=v"(p1) : "v"(v2), "v"(v3));
        *(uint2*)(Cg + (size_t)cg*128 + rg) = make_uint2(p0, p1);
      }
    }
  }
}

// ---------------- final: res[b] = log(sum entries) + sum(scales) ----------------
__global__ __launch_bounds__(256) void k_fin(
    const u16* __restrict__ fin, const float* __restrict__ scales, float* __restrict__ res){
  const int b = blockIdx.x;
  const int tid = threadIdx.x, lane = tid & 63, wid = tid >> 6;
  __shared__ float red[8];
  const u16* p = fin + (size_t)b*(S*S);
  float s = 0.f;
  #pragma unroll
  for (int i=0;i<8;i++){
    uint4 w = *(const uint4*)(p + (i*256+tid)*8);
    s += bf2f((u16)(w.x&0xFFFFu)) + bf2f((u16)(w.x>>16))
       + bf2f((u16)(w.y&0xFFFFu)) + bf2f((u16)(w.y>>16))
       + bf2f((u16)(w.z&0xFFFFu)) + bf2f((u16)(w.z>>16))
       + bf2f((u16)(w.w&0xFFFFu)) + bf2f((u16)(w.w>>16));
  }
  for (int o=1;o<64;o<<=1) s += __shfl_xor(s,o);
  if (lane==0) red[wid] = s;
  float sl = (tid < 127) ? scales[(size_t)b*127 + tid] : 0.f;
  for (int o=1;o<64;o<<=1) sl += __shfl_xor(sl,o);
  if (lane==0) red[4+wid] = sl;
  __syncthreads();
  if (tid==0){
    float tot = red[0]+red[1]+red[2]+red[3];
    float ssum = red[4]+red[5]+red[6]+red[7];
    res[b] = logf(tot) + ssum;
  }
}

__global__ void k_final(const float* __restrict__ res, float* __restrict__ out){
  if (threadIdx.x==0){
    float s = 0.f;
    for (int i=0;i<B;i++) s += res[i];
    out[0] = s;
  }
}

extern "C" void kernel_launch(void* const* d_in, const int* in_sizes, int n_in,
                              void* d_out, int out_size, void* d_ws, size_t ws_size,
                              hipStream_t stream){
  const int*   text      = (const int*)d_in[0];
  const int*   w2s       = (const int*)d_in[1];
  const float* start_emb = (const float*)d_in[2];
  const float* start_w1  = (const float*)d_in[3];
  const float* start_b1  = (const float*)d_in[4];
  const float* start_w2  = (const float*)d_in[5];
  const float* start_b2  = (const float*)d_in[6];
  const float* start_wo  = (const float*)d_in[7];
  const float* start_bo  = (const float*)d_in[8];
  const float* state_emb = (const float*)d_in[9];
  const float* trans_w1  = (const float*)d_in[10];
  const float* trans_b1  = (const float*)d_in[11];
  const float* trans_w2  = (const float*)d_in[12];
  const float* trans_b2  = (const float*)d_in[13];
  const float* trans_wo  = (const float*)d_in[14];
  const float* trans_bo  = (const float*)d_in[15];
  const float* pre_emb   = (const float*)d_in[16];
  const float* term_w1   = (const float*)d_in[17];
  const float* term_b1   = (const float*)d_in[18];
  const float* term_w2   = (const float*)d_in[19];
  const float* term_b2   = (const float*)d_in[20];
  const float* term_wo   = (const float*)d_in[21];
  const float* term_bo   = (const float*)d_in[22];

  char* ws = (char*)d_ws;
  size_t off = 0;
  auto alloc = [&](size_t bytes)->char*{ char* p = ws + off; off += (bytes + 255) & ~(size_t)255; return p; };
  u16*   embb     = (u16*)  alloc(sizeof(u16)*3*(size_t)C*H);
  u16*   h1b      = (u16*)  alloc(sizeof(u16)*3*(size_t)C*H);
  u16*   h2b      = (u16*)  alloc(sizeof(u16)*3*(size_t)C*H);
  u16*   wt       = (u16*)  alloc(sizeof(u16)*6*(size_t)H*H);
  float* start_lp = (float*)alloc(sizeof(float)*C);
  float* shift    = (float*)alloc(sizeof(float)*C);
  float* shiftp   = (float*)alloc(sizeof(float)*(size_t)C*NR);
  float* sumexp   = (float*)alloc(sizeof(float)*(size_t)C*NR);
  float* lse      = (float*)alloc(sizeof(float)*C);
  float* resb     = (float*)alloc(sizeof(float)*B);
  float* scales   = (float*)alloc(sizeof(float)*(size_t)B*127);
  u16*   P        = (u16*)  alloc(sizeof(u16)*(size_t)C*C);
  u16*   wotb     = (u16*)  alloc(sizeof(u16)*(size_t)VP*H);
  u16*   wottr    = (u16*)  alloc(sizeof(u16)*(size_t)C*H);
  float* obs      = (float*)alloc(sizeof(float)*(size_t)B*T*S);
  u16*   potS     = (u16*)  alloc(sizeof(u16)*(size_t)B*128*S*S);   // level-0 tiles
  u16*   treeA    = (u16*)  alloc(sizeof(u16)*(size_t)B*64*S*S);
  u16*   treeB    = (u16*)  alloc(sizeof(u16)*(size_t)B*32*S*S);
  u16*   EM       = (u16*)potS;    // bf16 EM [VP][C], dead before k_pot writes potS
  float* TL       = (float*)treeA; // f32 TL [C][C] = 4MB, dead before tree level 1
  u16*   D        = (u16*)((char*)treeA + sizeof(float)*(size_t)C*C); // bf16 [VP][C], in treeA[4MB..24.7MB)
  (void)ws_size; (void)in_sizes; (void)n_in; (void)out_size;

  u16* embb0 = embb, *embb1 = embb + (size_t)C*H, *embb2 = embb + 2*(size_t)C*H;
  u16* h1b0 = h1b, *h1b1 = h1b + (size_t)C*H, *h1b2 = h1b + 2*(size_t)C*H;
  u16* h2b0 = h2b, *h2b1 = h2b + (size_t)C*H, *h2b2 = h2b + 2*(size_t)C*H;

  hipMemsetAsync(D, 0, sizeof(u16)*(size_t)VP*C, stream);

  Cvt3 cv; cv.s0 = start_emb; cv.s1 = state_emb; cv.s2 = pre_emb;
  cv.d0 = embb0; cv.d1 = embb1; cv.d2 = embb2;
  k_cvt3<<<dim3(C*H/(256*8), 3), dim3(256), 0, stream>>>(cv);

  T6 t6;
  t6.s[0]=start_w1; t6.s[1]=start_w2; t6.s[2]=trans_w1; t6.s[3]=trans_w2; t6.s[4]=term_w1; t6.s[5]=term_w2;
  for (int i=0;i<6;i++) t6.d[i] = wt + (size_t)i*H*H;
  k_transpose6<<<dim3(H/32, H/32, 6), dim3(32,8), 0, stream>>>(t6);

  M3 l1;
  l1.A[0]=embb0; l1.A[1]=embb1; l1.A[2]=embb2;
  l1.W[0]=wt;    l1.W[1]=wt+2*(size_t)H*H; l1.W[2]=wt+4*(size_t)H*H;
  l1.bias[0]=start_b1; l1.bias[1]=trans_b1; l1.bias[2]=term_b1;
  l1.R[0]=l1.R[1]=l1.R[2]=nullptr;
  l1.O[0]=h1b0; l1.O[1]=h1b1; l1.O[2]=h1b2;
  k_mlpg<0><<<dim3(H/128, C/128, 3), dim3(256), 0, stream>>>(l1);

  M3 l2;
  l2.A[0]=h1b0; l2.A[1]=h1b1; l2.A[2]=h1b2;
  l2.W[0]=wt+(size_t)H*H; l2.W[1]=wt+3*(size_t)H*H; l2.W[2]=wt+5*(size_t)H*H;
  l2.bias[0]=start_b2; l2.bias[1]=trans_b2; l2.bias[2]=term_b2;
  l2.R[0]=embb0; l2.R[1]=embb1; l2.R[2]=embb2;
  l2.O[0]=h2b0; l2.O[1]=h2b1; l2.O[2]=h2b2;
  k_mlpg<1><<<dim3(H/128, C/128, 3), dim3(256), 0, stream>>>(l2);

  k_start<<<dim3(1), dim3(1024), 0, stream>>>(h2b0, start_wo, start_bo, start_lp);
  k_transpose<<<dim3(VP/32, H/32), dim3(32,8), 0, stream>>>(term_wo, wotb, V);
  k_transpose<<<dim3(C/32, H/32), dim3(32,8), 0, stream>>>(trans_wo, wottr, C);
  // transition logits (f32) + row softmax -> P
  k_gemm<0,0><<<dim3(C/128, C/128), dim3(256), 0, stream>>>(h2b1, wottr, trans_bo, C, TL, C);
  k_softmax<<<dim3(C), dim3(256), 0, stream>>>(TL, P);
  // emission logits EM[v][c] bf16, row bias bo[v]
  k_gemm<1,1><<<dim3(C/128, VP/128), dim3(256), 0, stream>>>(wotb, h2b2, term_bo, V, EM, C);
  // exact column-max -> shift
  k_colmax<<<dim3(C/256, NR), dim3(256), 0, stream>>>(EM, shiftp);
  k_shiftc<<<dim3((C+255)/256), dim3(256), 0, stream>>>(shiftp, shift);
  // masked LSE via idempotent scatter + dense colsum (no atomics)
  k_scatter<<<dim3(V*S/256), dim3(256), 0, stream>>>(w2s, EM, shift, D);
  k_colsum<<<dim3(C/256, NR), dim3(256), 0, stream>>>(D, sumexp);
  k_lse<<<dim3((C+255)/256), dim3(256), 0, stream>>>(shift, sumexp, lse);
  k_obs<<<dim3(B*T), dim3(128), 0, stream>>>(text, w2s, EM, lse, obs);
  k_pot<<<dim3(128, B), dim3(256), 0, stream>>>(text, w2s, start_lp, obs, P, potS);

  // product tree: 128 -> 64 -> 32 -> 16 -> 8 -> 4 -> 2 -> 1
  {
    u16* lin = potS;
    u16* bufs[2] = { treeA, treeB };
    int nin = 128, soff = 0, cur = 0;
    while (nin > 1){
      int nout = nin >> 1;
      k_pair<<<dim3(nout, B), dim3(256), 0, stream>>>(lin, bufs[cur], scales, nin, soff);
      lin = bufs[cur];
      cur ^= 1;
      soff += nout;
      nin = nout;
    }
    k_fin<<<dim3(B), dim3(256), 0, stream>>>(lin, scales, resb);
  }
  k_final<<<dim3(1), dim3(64), 0, stream>>>(resb, (float*)d_out);
}

// Round 10
// 280.191 us; speedup vs baseline: 1.6139x; 1.0497x over previous
//
#include <hip/hip_runtime.h>
#include <hip/hip_bf16.h>

#define V 10000
#define VP 10112
#define C 1024
#define S 128
#define H 256
#define B 16
#define T 128
#define NR 64       // colsum row-chunks
#define CHUNK 158   // VP / NR
#define NRP 158     // colmax partials = (VP/128)*2
#define LDK 40      // padded LDS row length (u16) for k_gemm
#define PITCH 136   // k_pair0 LDS tile pitch (u16): 272B = 17*16B (b128-aligned)

typedef unsigned short u16;
typedef unsigned int u32;
typedef __bf16 bf16x8 __attribute__((ext_vector_type(8)));
typedef float f32x4 __attribute__((ext_vector_type(4)));

static __device__ __forceinline__ float bf2f(u16 x){ return __uint_as_float(((u32)x)<<16); }
static __device__ __forceinline__ u16 f2bf(float f){ u32 u=__float_as_uint(f); return (u16)((u + 0x7FFFu + ((u>>16)&1u))>>16); }

// ---------------- batched f32 -> bf16 convert (3 embeddings, C*H each) ----------------
struct Cvt3 { const float* s0; const float* s1; const float* s2; u16* d0; u16* d1; u16* d2; };
__global__ __launch_bounds__(256) void k_cvt3(Cvt3 a){
  const float* s = (blockIdx.y==0)? a.s0 : (blockIdx.y==1)? a.s1 : a.s2;
  u16* d = (blockIdx.y==0)? a.d0 : (blockIdx.y==1)? a.d1 : a.d2;
  int i = (blockIdx.x*256 + threadIdx.x)*8;
  float4 x0 = *(const float4*)(s+i);
  float4 x1 = *(const float4*)(s+i+4);
  u16 h[8] = {f2bf(x0.x),f2bf(x0.y),f2bf(x0.z),f2bf(x0.w),f2bf(x1.x),f2bf(x1.y),f2bf(x1.z),f2bf(x1.w)};
  *(uint4*)(d+i) = *(uint4*)h;
}

// ---------------- transpose src (H,N) f32 -> dst (NP,H) bf16, zero-padded ----------------
__global__ __launch_bounds__(256) void k_transpose(const float* __restrict__ src, u16* __restrict__ dst, int N){
  __shared__ float tile[32][33];
  int v0 = blockIdx.x*32, k0 = blockIdx.y*32;
  int tx = threadIdx.x, ty = threadIdx.y; // 32 x 8
  for (int i=0;i<32;i+=8){
    int k = k0+ty+i, v = v0+tx;
    tile[ty+i][tx] = (v < N) ? src[(size_t)k*N + v] : 0.f;
  }
  __syncthreads();
  for (int i=0;i<32;i+=8){
    int v = v0+ty+i, k = k0+tx;
    dst[(size_t)v*H + k] = f2bf(tile[tx][ty+i]);
  }
}

// ---------------- batched transpose of six (H,H) f32 weights -> bf16 [j][k] ----------------
struct T6 { const float* s[6]; u16* d[6]; };
__global__ __launch_bounds__(256) void k_transpose6(T6 a){
  const float* src = a.s[blockIdx.z];
  u16* dst = a.d[blockIdx.z];
  __shared__ float tile[32][33];
  int v0 = blockIdx.x*32, k0 = blockIdx.y*32;
  int tx = threadIdx.x, ty = threadIdx.y; // 32 x 8
  for (int i=0;i<32;i+=8){
    int k = k0+ty+i, v = v0+tx;
    tile[ty+i][tx] = src[(size_t)k*H + v];
  }
  __syncthreads();
  for (int i=0;i<32;i+=8){
    int v = v0+ty+i, k = k0+tx;
    dst[(size_t)v*H + k] = f2bf(tile[tx][ty+i]);
  }
}

// ---------------- batched MLP layer (3 MLPs via blockIdx.z), 128x128 MFMA tile ----------------
struct M3 { const u16* A[3]; const u16* W[3]; const float* bias[3]; const u16* R[3]; u16* O[3]; };
template<int RESID>
__global__ __launch_bounds__(256) void k_mlpg(M3 a){
  const int z = blockIdx.z;
  const u16* A  = a.A[z];
  const u16* BT = a.W[z];
  const float* bias = a.bias[z];
  const u16* Rm = a.R[z];
  u16* O = a.O[z];
  __shared__ u16 As[128*LDK];
  __shared__ u16 Bs[128*LDK];
  const int tid = threadIdx.x;
  const int lane = tid & 63, wave = tid >> 6;
  const int wm = wave >> 1, wn = wave & 1;
  const int m0 = blockIdx.y * 128, n0 = blockIdx.x * 128;
  const int lr = lane & 15, lg = lane >> 4;
  f32x4 acc[4][4] = {};
  const int sr = tid >> 1, sh = (tid & 1) * 16;
  for (int ks = 0; ks < H; ks += 32){
    const u16* ga = A  + (size_t)(m0 + sr)*H + ks + sh;
    const u16* gb = BT + (size_t)(n0 + sr)*H + ks + sh;
    uint4 a0 = *(const uint4*)ga;
    uint4 a1 = *(const uint4*)(ga + 8);
    uint4 b0 = *(const uint4*)gb;
    uint4 b1 = *(const uint4*)(gb + 8);
    __syncthreads();
    *(uint4*)&As[sr*LDK + sh]     = a0;
    *(uint4*)&As[sr*LDK + sh + 8] = a1;
    *(uint4*)&Bs[sr*LDK + sh]     = b0;
    *(uint4*)&Bs[sr*LDK + sh + 8] = b1;
    __syncthreads();
    bf16x8 af[4], bfr[4];
    #pragma unroll
    for (int m=0;m<4;m++) af[m]  = *(const bf16x8*)&As[(wm*64 + m*16 + lr)*LDK + lg*8];
    #pragma unroll
    for (int n=0;n<4;n++) bfr[n] = *(const bf16x8*)&Bs[(wn*64 + n*16 + lr)*LDK + lg*8];
    #pragma unroll
    for (int m=0;m<4;m++)
      #pragma unroll
      for (int n=0;n<4;n++)
        acc[m][n] = __builtin_amdgcn_mfma_f32_16x16x32_bf16(af[m], bfr[n], acc[m][n], 0,0,0);
  }
  #pragma unroll
  for (int m=0;m<4;m++){
    int r_g = m0 + wm*64 + m*16 + lg*4;
    #pragma unroll
    for (int n=0;n<4;n++){
      int n_g = n0 + wn*64 + n*16 + lr;
      float bv = bias[n_g];
      #pragma unroll
      for (int reg=0; reg<4; reg++){
        int r = r_g + reg;
        float val = acc[m][n][reg] + bv;
        if (RESID) val += bf2f(Rm[(size_t)r*H + n_g]);
        val = fmaxf(val, 0.f);
        O[(size_t)r*H + n_g] = f2bf(val);
      }
    }
  }
}

// ---------------- start head + log_softmax over C (bf16 h2) ----------------
__global__ __launch_bounds__(1024) void k_start(
    const u16* __restrict__ h2, const float* __restrict__ wo, const float* __restrict__ bo,
    float* __restrict__ start_lp){
  const int c = threadIdx.x;
  const int lane = c & 63, wid = c >> 6;
  __shared__ float red[16];
  __shared__ float Ms, Zs;
  float acc = bo[0];
  const u16* row = h2 + (size_t)c*H;
  for (int k=0;k<H;k+=8){
    uint4 hv = *(const uint4*)(row+k);
    float4 w0 = *(const float4*)(wo+k);
    float4 w1 = *(const float4*)(wo+k+4);
    acc = fmaf(bf2f((u16)(hv.x&0xFFFFu)), w0.x, acc);
    acc = fmaf(bf2f((u16)(hv.x>>16)),     w0.y, acc);
    acc = fmaf(bf2f((u16)(hv.y&0xFFFFu)), w0.z, acc);
    acc = fmaf(bf2f((u16)(hv.y>>16)),     w0.w, acc);
    acc = fmaf(bf2f((u16)(hv.z&0xFFFFu)), w1.x, acc);
    acc = fmaf(bf2f((u16)(hv.z>>16)),     w1.y, acc);
    acc = fmaf(bf2f((u16)(hv.w&0xFFFFu)), w1.z, acc);
    acc = fmaf(bf2f((u16)(hv.w>>16)),     w1.w, acc);
  }
  float m = acc;
  for (int o=1;o<64;o<<=1) m = fmaxf(m, __shfl_xor(m,o));
  if (lane==0) red[wid]=m;
  __syncthreads();
  if (c==0){ float t=red[0]; for(int i=1;i<16;i++) t=fmaxf(t,red[i]); Ms=t; }
  __syncthreads();
  float M = Ms;
  float e = expf(acc - M);
  float sum = e;
  for (int o=1;o<64;o<<=1) sum += __shfl_xor(sum,o);
  __syncthreads();
  if (lane==0) red[wid]=sum;
  __syncthreads();
  if (c==0){ float t=0.f; for(int i=0;i<16;i++) t+=red[i]; Zs=t; }
  __syncthreads();
  start_lp[c] = acc - (M + logf(Zs));
}

// ---------------- generic 128x128-tile MFMA GEMM: out = A(M,H) @ BT(N,H)^T + bias ----------------
// COLMAX=1: also writes per-(block-row-half) column-max partials to cmax[(by*2+wm)*C + col].
template<int BIAS_ROW, int BF16OUT, int COLMAX>
__global__ __launch_bounds__(256) void k_gemm(
    const u16* __restrict__ A, const u16* __restrict__ BT,
    const float* __restrict__ bias, int biasBound,
    void* __restrict__ outp, int ldout, float* __restrict__ cmax){
  __shared__ u16 As[128*LDK];
  __shared__ u16 Bs[128*LDK];
  const int tid = threadIdx.x;
  const int lane = tid & 63, wave = tid >> 6;
  const int wm = wave >> 1, wn = wave & 1;
  const int m0 = blockIdx.y * 128, n0 = blockIdx.x * 128;
  const int lr = lane & 15, lg = lane >> 4;
  f32x4 acc[4][4] = {};
  const int sr = tid >> 1, sh = (tid & 1) * 16;
  for (int ks = 0; ks < H; ks += 32){
    const u16* ga = A  + (size_t)(m0 + sr)*H + ks + sh;
    const u16* gb = BT + (size_t)(n0 + sr)*H + ks + sh;
    uint4 a0 = *(const uint4*)ga;
    uint4 a1 = *(const uint4*)(ga + 8);
    uint4 b0 = *(const uint4*)gb;
    uint4 b1 = *(const uint4*)(gb + 8);
    __syncthreads();
    *(uint4*)&As[sr*LDK + sh]     = a0;
    *(uint4*)&As[sr*LDK + sh + 8] = a1;
    *(uint4*)&Bs[sr*LDK + sh]     = b0;
    *(uint4*)&Bs[sr*LDK + sh + 8] = b1;
    __syncthreads();
    bf16x8 af[4], bfr[4];
    #pragma unroll
    for (int m=0;m<4;m++) af[m]  = *(const bf16x8*)&As[(wm*64 + m*16 + lr)*LDK + lg*8];
    #pragma unroll
    for (int n=0;n<4;n++) bfr[n] = *(const bf16x8*)&Bs[(wn*64 + n*16 + lr)*LDK + lg*8];
    #pragma unroll
    for (int m=0;m<4;m++)
      #pragma unroll
      for (int n=0;n<4;n++)
        acc[m][n] = __builtin_amdgcn_mfma_f32_16x16x32_bf16(af[m], bfr[n], acc[m][n], 0,0,0);
  }
  float cmx[4] = {-1e30f,-1e30f,-1e30f,-1e30f};
  #pragma unroll
  for (int m=0;m<4;m++){
    int r_g = m0 + wm*64 + m*16 + lg*4;
    #pragma unroll
    for (int n=0;n<4;n++){
      int n_g = n0 + wn*64 + n*16 + lr;
      float bcol = BIAS_ROW ? 0.f : bias[n_g];
      #pragma unroll
      for (int reg=0; reg<4; reg++){
        int r = r_g + reg;
        float bv = BIAS_ROW ? ((r < biasBound) ? bias[r] : 0.f) : bcol;
        float val = acc[m][n][reg] + bv;
        if (COLMAX) cmx[n] = fmaxf(cmx[n], val);
        if (BF16OUT) ((u16*)outp)[(size_t)r*ldout + n_g] = f2bf(val);
        else         ((float*)outp)[(size_t)r*ldout + n_g] = val;
      }
    }
  }
  if (COLMAX){
    #pragma unroll
    for (int n=0;n<4;n++){
      float m_ = cmx[n];
      m_ = fmaxf(m_, __shfl_xor(m_,16));
      m_ = fmaxf(m_, __shfl_xor(m_,32));
      if (lg==0) cmax[((size_t)(blockIdx.y*2 + wm))*C + n0 + wn*64 + n*16 + lr] = m_;
    }
  }
}

// ---------------- row softmax: TL (C,C) f32 -> P (C,C) bf16 ----------------
__global__ __launch_bounds__(256) void k_softmax(const float* __restrict__ TL, u16* __restrict__ P){
  const int c = blockIdx.x;
  const int tid = threadIdx.x, lane = tid & 63, wid = tid >> 6;
  __shared__ float red[4];
  __shared__ float Ms, Zs;
  float4 v = ((const float4*)(TL + (size_t)c*C))[tid];
  float m = fmaxf(fmaxf(v.x,v.y), fmaxf(v.z,v.w));
  for (int o=1;o<64;o<<=1) m = fmaxf(m, __shfl_xor(m,o));
  if (lane==0) red[wid] = m;
  __syncthreads();
  if (tid==0) Ms = fmaxf(fmaxf(red[0],red[1]), fmaxf(red[2],red[3]));
  __syncthreads();
  float M = Ms;
  float e0 = expf(v.x-M), e1 = expf(v.y-M), e2 = expf(v.z-M), e3 = expf(v.w-M);
  float s = (e0+e1)+(e2+e3);
  for (int o=1;o<64;o<<=1) s += __shfl_xor(s,o);
  if (lane==0) red[wid] = s;
  __syncthreads();
  if (tid==0) Zs = red[0]+red[1]+red[2]+red[3];
  __syncthreads();
  float inv = 1.f/Zs;
  u32 lo = (u32)f2bf(e0*inv) | ((u32)f2bf(e1*inv)<<16);
  u32 hi = (u32)f2bf(e2*inv) | ((u32)f2bf(e3*inv)<<16);
  *(uint2*)(P + (size_t)c*C + tid*4) = make_uint2(lo, hi);
}

// ---------------- combine partials: shift[c] = max_r cmax[r][c] (exact colmax) ----------------
__global__ void k_shiftc(const float* __restrict__ shiftp, float* __restrict__ shift){
  int c = threadIdx.x + blockIdx.x*blockDim.x;
  if (c < C){
    float m = -1e30f;
    for (int r=0;r<NRP;r++) m = fmaxf(m, shiftp[(size_t)r*C + c]);
    shift[c] = m;
  }
}

// ---------------- scatter D[v][c] = exp(EM[v][c] - shift[c]) (bf16, idempotent dedupe) ----------------
__global__ __launch_bounds__(256) void k_scatter(
    const int* __restrict__ w2s, const u16* __restrict__ EM,
    const float* __restrict__ shift, u16* __restrict__ D){
  int idx = blockIdx.x*256 + threadIdx.x;   // over V*S
  int v = idx >> 7;
  const int c = w2s[idx];
  float val = bf2f(EM[(size_t)v*C + c]);
  D[(size_t)v*C + c] = f2bf(expf(val - shift[c]));
}

// ---------------- column-sum of D over row chunks -> sumexp[chunk*C + c] ----------------
__global__ __launch_bounds__(256) void k_colsum(const u16* __restrict__ D, float* __restrict__ sumexp){
  const int c = blockIdx.x*256 + threadIdx.x;
  const int v0 = blockIdx.y*CHUNK;
  float s = 0.f;
  const u16* p = D + (size_t)v0*C + c;
  #pragma unroll 2
  for (int i=0;i<CHUNK;i++){ s += bf2f(p[0]); p += C; }
  sumexp[(size_t)blockIdx.y*C + c] = s;
}

__global__ void k_lse(const float* __restrict__ shift, const float* __restrict__ sumexp, float* __restrict__ lse){
  int c = threadIdx.x + blockIdx.x*blockDim.x;
  if (c < C){
    float s = 0.f;
    for (int r=0;r<NR;r++) s += sumexp[(size_t)r*C + c];
    lse[c] = shift[c] + logf(s);
  }
}

// ---------------- obs[b,t,s] = EM[text,c] - lse[c] ----------------
__global__ __launch_bounds__(128) void k_obs(
    const int* __restrict__ text, const int* __restrict__ w2s,
    const u16* __restrict__ EM, const float* __restrict__ lse,
    float* __restrict__ obs){
  const int bt = blockIdx.x;
  const int s = threadIdx.x;
  const int v = text[bt];
  const int c = w2s[(size_t)v*S + s];
  obs[(size_t)bt*S + s] = bf2f(EM[(size_t)v*C + c]) - lse[c];
}

// ---------------- fused level-0 gather + first pair product ----------------
// out[j] = tile_{2j+1} . tile_{2j}, tiles gathered into LDS (never materialized in HBM).
// tile_t[sn][sp] = P[cp_t[sp], cn_t[sn]] * eo_t[sn] * (t==0 ? a0[sp] : 1); t==127 -> I.
__global__ __launch_bounds__(256) void k_pair0(
    const int* __restrict__ text, const int* __restrict__ w2s,
    const float* __restrict__ start_lp, const float* __restrict__ obs,
    const u16* __restrict__ P, u16* __restrict__ out, float* __restrict__ scales){
  const int j = blockIdx.x;   // 0..63
  const int b = blockIdx.y;
  const int t0 = 2*j, t1 = 2*j+1;
  __shared__ __align__(16) u16 tA[128*PITCH];  // tile t1, A layout [sn][sp]
  __shared__ __align__(16) u16 tB[128*PITCH];  // tile t0, BT layout [sp][sn]
  __shared__ int cp0[S], cn0[S], cp1[S], cn1[S];
  __shared__ float eo0[S], eo1[S], a00[S];
  __shared__ float red[4];
  const int tid = threadIdx.x;
  if (tid < 128){
    int s = tid;
    int cpv = w2s[(size_t)text[b*T + t0]*S + s];
    cp0[s] = cpv;
    cn0[s] = w2s[(size_t)text[b*T + t0+1]*S + s];
    eo0[s] = expf(obs[((size_t)b*T + t0 + 1)*S + s]);
    a00[s] = (t0==0) ? expf(start_lp[cpv] + obs[(size_t)(b*T)*S + s]) : 1.0f;
  } else if (t1 < 127){
    int s = tid-128;
    cp1[s] = w2s[(size_t)text[b*T + t1]*S + s];
    cn1[s] = w2s[(size_t)text[b*T + t1+1]*S + s];
    eo1[s] = expf(obs[((size_t)b*T + t1 + 1)*S + s]);
  }
  __syncthreads();
  const int sn = tid & 127, half = tid >> 7;
  {
    const float e = eo0[sn];
    for (int it=0; it<64; ++it){
      int sp = it*2 + half;
      float v = bf2f(P[(size_t)cp0[sp]*C + cn0[sn]]) * e * a00[sp];
      tB[sp*PITCH + sn] = f2bf(v);           // contiguous-sn LDS write
    }
  }
  if (t1 < 127){
    const float e = eo1[sn];
    for (int it=0; it<64; ++it){
      int sp = it*2 + half;
      tA[sn*PITCH + sp] = f2bf(bf2f(P[(size_t)cp1[sp]*C + cn1[sn]]) * e);
    }
  } else {
    for (int it=0; it<64; ++it){
      int sp = it*2 + half;
      tA[sn*PITCH + sp] = (sn==sp) ? (u16)0x3F80u : (u16)0u;
    }
  }
  __syncthreads();
  const int lane = tid & 63, wave = tid >> 6;
  const int wm = wave >> 1, wn = wave & 1;
  const int lr = lane & 15, lg = lane >> 4;
  f32x4 acc[4][4] = {};
  #pragma unroll
  for (int kc=0; kc<4; ++kc){
    bf16x8 af[4], bfr[4];
    #pragma unroll
    for (int m=0;m<4;m++) af[m]  = *(const bf16x8*)&tA[(wm*64+m*16+lr)*PITCH + kc*32 + lg*8];
    #pragma unroll
    for (int n=0;n<4;n++) bfr[n] = *(const bf16x8*)&tB[(wn*64+n*16+lr)*PITCH + kc*32 + lg*8];
    #pragma unroll
    for (int m=0;m<4;m++)
      #pragma unroll
      for (int n=0;n<4;n++)
        acc[m][n] = __builtin_amdgcn_mfma_f32_16x16x32_bf16(af[m], bfr[n], acc[m][n], 0,0,0);
  }
  float mx = 0.f;
  #pragma unroll
  for (int m=0;m<4;m++)
    #pragma unroll
    for (int n=0;n<4;n++)
      #pragma unroll
      for (int r=0;r<4;r++) mx = fmaxf(mx, acc[m][n][r]);
  for (int o=1;o<64;o<<=1) mx = fmaxf(mx, __shfl_xor(mx,o));
  if (lane==0) red[wave] = mx;
  __syncthreads();
  mx = fmaxf(fmaxf(red[0],red[1]), fmaxf(red[2],red[3]));
  const float sc = 1.0f / mx;
  if (tid==0) scales[(size_t)b*127 + j] = logf(mx);
  u16* Cg = out + ((size_t)b*64 + j)*(S*S);
  if (j & 1){
    #pragma unroll
    for (int m=0;m<4;m++){
      int rg = wm*64 + m*16 + lg*4;
      #pragma unroll
      for (int n=0;n<4;n++){
        int cg = wn*64 + n*16 + lr;
        #pragma unroll
        for (int r=0;r<4;r++) Cg[(size_t)(rg+r)*128 + cg] = f2bf(acc[m][n][r]*sc);
      }
    }
  } else {
    #pragma unroll
    for (int m=0;m<4;m++){
      int rg = wm*64 + m*16 + lg*4;
      #pragma unroll
      for (int n=0;n<4;n++){
        int cg = wn*64 + n*16 + lr;
        float v0=acc[m][n][0]*sc, v1=acc[m][n][1]*sc, v2=acc[m][n][2]*sc, v3=acc[m][n][3]*sc;
        u32 p0, p1;
        asm("v_cvt_pk_bf16_f32 %0, %1, %2" : "=v"(p0) : "v"(v0), "v"(v1));
        asm("v_cvt_pk_bf16_f32 %0, %1, %2" : "=v"(p1) : "v"(v2), "v"(v3));
        *(uint2*)(Cg + (size_t)cg*128 + rg) = make_uint2(p0, p1);
      }
    }
  }
}

// ---------------- tree pair-product: out[j] = in[2j+1] . in[2j] ----------------
__global__ __launch_bounds__(256) void k_pair(
    const u16* __restrict__ in, u16* __restrict__ out,
    float* __restrict__ scales, int nin, int soff){
  const int j = blockIdx.x;
  const int b = blockIdx.y;
  const int nout = nin >> 1;
  const u16* Ag = in + ((size_t)b*nin + 2*j+1)*(S*S);
  const u16* Bg = in + ((size_t)b*nin + 2*j  )*(S*S);
  u16* Cg = out + ((size_t)b*nout + j)*(S*S);
  const int tid = threadIdx.x;
  const int lane = tid & 63, wave = tid >> 6;
  const int wm = wave >> 1, wn = wave & 1;
  const int lr = lane & 15, lg = lane >> 4;
  f32x4 acc[4][4] = {};
  #pragma unroll
  for (int kc=0; kc<4; ++kc){
    bf16x8 af[4], bfr[4];
    #pragma unroll
    for (int m=0;m<4;m++) af[m]  = *(const bf16x8*)(Ag + (size_t)(wm*64+m*16+lr)*128 + kc*32 + lg*8);
    #pragma unroll
    for (int n=0;n<4;n++) bfr[n] = *(const bf16x8*)(Bg + (size_t)(wn*64+n*16+lr)*128 + kc*32 + lg*8);
    #pragma unroll
    for (int m=0;m<4;m++)
      #pragma unroll
      for (int n=0;n<4;n++)
        acc[m][n] = __builtin_amdgcn_mfma_f32_16x16x32_bf16(af[m], bfr[n], acc[m][n], 0,0,0);
  }
  __shared__ float red[4];
  float mx = 0.f;
  #pragma unroll
  for (int m=0;m<4;m++)
    #pragma unroll
    for (int n=0;n<4;n++)
      #pragma unroll
      for (int r=0;r<4;r++) mx = fmaxf(mx, acc[m][n][r]);
  for (int o=1;o<64;o<<=1) mx = fmaxf(mx, __shfl_xor(mx,o));
  if (lane==0) red[wave] = mx;
  __syncthreads();
  mx = fmaxf(fmaxf(red[0],red[1]), fmaxf(red[2],red[3]));
  const float sc = 1.0f / mx;
  if (tid==0) scales[(size_t)b*127 + soff + j] = logf(mx);
  if (j & 1){
    #pragma unroll
    for (int m=0;m<4;m++){
      int rg = wm*64 + m*16 + lg*4;
      #pragma unroll
      for (int n=0;n<4;n++){
        int cg = wn*64 + n*16 + lr;
        #pragma unroll
        for (int r=0;r<4;r++) Cg[(size_t)(rg+r)*128 + cg] = f2bf(acc[m][n][r]*sc);
      }
    }
  } else {
    #pragma unroll
    for (int m=0;m<4;m++){
      int rg = wm*64 + m*16 + lg*4;
      #pragma unroll
      for (int n=0;n<4;n++){
        int cg = wn*64 + n*16 + lr;
        float v0=acc[m][n][0]*sc, v1=acc[m][n][1]*sc, v2=acc[m][n][2]*sc, v3=acc[m][n][3]*sc;
        u32 p0, p1;
        asm("v_cvt_pk_bf16_f32 %0, %1, %2" : "=v"(p0) : "v"(v0), "v"(v1));
        asm("v_cvt_pk_bf16_f32 %0, %1, %2" : "=v"(p1) : "v"(v2), "v"(v3));
        *(uint2*)(Cg + (size_t)cg*128 + rg) = make_uint2(p0, p1);
      }
    }
  }
}

// ---------------- final: res[b] = log(sum entries) + sum(scales) ----------------
__global__ __launch_bounds__(256) void k_fin(
    const u16* __restrict__ fin, const float* __restrict__ scales, float* __restrict__ res){
  const int b = blockIdx.x;
  const int tid = threadIdx.x, lane = tid & 63, wid = tid >> 6;
  __shared__ float red[8];
  const u16* p = fin + (size_t)b*(S*S);
  float s = 0.f;
  #pragma unroll
  for (int i=0;i<8;i++){
    uint4 w = *(const uint4*)(p + (i*256+tid)*8);
    s += bf2f((u16)(w.x&0xFFFFu)) + bf2f((u16)(w.x>>16))
       + bf2f((u16)(w.y&0xFFFFu)) + bf2f((u16)(w.y>>16))
       + bf2f((u16)(w.z&0xFFFFu)) + bf2f((u16)(w.z>>16))
       + bf2f((u16)(w.w&0xFFFFu)) + bf2f((u16)(w.w>>16));
  }
  for (int o=1;o<64;o<<=1) s += __shfl_xor(s,o);
  if (lane==0) red[wid] = s;
  float sl = (tid < 127) ? scales[(size_t)b*127 + tid] : 0.f;
  for (int o=1;o<64;o<<=1) sl += __shfl_xor(sl,o);
  if (lane==0) red[4+wid] = sl;
  __syncthreads();
  if (tid==0){
    float tot = red[0]+red[1]+red[2]+red[3];
    float ssum = red[4]+red[5]+red[6]+red[7];
    res[b] = logf(tot) + ssum;
  }
}

__global__ void k_final(const float* __restrict__ res, float* __restrict__ out){
  if (threadIdx.x==0){
    float s = 0.f;
    for (int i=0;i<B;i++) s += res[i];
    out[0] = s;
  }
}

extern "C" void kernel_launch(void* const* d_in, const int* in_sizes, int n_in,
                              void* d_out, int out_size, void* d_ws, size_t ws_size,
                              hipStream_t stream){
  const int*   text      = (const int*)d_in[0];
  const int*   w2s       = (const int*)d_in[1];
  const float* start_emb = (const float*)d_in[2];
  const float* start_w1  = (const float*)d_in[3];
  const float* start_b1  = (const float*)d_in[4];
  const float* start_w2  = (const float*)d_in[5];
  const float* start_b2  = (const float*)d_in[6];
  const float* start_wo  = (const float*)d_in[7];
  const float* start_bo  = (const float*)d_in[8];
  const float* state_emb = (const float*)d_in[9];
  const float* trans_w1  = (const float*)d_in[10];
  const float* trans_b1  = (const float*)d_in[11];
  const float* trans_w2  = (const float*)d_in[12];
  const float* trans_b2  = (const float*)d_in[13];
  const float* trans_wo  = (const float*)d_in[14];
  const float* trans_bo  = (const float*)d_in[15];
  const float* pre_emb   = (const float*)d_in[16];
  const float* term_w1   = (const float*)d_in[17];
  const float* term_b1   = (const float*)d_in[18];
  const float* term_w2   = (const float*)d_in[19];
  const float* term_b2   = (const float*)d_in[20];
  const float* term_wo   = (const float*)d_in[21];
  const float* term_bo   = (const float*)d_in[22];

  char* ws = (char*)d_ws;
  size_t off = 0;
  auto alloc = [&](size_t bytes)->char*{ char* p = ws + off; off += (bytes + 255) & ~(size_t)255; return p; };
  u16*   embb     = (u16*)  alloc(sizeof(u16)*3*(size_t)C*H);
  u16*   h1b      = (u16*)  alloc(sizeof(u16)*3*(size_t)C*H);
  u16*   h2b      = (u16*)  alloc(sizeof(u16)*3*(size_t)C*H);
  u16*   wt       = (u16*)  alloc(sizeof(u16)*6*(size_t)H*H);
  float* start_lp = (float*)alloc(sizeof(float)*C);
  float* shift    = (float*)alloc(sizeof(float)*C);
  float* shiftp   = (float*)alloc(sizeof(float)*(size_t)C*NRP);
  float* sumexp   = (float*)alloc(sizeof(float)*(size_t)C*NR);
  float* lse      = (float*)alloc(sizeof(float)*C);
  float* resb     = (float*)alloc(sizeof(float)*B);
  float* scales   = (float*)alloc(sizeof(float)*(size_t)B*127);
  u16*   P        = (u16*)  alloc(sizeof(u16)*(size_t)C*C);
  u16*   wotb     = (u16*)  alloc(sizeof(u16)*(size_t)VP*H);
  u16*   wottr    = (u16*)  alloc(sizeof(u16)*(size_t)C*H);
  float* obs      = (float*)alloc(sizeof(float)*(size_t)B*T*S);
  u16*   EM       = (u16*)  alloc(sizeof(u16)*(size_t)VP*C);        // bf16 EM [VP][C]
  u16*   treeA    = (u16*)  alloc(sizeof(u16)*(size_t)B*64*S*S);    // 32MB
  u16*   treeB    = (u16*)  alloc(sizeof(u16)*(size_t)B*32*S*S);    // 16MB
  float* TL       = (float*)treeA; // f32 TL [C][C] = 4MB, dead before k_pair0 writes treeA
  u16*   D        = (u16*)((char*)treeA + sizeof(float)*(size_t)C*C); // bf16 [VP][C], treeA[4MB..24.7MB)
  (void)ws_size; (void)in_sizes; (void)n_in; (void)out_size;

  u16* embb0 = embb, *embb1 = embb + (size_t)C*H, *embb2 = embb + 2*(size_t)C*H;
  u16* h1b0 = h1b, *h1b1 = h1b + (size_t)C*H, *h1b2 = h1b + 2*(size_t)C*H;
  u16* h2b0 = h2b, *h2b1 = h2b + (size_t)C*H, *h2b2 = h2b + 2*(size_t)C*H;

  hipMemsetAsync(D, 0, sizeof(u16)*(size_t)VP*C, stream);

  Cvt3 cv; cv.s0 = start_emb; cv.s1 = state_emb; cv.s2 = pre_emb;
  cv.d0 = embb0; cv.d1 = embb1; cv.d2 = embb2;
  k_cvt3<<<dim3(C*H/(256*8), 3), dim3(256), 0, stream>>>(cv);

  T6 t6;
  t6.s[0]=start_w1; t6.s[1]=start_w2; t6.s[2]=trans_w1; t6.s[3]=trans_w2; t6.s[4]=term_w1; t6.s[5]=term_w2;
  for (int i=0;i<6;i++) t6.d[i] = wt + (size_t)i*H*H;
  k_transpose6<<<dim3(H/32, H/32, 6), dim3(32,8), 0, stream>>>(t6);

  M3 l1;
  l1.A[0]=embb0; l1.A[1]=embb1; l1.A[2]=embb2;
  l1.W[0]=wt;    l1.W[1]=wt+2*(size_t)H*H; l1.W[2]=wt+4*(size_t)H*H;
  l1.bias[0]=start_b1; l1.bias[1]=trans_b1; l1.bias[2]=term_b1;
  l1.R[0]=l1.R[1]=l1.R[2]=nullptr;
  l1.O[0]=h1b0; l1.O[1]=h1b1; l1.O[2]=h1b2;
  k_mlpg<0><<<dim3(H/128, C/128, 3), dim3(256), 0, stream>>>(l1);

  M3 l2;
  l2.A[0]=h1b0; l2.A[1]=h1b1; l2.A[2]=h1b2;
  l2.W[0]=wt+(size_t)H*H; l2.W[1]=wt+3*(size_t)H*H; l2.W[2]=wt+5*(size_t)H*H;
  l2.bias[0]=start_b2; l2.bias[1]=trans_b2; l2.bias[2]=term_b2;
  l2.R[0]=embb0; l2.R[1]=embb1; l2.R[2]=embb2;
  l2.O[0]=h2b0; l2.O[1]=h2b1; l2.O[2]=h2b2;
  k_mlpg<1><<<dim3(H/128, C/128, 3), dim3(256), 0, stream>>>(l2);

  k_start<<<dim3(1), dim3(1024), 0, stream>>>(h2b0, start_wo, start_bo, start_lp);
  k_transpose<<<dim3(VP/32, H/32), dim3(32,8), 0, stream>>>(term_wo, wotb, V);
  k_transpose<<<dim3(C/32, H/32), dim3(32,8), 0, stream>>>(trans_wo, wottr, C);
  // transition logits (f32) + row softmax -> P
  k_gemm<0,0,0><<<dim3(C/128, C/128), dim3(256), 0, stream>>>(h2b1, wottr, trans_bo, C, TL, C, nullptr);
  k_softmax<<<dim3(C), dim3(256), 0, stream>>>(TL, P);
  // emission logits EM[v][c] bf16, row bias bo[v], fused column-max partials
  k_gemm<1,1,1><<<dim3(C/128, VP/128), dim3(256), 0, stream>>>(wotb, h2b2, term_bo, V, EM, C, shiftp);
  k_shiftc<<<dim3((C+255)/256), dim3(256), 0, stream>>>(shiftp, shift);
  // masked LSE via idempotent scatter + dense colsum (no atomics)
  k_scatter<<<dim3(V*S/256), dim3(256), 0, stream>>>(w2s, EM, shift, D);
  k_colsum<<<dim3(C/256, NR), dim3(256), 0, stream>>>(D, sumexp);
  k_lse<<<dim3((C+255)/256), dim3(256), 0, stream>>>(shift, sumexp, lse);
  k_obs<<<dim3(B*T), dim3(128), 0, stream>>>(text, w2s, EM, lse, obs);

  // fused gather + level-1 product: 128 virtual tiles -> 64 tiles (treeA)
  k_pair0<<<dim3(64, B), dim3(256), 0, stream>>>(text, w2s, start_lp, obs, P, treeA, scales);

  // remaining tree: 64 -> 32 -> 16 -> 8 -> 4 -> 2 -> 1
  {
    u16* lin = treeA;
    u16* bufs[2] = { treeB, treeA };
    int nin = 64, soff = 64, cur = 0;
    while (nin > 1){
      int nout = nin >> 1;
      k_pair<<<dim3(nout, B), dim3(256), 0, stream>>>(lin, bufs[cur], scales, nin, soff);
      lin = bufs[cur];
      cur ^= 1;
      soff += nout;
      nin = nout;
    }
    k_fin<<<dim3(B), dim3(256), 0, stream>>>(lin, scales, resb);
  }
  k_final<<<dim3(1), dim3(64), 0, stream>>>(resb, (float*)d_out);
}

// Round 11
// 280.062 us; speedup vs baseline: 1.6146x; 1.0005x over previous
//
#include <hip/hip_runtime.h>
#include <hip/hip_bf16.h>

#define V 10000
#define VP 10112
#define C 1024
#define S 128
#define H 256
#define B 16
#define T 128
#define NR 64       // colsum row-chunks
#define CHUNK 158   // VP / NR
#define NRP 158     // colmax partials = (VP/128)*2
#define LDK 40      // padded LDS row length (u16) for k_gemm
#define PITCH 136   // k_pair0 LDS tile pitch (u16): 272B = 17*16B (b128-aligned)

typedef unsigned short u16;
typedef unsigned int u32;
typedef __bf16 bf16x8 __attribute__((ext_vector_type(8)));
typedef float f32x4 __attribute__((ext_vector_type(4)));

static __device__ __forceinline__ float bf2f(u16 x){ return __uint_as_float(((u32)x)<<16); }
static __device__ __forceinline__ u16 f2bf(float f){ u32 u=__float_as_uint(f); return (u16)((u + 0x7FFFu + ((u>>16)&1u))>>16); }

// ---------------- batched f32 -> bf16 convert (3 embeddings, C*H each) ----------------
struct Cvt3 { const float* s0; const float* s1; const float* s2; u16* d0; u16* d1; u16* d2; };
__global__ __launch_bounds__(256) void k_cvt3(Cvt3 a){
  const float* s = (blockIdx.y==0)? a.s0 : (blockIdx.y==1)? a.s1 : a.s2;
  u16* d = (blockIdx.y==0)? a.d0 : (blockIdx.y==1)? a.d1 : a.d2;
  int i = (blockIdx.x*256 + threadIdx.x)*8;
  float4 x0 = *(const float4*)(s+i);
  float4 x1 = *(const float4*)(s+i+4);
  u16 h[8] = {f2bf(x0.x),f2bf(x0.y),f2bf(x0.z),f2bf(x0.w),f2bf(x1.x),f2bf(x1.y),f2bf(x1.z),f2bf(x1.w)};
  *(uint4*)(d+i) = *(uint4*)h;
}

// ---------------- transpose src (H,N) f32 -> dst (NP,H) bf16, zero-padded ----------------
__global__ __launch_bounds__(256) void k_transpose(const float* __restrict__ src, u16* __restrict__ dst, int N){
  __shared__ float tile[32][33];
  int v0 = blockIdx.x*32, k0 = blockIdx.y*32;
  int tx = threadIdx.x, ty = threadIdx.y; // 32 x 8
  for (int i=0;i<32;i+=8){
    int k = k0+ty+i, v = v0+tx;
    tile[ty+i][tx] = (v < N) ? src[(size_t)k*N + v] : 0.f;
  }
  __syncthreads();
  for (int i=0;i<32;i+=8){
    int v = v0+ty+i, k = k0+tx;
    dst[(size_t)v*H + k] = f2bf(tile[tx][ty+i]);
  }
}

// ---------------- batched transpose of six (H,H) f32 weights -> bf16 [j][k] ----------------
struct T6 { const float* s[6]; u16* d[6]; };
__global__ __launch_bounds__(256) void k_transpose6(T6 a){
  const float* src = a.s[blockIdx.z];
  u16* dst = a.d[blockIdx.z];
  __shared__ float tile[32][33];
  int v0 = blockIdx.x*32, k0 = blockIdx.y*32;
  int tx = threadIdx.x, ty = threadIdx.y; // 32 x 8
  for (int i=0;i<32;i+=8){
    int k = k0+ty+i, v = v0+tx;
    tile[ty+i][tx] = src[(size_t)k*H + v];
  }
  __syncthreads();
  for (int i=0;i<32;i+=8){
    int v = v0+ty+i, k = k0+tx;
    dst[(size_t)v*H + k] = f2bf(tile[tx][ty+i]);
  }
}

// ---------------- batched MLP layer (3 MLPs via blockIdx.z), 128x128 MFMA tile ----------------
struct M3 { const u16* A[3]; const u16* W[3]; const float* bias[3]; const u16* R[3]; u16* O[3]; };
template<int RESID>
__global__ __launch_bounds__(256) void k_mlpg(M3 a){
  const int z = blockIdx.z;
  const u16* A  = a.A[z];
  const u16* BT = a.W[z];
  const float* bias = a.bias[z];
  const u16* Rm = a.R[z];
  u16* O = a.O[z];
  __shared__ u16 As[128*LDK];
  __shared__ u16 Bs[128*LDK];
  const int tid = threadIdx.x;
  const int lane = tid & 63, wave = tid >> 6;
  const int wm = wave >> 1, wn = wave & 1;
  const int m0 = blockIdx.y * 128, n0 = blockIdx.x * 128;
  const int lr = lane & 15, lg = lane >> 4;
  f32x4 acc[4][4] = {};
  const int sr = tid >> 1, sh = (tid & 1) * 16;
  for (int ks = 0; ks < H; ks += 32){
    const u16* ga = A  + (size_t)(m0 + sr)*H + ks + sh;
    const u16* gb = BT + (size_t)(n0 + sr)*H + ks + sh;
    uint4 a0 = *(const uint4*)ga;
    uint4 a1 = *(const uint4*)(ga + 8);
    uint4 b0 = *(const uint4*)gb;
    uint4 b1 = *(const uint4*)(gb + 8);
    __syncthreads();
    *(uint4*)&As[sr*LDK + sh]     = a0;
    *(uint4*)&As[sr*LDK + sh + 8] = a1;
    *(uint4*)&Bs[sr*LDK + sh]     = b0;
    *(uint4*)&Bs[sr*LDK + sh + 8] = b1;
    __syncthreads();
    bf16x8 af[4], bfr[4];
    #pragma unroll
    for (int m=0;m<4;m++) af[m]  = *(const bf16x8*)&As[(wm*64 + m*16 + lr)*LDK + lg*8];
    #pragma unroll
    for (int n=0;n<4;n++) bfr[n] = *(const bf16x8*)&Bs[(wn*64 + n*16 + lr)*LDK + lg*8];
    #pragma unroll
    for (int m=0;m<4;m++)
      #pragma unroll
      for (int n=0;n<4;n++)
        acc[m][n] = __builtin_amdgcn_mfma_f32_16x16x32_bf16(af[m], bfr[n], acc[m][n], 0,0,0);
  }
  #pragma unroll
  for (int m=0;m<4;m++){
    int r_g = m0 + wm*64 + m*16 + lg*4;
    #pragma unroll
    for (int n=0;n<4;n++){
      int n_g = n0 + wn*64 + n*16 + lr;
      float bv = bias[n_g];
      #pragma unroll
      for (int reg=0; reg<4; reg++){
        int r = r_g + reg;
        float val = acc[m][n][reg] + bv;
        if (RESID) val += bf2f(Rm[(size_t)r*H + n_g]);
        val = fmaxf(val, 0.f);
        O[(size_t)r*H + n_g] = f2bf(val);
      }
    }
  }
}

// ---------------- start head + log_softmax over C (bf16 h2) ----------------
__global__ __launch_bounds__(1024) void k_start(
    const u16* __restrict__ h2, const float* __restrict__ wo, const float* __restrict__ bo,
    float* __restrict__ start_lp){
  const int c = threadIdx.x;
  const int lane = c & 63, wid = c >> 6;
  __shared__ float red[16];
  __shared__ float Ms, Zs;
  float acc = bo[0];
  const u16* row = h2 + (size_t)c*H;
  for (int k=0;k<H;k+=8){
    uint4 hv = *(const uint4*)(row+k);
    float4 w0 = *(const float4*)(wo+k);
    float4 w1 = *(const float4*)(wo+k+4);
    acc = fmaf(bf2f((u16)(hv.x&0xFFFFu)), w0.x, acc);
    acc = fmaf(bf2f((u16)(hv.x>>16)),     w0.y, acc);
    acc = fmaf(bf2f((u16)(hv.y&0xFFFFu)), w0.z, acc);
    acc = fmaf(bf2f((u16)(hv.y>>16)),     w0.w, acc);
    acc = fmaf(bf2f((u16)(hv.z&0xFFFFu)), w1.x, acc);
    acc = fmaf(bf2f((u16)(hv.z>>16)),     w1.y, acc);
    acc = fmaf(bf2f((u16)(hv.w&0xFFFFu)), w1.z, acc);
    acc = fmaf(bf2f((u16)(hv.w>>16)),     w1.w, acc);
  }
  float m = acc;
  for (int o=1;o<64;o<<=1) m = fmaxf(m, __shfl_xor(m,o));
  if (lane==0) red[wid]=m;
  __syncthreads();
  if (c==0){ float t=red[0]; for(int i=1;i<16;i++) t=fmaxf(t,red[i]); Ms=t; }
  __syncthreads();
  float M = Ms;
  float e = expf(acc - M);
  float sum = e;
  for (int o=1;o<64;o<<=1) sum += __shfl_xor(sum,o);
  __syncthreads();
  if (lane==0) red[wid]=sum;
  __syncthreads();
  if (c==0){ float t=0.f; for(int i=0;i<16;i++) t+=red[i]; Zs=t; }
  __syncthreads();
  start_lp[c] = acc - (M + logf(Zs));
}

// ---------------- generic 128x128-tile MFMA GEMM: out = A(M,H) @ BT(N,H)^T + bias ----------------
// COLMAX=1: also writes per-(block-row-half) column-max partials to cmax[(by*2+wm)*C + col].
template<int BIAS_ROW, int BF16OUT, int COLMAX>
__global__ __launch_bounds__(256) void k_gemm(
    const u16* __restrict__ A, const u16* __restrict__ BT,
    const float* __restrict__ bias, int biasBound,
    void* __restrict__ outp, int ldout, float* __restrict__ cmax){
  __shared__ u16 As[128*LDK];
  __shared__ u16 Bs[128*LDK];
  const int tid = threadIdx.x;
  const int lane = tid & 63, wave = tid >> 6;
  const int wm = wave >> 1, wn = wave & 1;
  const int m0 = blockIdx.y * 128, n0 = blockIdx.x * 128;
  const int lr = lane & 15, lg = lane >> 4;
  f32x4 acc[4][4] = {};
  const int sr = tid >> 1, sh = (tid & 1) * 16;
  for (int ks = 0; ks < H; ks += 32){
    const u16* ga = A  + (size_t)(m0 + sr)*H + ks + sh;
    const u16* gb = BT + (size_t)(n0 + sr)*H + ks + sh;
    uint4 a0 = *(const uint4*)ga;
    uint4 a1 = *(const uint4*)(ga + 8);
    uint4 b0 = *(const uint4*)gb;
    uint4 b1 = *(const uint4*)(gb + 8);
    __syncthreads();
    *(uint4*)&As[sr*LDK + sh]     = a0;
    *(uint4*)&As[sr*LDK + sh + 8] = a1;
    *(uint4*)&Bs[sr*LDK + sh]     = b0;
    *(uint4*)&Bs[sr*LDK + sh + 8] = b1;
    __syncthreads();
    bf16x8 af[4], bfr[4];
    #pragma unroll
    for (int m=0;m<4;m++) af[m]  = *(const bf16x8*)&As[(wm*64 + m*16 + lr)*LDK + lg*8];
    #pragma unroll
    for (int n=0;n<4;n++) bfr[n] = *(const bf16x8*)&Bs[(wn*64 + n*16 + lr)*LDK + lg*8];
    #pragma unroll
    for (int m=0;m<4;m++)
      #pragma unroll
      for (int n=0;n<4;n++)
        acc[m][n] = __builtin_amdgcn_mfma_f32_16x16x32_bf16(af[m], bfr[n], acc[m][n], 0,0,0);
  }
  float cmx[4] = {-1e30f,-1e30f,-1e30f,-1e30f};
  #pragma unroll
  for (int m=0;m<4;m++){
    int r_g = m0 + wm*64 + m*16 + lg*4;
    #pragma unroll
    for (int n=0;n<4;n++){
      int n_g = n0 + wn*64 + n*16 + lr;
      float bcol = BIAS_ROW ? 0.f : bias[n_g];
      #pragma unroll
      for (int reg=0; reg<4; reg++){
        int r = r_g + reg;
        float bv = BIAS_ROW ? ((r < biasBound) ? bias[r] : 0.f) : bcol;
        float val = acc[m][n][reg] + bv;
        if (COLMAX) cmx[n] = fmaxf(cmx[n], val);
        if (BF16OUT) ((u16*)outp)[(size_t)r*ldout + n_g] = f2bf(val);
        else         ((float*)outp)[(size_t)r*ldout + n_g] = val;
      }
    }
  }
  if (COLMAX){
    #pragma unroll
    for (int n=0;n<4;n++){
      float m_ = cmx[n];
      m_ = fmaxf(m_, __shfl_xor(m_,16));
      m_ = fmaxf(m_, __shfl_xor(m_,32));
      if (lg==0) cmax[((size_t)(blockIdx.y*2 + wm))*C + n0 + wn*64 + n*16 + lr] = m_;
    }
  }
}

// ---------------- row softmax: TL (C,C) f32 -> P (C,C) bf16 ----------------
__global__ __launch_bounds__(256) void k_softmax(const float* __restrict__ TL, u16* __restrict__ P){
  const int c = blockIdx.x;
  const int tid = threadIdx.x, lane = tid & 63, wid = tid >> 6;
  __shared__ float red[4];
  __shared__ float Ms, Zs;
  float4 v = ((const float4*)(TL + (size_t)c*C))[tid];
  float m = fmaxf(fmaxf(v.x,v.y), fmaxf(v.z,v.w));
  for (int o=1;o<64;o<<=1) m = fmaxf(m, __shfl_xor(m,o));
  if (lane==0) red[wid] = m;
  __syncthreads();
  if (tid==0) Ms = fmaxf(fmaxf(red[0],red[1]), fmaxf(red[2],red[3]));
  __syncthreads();
  float M = Ms;
  float e0 = expf(v.x-M), e1 = expf(v.y-M), e2 = expf(v.z-M), e3 = expf(v.w-M);
  float s = (e0+e1)+(e2+e3);
  for (int o=1;o<64;o<<=1) s += __shfl_xor(s,o);
  if (lane==0) red[wid] = s;
  __syncthreads();
  if (tid==0) Zs = red[0]+red[1]+red[2]+red[3];
  __syncthreads();
  float inv = 1.f/Zs;
  u32 lo = (u32)f2bf(e0*inv) | ((u32)f2bf(e1*inv)<<16);
  u32 hi = (u32)f2bf(e2*inv) | ((u32)f2bf(e3*inv)<<16);
  *(uint2*)(P + (size_t)c*C + tid*4) = make_uint2(lo, hi);
}

// ---------------- combine partials: shift[c] = max_r cmax[r][c] (exact colmax) ----------------
__global__ void k_shiftc(const float* __restrict__ shiftp, float* __restrict__ shift){
  int c = threadIdx.x + blockIdx.x*blockDim.x;
  if (c < C){
    float m = -1e30f;
    for (int r=0;r<NRP;r++) m = fmaxf(m, shiftp[(size_t)r*C + c]);
    shift[c] = m;
  }
}

// ---------------- scatter D[v][c] = exp(EM[v][c] - shift[c]) (bf16, idempotent dedupe) ----------------
__global__ __launch_bounds__(256) void k_scatter(
    const int* __restrict__ w2s, const u16* __restrict__ EM,
    const float* __restrict__ shift, u16* __restrict__ D){
  int idx = blockIdx.x*256 + threadIdx.x;   // over V*S
  int v = idx >> 7;
  const int c = w2s[idx];
  float val = bf2f(EM[(size_t)v*C + c]);
  D[(size_t)v*C + c] = f2bf(expf(val - shift[c]));
}

// ---------------- column-sum of D over row chunks -> sumexp[chunk*C + c] ----------------
__global__ __launch_bounds__(256) void k_colsum(const u16* __restrict__ D, float* __restrict__ sumexp){
  const int c = blockIdx.x*256 + threadIdx.x;
  const int v0 = blockIdx.y*CHUNK;
  float s = 0.f;
  const u16* p = D + (size_t)v0*C + c;
  #pragma unroll 2
  for (int i=0;i<CHUNK;i++){ s += bf2f(p[0]); p += C; }
  sumexp[(size_t)blockIdx.y*C + c] = s;
}

__global__ void k_lse(const float* __restrict__ shift, const float* __restrict__ sumexp, float* __restrict__ lse){
  int c = threadIdx.x + blockIdx.x*blockDim.x;
  if (c < C){
    float s = 0.f;
    for (int r=0;r<NR;r++) s += sumexp[(size_t)r*C + c];
    lse[c] = shift[c] + logf(s);
  }
}

// ---------------- obs[b,t,s] = EM[text,c] - lse[c] ----------------
__global__ __launch_bounds__(128) void k_obs(
    const int* __restrict__ text, const int* __restrict__ w2s,
    const u16* __restrict__ EM, const float* __restrict__ lse,
    float* __restrict__ obs){
  const int bt = blockIdx.x;
  const int s = threadIdx.x;
  const int v = text[bt];
  const int c = w2s[(size_t)v*S + s];
  obs[(size_t)bt*S + s] = bf2f(EM[(size_t)v*C + c]) - lse[c];
}

// ---------------- fused level-0 gather + first pair product (single LDS buffer) ----------------
// out[j] = tile_{2j+1} . tile_{2j}; tile buffer time-shared: gather t0 (BT layout) ->
// B-frags to regs -> re-gather t1 (A layout, packed b128 writes) -> MFMA.
__global__ __launch_bounds__(256) void k_pair0(
    const int* __restrict__ text, const int* __restrict__ w2s,
    const float* __restrict__ start_lp, const float* __restrict__ obs,
    const u16* __restrict__ P, u16* __restrict__ out, float* __restrict__ scales){
  const int j = blockIdx.x;   // 0..63
  const int b = blockIdx.y;
  const int t0 = 2*j, t1 = 2*j+1;
  __shared__ __align__(16) u16 tile[128*PITCH];
  __shared__ int cp0[S], cn0[S], cp1[S], cn1[S];
  __shared__ float eo0[S], eo1[S], a00[S];
  __shared__ float red[4];
  const int tid = threadIdx.x;
  if (tid < 128){
    int s = tid;
    int cpv = w2s[(size_t)text[b*T + t0]*S + s];
    cp0[s] = cpv;
    cn0[s] = w2s[(size_t)text[b*T + t0+1]*S + s];
    eo0[s] = expf(obs[((size_t)b*T + t0 + 1)*S + s]);
    a00[s] = (t0==0) ? expf(start_lp[cpv] + obs[(size_t)(b*T)*S + s]) : 1.0f;
  } else if (t1 < 127){
    int s = tid-128;
    cp1[s] = w2s[(size_t)text[b*T + t1]*S + s];
    cn1[s] = w2s[(size_t)text[b*T + t1+1]*S + s];
    eo1[s] = expf(obs[((size_t)b*T + t1 + 1)*S + s]);
  }
  __syncthreads();
  const int sn = tid & 127, half = tid >> 7;
  const int lane = tid & 63, wave = tid >> 6;
  const int wm = wave >> 1, wn = wave & 1;
  const int lr = lane & 15, lg = lane >> 4;
  // ---- phase 1: gather tile t0 in BT layout [sp][sn] (conflict-free u16 writes) ----
  {
    const float e = eo0[sn];
    const int cnv = cn0[sn];
    for (int it=0; it<64; ++it){
      int sp = it*2 + half;
      float v = bf2f(P[(size_t)cp0[sp]*C + cnv]) * e * a00[sp];
      tile[sp*PITCH + sn] = f2bf(v);
    }
  }
  __syncthreads();
  // ---- load B fragments to registers (statically indexed) ----
  bf16x8 bfr[4][4];
  #pragma unroll
  for (int n=0;n<4;n++)
    #pragma unroll
    for (int kc=0;kc<4;kc++)
      bfr[n][kc] = *(const bf16x8*)&tile[(wn*64+n*16+lr)*PITCH + kc*32 + lg*8];
  __syncthreads();
  // ---- phase 2: gather tile t1 in A layout [sn][sp], packed b128 writes ----
  if (t1 < 127){
    const float e = eo1[sn];
    const int cnv = cn1[sn];
    #pragma unroll
    for (int g=0; g<8; ++g){
      u16 h[8];
      #pragma unroll
      for (int q=0; q<8; ++q){
        int sp = half*64 + g*8 + q;
        h[q] = f2bf(bf2f(P[(size_t)cp1[sp]*C + cnv]) * e);
      }
      *(uint4*)&tile[sn*PITCH + half*64 + g*8] = *(uint4*)h;
    }
  } else {
    #pragma unroll
    for (int g=0; g<8; ++g){
      u16 h[8];
      #pragma unroll
      for (int q=0; q<8; ++q){
        int sp = half*64 + g*8 + q;
        h[q] = (sn == sp) ? (u16)0x3F80u : (u16)0u;
      }
      *(uint4*)&tile[sn*PITCH + half*64 + g*8] = *(uint4*)h;
    }
  }
  __syncthreads();
  // ---- MFMA: A from LDS, B from regs ----
  f32x4 acc[4][4] = {};
  #pragma unroll
  for (int kc=0; kc<4; ++kc){
    bf16x8 af[4];
    #pragma unroll
    for (int m=0;m<4;m++) af[m] = *(const bf16x8*)&tile[(wm*64+m*16+lr)*PITCH + kc*32 + lg*8];
    #pragma unroll
    for (int m=0;m<4;m++)
      #pragma unroll
      for (int n=0;n<4;n++)
        acc[m][n] = __builtin_amdgcn_mfma_f32_16x16x32_bf16(af[m], bfr[n][kc], acc[m][n], 0,0,0);
  }
  float mx = 0.f;
  #pragma unroll
  for (int m=0;m<4;m++)
    #pragma unroll
    for (int n=0;n<4;n++)
      #pragma unroll
      for (int r=0;r<4;r++) mx = fmaxf(mx, acc[m][n][r]);
  for (int o=1;o<64;o<<=1) mx = fmaxf(mx, __shfl_xor(mx,o));
  if (lane==0) red[wave] = mx;
  __syncthreads();
  mx = fmaxf(fmaxf(red[0],red[1]), fmaxf(red[2],red[3]));
  const float sc = 1.0f / mx;
  if (tid==0) scales[(size_t)b*127 + j] = logf(mx);
  u16* Cg = out + ((size_t)b*64 + j)*(S*S);
  if (j & 1){
    #pragma unroll
    for (int m=0;m<4;m++){
      int rg = wm*64 + m*16 + lg*4;
      #pragma unroll
      for (int n=0;n<4;n++){
        int cg = wn*64 + n*16 + lr;
        #pragma unroll
        for (int r=0;r<4;r++) Cg[(size_t)(rg+r)*128 + cg] = f2bf(acc[m][n][r]*sc);
      }
    }
  } else {
    #pragma unroll
    for (int m=0;m<4;m++){
      int rg = wm*64 + m*16 + lg*4;
      #pragma unroll
      for (int n=0;n<4;n++){
        int cg = wn*64 + n*16 + lr;
        float v0=acc[m][n][0]*sc, v1=acc[m][n][1]*sc, v2=acc[m][n][2]*sc, v3=acc[m][n][3]*sc;
        u32 p0, p1;
        asm("v_cvt_pk_bf16_f32 %0, %1, %2" : "=v"(p0) : "v"(v0), "v"(v1));
        asm("v_cvt_pk_bf16_f32 %0, %1, %2" : "=v"(p1) : "v"(v2), "v"(v3));
        *(uint2*)(Cg + (size_t)cg*128 + rg) = make_uint2(p0, p1);
      }
    }
  }
}

// ---------------- tree pair-product: out[j] = in[2j+1] . in[2j] ----------------
__global__ __launch_bounds__(256) void k_pair(
    const u16* __restrict__ in, u16* __restrict__ out,
    float* __restrict__ scales, int nin, int soff){
  const int j = blockIdx.x;
  const int b = blockIdx.y;
  const int nout = nin >> 1;
  const u16* Ag = in + ((size_t)b*nin + 2*j+1)*(S*S);
  const u16* Bg = in + ((size_t)b*nin + 2*j  )*(S*S);
  u16* Cg = out + ((size_t)b*nout + j)*(S*S);
  const int tid = threadIdx.x;
  const int lane = tid & 63, wave = tid >> 6;
  const int wm = wave >> 1, wn = wave & 1;
  const int lr = lane & 15, lg = lane >> 4;
  f32x4 acc[4][4] = {};
  #pragma unroll
  for (int kc=0; kc<4; ++kc){
    bf16x8 af[4], bfr[4];
    #pragma unroll
    for (int m=0;m<4;m++) af[m]  = *(const bf16x8*)(Ag + (size_t)(wm*64+m*16+lr)*128 + kc*32 + lg*8);
    #pragma unroll
    for (int n=0;n<4;n++) bfr[n] = *(const bf16x8*)(Bg + (size_t)(wn*64+n*16+lr)*128 + kc*32 + lg*8);
    #pragma unroll
    for (int m=0;m<4;m++)
      #pragma unroll
      for (int n=0;n<4;n++)
        acc[m][n] = __builtin_amdgcn_mfma_f32_16x16x32_bf16(af[m], bfr[n], acc[m][n], 0,0,0);
  }
  __shared__ float red[4];
  float mx = 0.f;
  #pragma unroll
  for (int m=0;m<4;m++)
    #pragma unroll
    for (int n=0;n<4;n++)
      #pragma unroll
      for (int r=0;r<4;r++) mx = fmaxf(mx, acc[m][n][r]);
  for (int o=1;o<64;o<<=1) mx = fmaxf(mx, __shfl_xor(mx,o));
  if (lane==0) red[wave] = mx;
  __syncthreads();
  mx = fmaxf(fmaxf(red[0],red[1]), fmaxf(red[2],red[3]));
  const float sc = 1.0f / mx;
  if (tid==0) scales[(size_t)b*127 + soff + j] = logf(mx);
  if (j & 1){
    #pragma unroll
    for (int m=0;m<4;m++){
      int rg = wm*64 + m*16 + lg*4;
      #pragma unroll
      for (int n=0;n<4;n++){
        int cg = wn*64 + n*16 + lr;
        #pragma unroll
        for (int r=0;r<4;r++) Cg[(size_t)(rg+r)*128 + cg] = f2bf(acc[m][n][r]*sc);
      }
    }
  } else {
    #pragma unroll
    for (int m=0;m<4;m++){
      int rg = wm*64 + m*16 + lg*4;
      #pragma unroll
      for (int n=0;n<4;n++){
        int cg = wn*64 + n*16 + lr;
        float v0=acc[m][n][0]*sc, v1=acc[m][n][1]*sc, v2=acc[m][n][2]*sc, v3=acc[m][n][3]*sc;
        u32 p0, p1;
        asm("v_cvt_pk_bf16_f32 %0, %1, %2" : "=v"(p0) : "v"(v0), "v"(v1));
        asm("v_cvt_pk_bf16_f32 %0, %1, %2" : "=v"(p1) : "v"(v2), "v"(v3));
        *(uint2*)(Cg + (size_t)cg*128 + rg) = make_uint2(p0, p1);
      }
    }
  }
}

// ---------------- final: res[b] = log(sum entries) + sum(scales) ----------------
__global__ __launch_bounds__(256) void k_fin(
    const u16* __restrict__ fin, const float* __restrict__ scales, float* __restrict__ res){
  const int b = blockIdx.x;
  const int tid = threadIdx.x, lane = tid & 63, wid = tid >> 6;
  __shared__ float red[8];
  const u16* p = fin + (size_t)b*(S*S);
  float s = 0.f;
  #pragma unroll
  for (int i=0;i<8;i++){
    uint4 w = *(const uint4*)(p + (i*256+tid)*8);
    s += bf2f((u16)(w.x&0xFFFFu)) + bf2f((u16)(w.x>>16))
       + bf2f((u16)(w.y&0xFFFFu)) + bf2f((u16)(w.y>>16))
       + bf2f((u16)(w.z&0xFFFFu)) + bf2f((u16)(w.z>>16))
       + bf2f((u16)(w.w&0xFFFFu)) + bf2f((u16)(w.w>>16));
  }
  for (int o=1;o<64;o<<=1) s += __shfl_xor(s,o);
  if (lane==0) red[wid] = s;
  float sl = (tid < 127) ? scales[(size_t)b*127 + tid] : 0.f;
  for (int o=1;o<64;o<<=1) sl += __shfl_xor(sl,o);
  if (lane==0) red[4+wid] = sl;
  __syncthreads();
  if (tid==0){
    float tot = red[0]+red[1]+red[2]+red[3];
    float ssum = red[4]+red[5]+red[6]+red[7];
    res[b] = logf(tot) + ssum;
  }
}

__global__ void k_final(const float* __restrict__ res, float* __restrict__ out){
  if (threadIdx.x==0){
    float s = 0.f;
    for (int i=0;i<B;i++) s += res[i];
    out[0] = s;
  }
}

extern "C" void kernel_launch(void* const* d_in, const int* in_sizes, int n_in,
                              void* d_out, int out_size, void* d_ws, size_t ws_size,
                              hipStream_t stream){
  const int*   text      = (const int*)d_in[0];
  const int*   w2s       = (const int*)d_in[1];
  const float* start_emb = (const float*)d_in[2];
  const float* start_w1  = (const float*)d_in[3];
  const float* start_b1  = (const float*)d_in[4];
  const float* start_w2  = (const float*)d_in[5];
  const float* start_b2  = (const float*)d_in[6];
  const float* start_wo  = (const float*)d_in[7];
  const float* start_bo  = (const float*)d_in[8];
  const float* state_emb = (const float*)d_in[9];
  const float* trans_w1  = (const float*)d_in[10];
  const float* trans_b1  = (const float*)d_in[11];
  const float* trans_w2  = (const float*)d_in[12];
  const float* trans_b2  = (const float*)d_in[13];
  const float* trans_wo  = (const float*)d_in[14];
  const float* trans_bo  = (const float*)d_in[15];
  const float* pre_emb   = (const float*)d_in[16];
  const float* term_w1   = (const float*)d_in[17];
  const float* term_b1   = (const float*)d_in[18];
  const float* term_w2   = (const float*)d_in[19];
  const float* term_b2   = (const float*)d_in[20];
  const float* term_wo   = (const float*)d_in[21];
  const float* term_bo   = (const float*)d_in[22];

  char* ws = (char*)d_ws;
  size_t off = 0;
  auto alloc = [&](size_t bytes)->char*{ char* p = ws + off; off += (bytes + 255) & ~(size_t)255; return p; };
  u16*   embb     = (u16*)  alloc(sizeof(u16)*3*(size_t)C*H);
  u16*   h1b      = (u16*)  alloc(sizeof(u16)*3*(size_t)C*H);
  u16*   h2b      = (u16*)  alloc(sizeof(u16)*3*(size_t)C*H);
  u16*   wt       = (u16*)  alloc(sizeof(u16)*6*(size_t)H*H);
  float* start_lp = (float*)alloc(sizeof(float)*C);
  float* shift    = (float*)alloc(sizeof(float)*C);
  float* shiftp   = (float*)alloc(sizeof(float)*(size_t)C*NRP);
  float* sumexp   = (float*)alloc(sizeof(float)*(size_t)C*NR);
  float* lse      = (float*)alloc(sizeof(float)*C);
  float* resb     = (float*)alloc(sizeof(float)*B);
  float* scales   = (float*)alloc(sizeof(float)*(size_t)B*127);
  u16*   P        = (u16*)  alloc(sizeof(u16)*(size_t)C*C);
  u16*   wotb     = (u16*)  alloc(sizeof(u16)*(size_t)VP*H);
  u16*   wottr    = (u16*)  alloc(sizeof(u16)*(size_t)C*H);
  float* obs      = (float*)alloc(sizeof(float)*(size_t)B*T*S);
  u16*   EM       = (u16*)  alloc(sizeof(u16)*(size_t)VP*C);        // bf16 EM [VP][C]
  u16*   treeA    = (u16*)  alloc(sizeof(u16)*(size_t)B*64*S*S);    // 32MB
  u16*   treeB    = (u16*)  alloc(sizeof(u16)*(size_t)B*32*S*S);    // 16MB
  float* TL       = (float*)treeA; // f32 TL [C][C] = 4MB, dead before k_pair0 writes treeA
  u16*   D        = (u16*)((char*)treeA + sizeof(float)*(size_t)C*C); // bf16 [VP][C], treeA[4MB..24.7MB)
  (void)ws_size; (void)in_sizes; (void)n_in; (void)out_size;

  u16* embb0 = embb, *embb1 = embb + (size_t)C*H, *embb2 = embb + 2*(size_t)C*H;
  u16* h1b0 = h1b, *h1b1 = h1b + (size_t)C*H, *h1b2 = h1b + 2*(size_t)C*H;
  u16* h2b0 = h2b, *h2b1 = h2b + (size_t)C*H, *h2b2 = h2b + 2*(size_t)C*H;

  hipMemsetAsync(D, 0, sizeof(u16)*(size_t)VP*C, stream);

  Cvt3 cv; cv.s0 = start_emb; cv.s1 = state_emb; cv.s2 = pre_emb;
  cv.d0 = embb0; cv.d1 = embb1; cv.d2 = embb2;
  k_cvt3<<<dim3(C*H/(256*8), 3), dim3(256), 0, stream>>>(cv);

  T6 t6;
  t6.s[0]=start_w1; t6.s[1]=start_w2; t6.s[2]=trans_w1; t6.s[3]=trans_w2; t6.s[4]=term_w1; t6.s[5]=term_w2;
  for (int i=0;i<6;i++) t6.d[i] = wt + (size_t)i*H*H;
  k_transpose6<<<dim3(H/32, H/32, 6), dim3(32,8), 0, stream>>>(t6);

  M3 l1;
  l1.A[0]=embb0; l1.A[1]=embb1; l1.A[2]=embb2;
  l1.W[0]=wt;    l1.W[1]=wt+2*(size_t)H*H; l1.W[2]=wt+4*(size_t)H*H;
  l1.bias[0]=start_b1; l1.bias[1]=trans_b1; l1.bias[2]=term_b1;
  l1.R[0]=l1.R[1]=l1.R[2]=nullptr;
  l1.O[0]=h1b0; l1.O[1]=h1b1; l1.O[2]=h1b2;
  k_mlpg<0><<<dim3(H/128, C/128, 3), dim3(256), 0, stream>>>(l1);

  M3 l2;
  l2.A[0]=h1b0; l2.A[1]=h1b1; l2.A[2]=h1b2;
  l2.W[0]=wt+(size_t)H*H; l2.W[1]=wt+3*(size_t)H*H; l2.W[2]=wt+5*(size_t)H*H;
  l2.bias[0]=start_b2; l2.bias[1]=trans_b2; l2.bias[2]=term_b2;
  l2.R[0]=embb0; l2.R[1]=embb1; l2.R[2]=embb2;
  l2.O[0]=h2b0; l2.O[1]=h2b1; l2.O[2]=h2b2;
  k_mlpg<1><<<dim3(H/128, C/128, 3), dim3(256), 0, stream>>>(l2);

  k_start<<<dim3(1), dim3(1024), 0, stream>>>(h2b0, start_wo, start_bo, start_lp);
  k_transpose<<<dim3(VP/32, H/32), dim3(32,8), 0, stream>>>(term_wo, wotb, V);
  k_transpose<<<dim3(C/32, H/32), dim3(32,8), 0, stream>>>(trans_wo, wottr, C);
  // transition logits (f32) + row softmax -> P
  k_gemm<0,0,0><<<dim3(C/128, C/128), dim3(256), 0, stream>>>(h2b1, wottr, trans_bo, C, TL, C, nullptr);
  k_softmax<<<dim3(C), dim3(256), 0, stream>>>(TL, P);
  // emission logits EM[v][c] bf16, row bias bo[v], fused column-max partials
  k_gemm<1,1,1><<<dim3(C/128, VP/128), dim3(256), 0, stream>>>(wotb, h2b2, term_bo, V, EM, C, shiftp);
  k_shiftc<<<dim3((C+255)/256), dim3(256), 0, stream>>>(shiftp, shift);
  // masked LSE via idempotent scatter + dense colsum (no atomics)
  k_scatter<<<dim3(V*S/256), dim3(256), 0, stream>>>(w2s, EM, shift, D);
  k_colsum<<<dim3(C/256, NR), dim3(256), 0, stream>>>(D, sumexp);
  k_lse<<<dim3((C+255)/256), dim3(256), 0, stream>>>(shift, sumexp, lse);
  k_obs<<<dim3(B*T), dim3(128), 0, stream>>>(text, w2s, EM, lse, obs);

  // fused gather + level-1 product: 128 virtual tiles -> 64 tiles (treeA)
  k_pair0<<<dim3(64, B), dim3(256), 0, stream>>>(text, w2s, start_lp, obs, P, treeA, scales);

  // remaining tree: 64 -> 32 -> 16 -> 8 -> 4 -> 2 -> 1
  {
    u16* lin = treeA;
    u16* bufs[2] = { treeB, treeA };
    int nin = 64, soff = 64, cur = 0;
    while (nin > 1){
      int nout = nin >> 1;
      k_pair<<<dim3(nout, B), dim3(256), 0, stream>>>(lin, bufs[cur], scales, nin, soff);
      lin = bufs[cur];
      cur ^= 1;
      soff += nout;
      nin = nout;
    }
    k_fin<<<dim3(B), dim3(256), 0, stream>>>(lin, scales, resb);
  }
  k_final<<<dim3(1), dim3(64), 0, stream>>>(resb, (float*)d_out);
}

// Round 12
// 277.408 us; speedup vs baseline: 1.6301x; 1.0096x over previous
//
#include <hip/hip_runtime.h>
#include <hip/hip_bf16.h>

#define V 10000
#define VP 10112
#define C 1024
#define S 128
#define H 256
#define B 16
#define T 128
#define NR 64       // colsum row-chunks
#define CHUNK 158   // VP / NR
#define NRP 158     // colmax partials = (VP/128)*2
#define LDK 40      // padded LDS row length (u16) for k_gemm
#define SPITCH 1032 // stage row pitch (u16)

// swizzled tile addressing: group g (8 u16) of row r at r*128 + (g^(r&7))*8
#define TIX(r,g) (((r)<<7) + ((((g) ^ ((r)&7)))<<3))

typedef unsigned short u16;
typedef unsigned int u32;
typedef __bf16 bf16x8 __attribute__((ext_vector_type(8)));
typedef float f32x4 __attribute__((ext_vector_type(4)));

static __device__ __forceinline__ float bf2f(u16 x){ return __uint_as_float(((u32)x)<<16); }
static __device__ __forceinline__ u16 f2bf(float f){ u32 u=__float_as_uint(f); return (u16)((u + 0x7FFFu + ((u>>16)&1u))>>16); }

// ---------------- batched f32 -> bf16 convert (3 embeddings, C*H each) ----------------
struct Cvt3 { const float* s0; const float* s1; const float* s2; u16* d0; u16* d1; u16* d2; };
__global__ __launch_bounds__(256) void k_cvt3(Cvt3 a){
  const float* s = (blockIdx.y==0)? a.s0 : (blockIdx.y==1)? a.s1 : a.s2;
  u16* d = (blockIdx.y==0)? a.d0 : (blockIdx.y==1)? a.d1 : a.d2;
  int i = (blockIdx.x*256 + threadIdx.x)*8;
  float4 x0 = *(const float4*)(s+i);
  float4 x1 = *(const float4*)(s+i+4);
  u16 h[8] = {f2bf(x0.x),f2bf(x0.y),f2bf(x0.z),f2bf(x0.w),f2bf(x1.x),f2bf(x1.y),f2bf(x1.z),f2bf(x1.w)};
  *(uint4*)(d+i) = *(uint4*)h;
}

// ---------------- transpose src (H,N) f32 -> dst (NP,H) bf16, zero-padded ----------------
__global__ __launch_bounds__(256) void k_transpose(const float* __restrict__ src, u16* __restrict__ dst, int N){
  __shared__ float tile[32][33];
  int v0 = blockIdx.x*32, k0 = blockIdx.y*32;
  int tx = threadIdx.x, ty = threadIdx.y; // 32 x 8
  for (int i=0;i<32;i+=8){
    int k = k0+ty+i, v = v0+tx;
    tile[ty+i][tx] = (v < N) ? src[(size_t)k*N + v] : 0.f;
  }
  __syncthreads();
  for (int i=0;i<32;i+=8){
    int v = v0+ty+i, k = k0+tx;
    dst[(size_t)v*H + k] = f2bf(tile[tx][ty+i]);
  }
}

// ---------------- batched transpose of six (H,H) f32 weights -> bf16 [j][k] ----------------
struct T6 { const float* s[6]; u16* d[6]; };
__global__ __launch_bounds__(256) void k_transpose6(T6 a){
  const float* src = a.s[blockIdx.z];
  u16* dst = a.d[blockIdx.z];
  __shared__ float tile[32][33];
  int v0 = blockIdx.x*32, k0 = blockIdx.y*32;
  int tx = threadIdx.x, ty = threadIdx.y; // 32 x 8
  for (int i=0;i<32;i+=8){
    int k = k0+ty+i, v = v0+tx;
    tile[ty+i][tx] = src[(size_t)k*H + v];
  }
  __syncthreads();
  for (int i=0;i<32;i+=8){
    int v = v0+ty+i, k = k0+tx;
    dst[(size_t)v*H + k] = f2bf(tile[tx][ty+i]);
  }
}

// ---------------- batched MLP layer (3 MLPs via blockIdx.z), 128x128 MFMA tile ----------------
struct M3 { const u16* A[3]; const u16* W[3]; const float* bias[3]; const u16* R[3]; u16* O[3]; };
template<int RESID>
__global__ __launch_bounds__(256) void k_mlpg(M3 a){
  const int z = blockIdx.z;
  const u16* A  = a.A[z];
  const u16* BT = a.W[z];
  const float* bias = a.bias[z];
  const u16* Rm = a.R[z];
  u16* O = a.O[z];
  __shared__ u16 As[128*LDK];
  __shared__ u16 Bs[128*LDK];
  const int tid = threadIdx.x;
  const int lane = tid & 63, wave = tid >> 6;
  const int wm = wave >> 1, wn = wave & 1;
  const int m0 = blockIdx.y * 128, n0 = blockIdx.x * 128;
  const int lr = lane & 15, lg = lane >> 4;
  f32x4 acc[4][4] = {};
  const int sr = tid >> 1, sh = (tid & 1) * 16;
  for (int ks = 0; ks < H; ks += 32){
    const u16* ga = A  + (size_t)(m0 + sr)*H + ks + sh;
    const u16* gb = BT + (size_t)(n0 + sr)*H + ks + sh;
    uint4 a0 = *(const uint4*)ga;
    uint4 a1 = *(const uint4*)(ga + 8);
    uint4 b0 = *(const uint4*)gb;
    uint4 b1 = *(const uint4*)(gb + 8);
    __syncthreads();
    *(uint4*)&As[sr*LDK + sh]     = a0;
    *(uint4*)&As[sr*LDK + sh + 8] = a1;
    *(uint4*)&Bs[sr*LDK + sh]     = b0;
    *(uint4*)&Bs[sr*LDK + sh + 8] = b1;
    __syncthreads();
    bf16x8 af[4], bfr[4];
    #pragma unroll
    for (int m=0;m<4;m++) af[m]  = *(const bf16x8*)&As[(wm*64 + m*16 + lr)*LDK + lg*8];
    #pragma unroll
    for (int n=0;n<4;n++) bfr[n] = *(const bf16x8*)&Bs[(wn*64 + n*16 + lr)*LDK + lg*8];
    #pragma unroll
    for (int m=0;m<4;m++)
      #pragma unroll
      for (int n=0;n<4;n++)
        acc[m][n] = __builtin_amdgcn_mfma_f32_16x16x32_bf16(af[m], bfr[n], acc[m][n], 0,0,0);
  }
  #pragma unroll
  for (int m=0;m<4;m++){
    int r_g = m0 + wm*64 + m*16 + lg*4;
    #pragma unroll
    for (int n=0;n<4;n++){
      int n_g = n0 + wn*64 + n*16 + lr;
      float bv = bias[n_g];
      #pragma unroll
      for (int reg=0; reg<4; reg++){
        int r = r_g + reg;
        float val = acc[m][n][reg] + bv;
        if (RESID) val += bf2f(Rm[(size_t)r*H + n_g]);
        val = fmaxf(val, 0.f);
        O[(size_t)r*H + n_g] = f2bf(val);
      }
    }
  }
}

// ---------------- start head + log_softmax over C (bf16 h2) ----------------
__global__ __launch_bounds__(1024) void k_start(
    const u16* __restrict__ h2, const float* __restrict__ wo, const float* __restrict__ bo,
    float* __restrict__ start_lp){
  const int c = threadIdx.x;
  const int lane = c & 63, wid = c >> 6;
  __shared__ float red[16];
  __shared__ float Ms, Zs;
  float acc = bo[0];
  const u16* row = h2 + (size_t)c*H;
  for (int k=0;k<H;k+=8){
    uint4 hv = *(const uint4*)(row+k);
    float4 w0 = *(const float4*)(wo+k);
    float4 w1 = *(const float4*)(wo+k+4);
    acc = fmaf(bf2f((u16)(hv.x&0xFFFFu)), w0.x, acc);
    acc = fmaf(bf2f((u16)(hv.x>>16)),     w0.y, acc);
    acc = fmaf(bf2f((u16)(hv.y&0xFFFFu)), w0.z, acc);
    acc = fmaf(bf2f((u16)(hv.y>>16)),     w0.w, acc);
    acc = fmaf(bf2f((u16)(hv.z&0xFFFFu)), w1.x, acc);
    acc = fmaf(bf2f((u16)(hv.z>>16)),     w1.y, acc);
    acc = fmaf(bf2f((u16)(hv.w&0xFFFFu)), w1.z, acc);
    acc = fmaf(bf2f((u16)(hv.w>>16)),     w1.w, acc);
  }
  float m = acc;
  for (int o=1;o<64;o<<=1) m = fmaxf(m, __shfl_xor(m,o));
  if (lane==0) red[wid]=m;
  __syncthreads();
  if (c==0){ float t=red[0]; for(int i=1;i<16;i++) t=fmaxf(t,red[i]); Ms=t; }
  __syncthreads();
  float M = Ms;
  float e = expf(acc - M);
  float sum = e;
  for (int o=1;o<64;o<<=1) sum += __shfl_xor(sum,o);
  __syncthreads();
  if (lane==0) red[wid]=sum;
  __syncthreads();
  if (c==0){ float t=0.f; for(int i=0;i<16;i++) t+=red[i]; Zs=t; }
  __syncthreads();
  start_lp[c] = acc - (M + logf(Zs));
}

// ---------------- generic 128x128-tile MFMA GEMM: out = A(M,H) @ BT(N,H)^T + bias ----------------
template<int BIAS_ROW, int BF16OUT, int COLMAX>
__global__ __launch_bounds__(256) void k_gemm(
    const u16* __restrict__ A, const u16* __restrict__ BT,
    const float* __restrict__ bias, int biasBound,
    void* __restrict__ outp, int ldout, float* __restrict__ cmax){
  __shared__ u16 As[128*LDK];
  __shared__ u16 Bs[128*LDK];
  const int tid = threadIdx.x;
  const int lane = tid & 63, wave = tid >> 6;
  const int wm = wave >> 1, wn = wave & 1;
  const int m0 = blockIdx.y * 128, n0 = blockIdx.x * 128;
  const int lr = lane & 15, lg = lane >> 4;
  f32x4 acc[4][4] = {};
  const int sr = tid >> 1, sh = (tid & 1) * 16;
  for (int ks = 0; ks < H; ks += 32){
    const u16* ga = A  + (size_t)(m0 + sr)*H + ks + sh;
    const u16* gb = BT + (size_t)(n0 + sr)*H + ks + sh;
    uint4 a0 = *(const uint4*)ga;
    uint4 a1 = *(const uint4*)(ga + 8);
    uint4 b0 = *(const uint4*)gb;
    uint4 b1 = *(const uint4*)(gb + 8);
    __syncthreads();
    *(uint4*)&As[sr*LDK + sh]     = a0;
    *(uint4*)&As[sr*LDK + sh + 8] = a1;
    *(uint4*)&Bs[sr*LDK + sh]     = b0;
    *(uint4*)&Bs[sr*LDK + sh + 8] = b1;
    __syncthreads();
    bf16x8 af[4], bfr[4];
    #pragma unroll
    for (int m=0;m<4;m++) af[m]  = *(const bf16x8*)&As[(wm*64 + m*16 + lr)*LDK + lg*8];
    #pragma unroll
    for (int n=0;n<4;n++) bfr[n] = *(const bf16x8*)&Bs[(wn*64 + n*16 + lr)*LDK + lg*8];
    #pragma unroll
    for (int m=0;m<4;m++)
      #pragma unroll
      for (int n=0;n<4;n++)
        acc[m][n] = __builtin_amdgcn_mfma_f32_16x16x32_bf16(af[m], bfr[n], acc[m][n], 0,0,0);
  }
  float cmx[4] = {-1e30f,-1e30f,-1e30f,-1e30f};
  #pragma unroll
  for (int m=0;m<4;m++){
    int r_g = m0 + wm*64 + m*16 + lg*4;
    #pragma unroll
    for (int n=0;n<4;n++){
      int n_g = n0 + wn*64 + n*16 + lr;
      float bcol = BIAS_ROW ? 0.f : bias[n_g];
      #pragma unroll
      for (int reg=0; reg<4; reg++){
        int r = r_g + reg;
        float bv = BIAS_ROW ? ((r < biasBound) ? bias[r] : 0.f) : bcol;
        float val = acc[m][n][reg] + bv;
        if (COLMAX) cmx[n] = fmaxf(cmx[n], val);
        if (BF16OUT) ((u16*)outp)[(size_t)r*ldout + n_g] = f2bf(val);
        else         ((float*)outp)[(size_t)r*ldout + n_g] = val;
      }
    }
  }
  if (COLMAX){
    #pragma unroll
    for (int n=0;n<4;n++){
      float m_ = cmx[n];
      m_ = fmaxf(m_, __shfl_xor(m_,16));
      m_ = fmaxf(m_, __shfl_xor(m_,32));
      if (lg==0) cmax[((size_t)(blockIdx.y*2 + wm))*C + n0 + wn*64 + n*16 + lr] = m_;
    }
  }
}

// ---------------- row softmax: TL (C,C) f32 -> P (C,C) bf16 ----------------
__global__ __launch_bounds__(256) void k_softmax(const float* __restrict__ TL, u16* __restrict__ P){
  const int c = blockIdx.x;
  const int tid = threadIdx.x, lane = tid & 63, wid = tid >> 6;
  __shared__ float red[4];
  __shared__ float Ms, Zs;
  float4 v = ((const float4*)(TL + (size_t)c*C))[tid];
  float m = fmaxf(fmaxf(v.x,v.y), fmaxf(v.z,v.w));
  for (int o=1;o<64;o<<=1) m = fmaxf(m, __shfl_xor(m,o));
  if (lane==0) red[wid] = m;
  __syncthreads();
  if (tid==0) Ms = fmaxf(fmaxf(red[0],red[1]), fmaxf(red[2],red[3]));
  __syncthreads();
  float M = Ms;
  float e0 = expf(v.x-M), e1 = expf(v.y-M), e2 = expf(v.z-M), e3 = expf(v.w-M);
  float s = (e0+e1)+(e2+e3);
  for (int o=1;o<64;o<<=1) s += __shfl_xor(s,o);
  if (lane==0) red[wid] = s;
  __syncthreads();
  if (tid==0) Zs = red[0]+red[1]+red[2]+red[3];
  __syncthreads();
  float inv = 1.f/Zs;
  u32 lo = (u32)f2bf(e0*inv) | ((u32)f2bf(e1*inv)<<16);
  u32 hi = (u32)f2bf(e2*inv) | ((u32)f2bf(e3*inv)<<16);
  *(uint2*)(P + (size_t)c*C + tid*4) = make_uint2(lo, hi);
}

// ---------------- combine partials: shift[c] = max_r cmax[r][c] ----------------
__global__ void k_shiftc(const float* __restrict__ shiftp, float* __restrict__ shift){
  int c = threadIdx.x + blockIdx.x*blockDim.x;
  if (c < C){
    float m = -1e30f;
    for (int r=0;r<NRP;r++) m = fmaxf(m, shiftp[(size_t)r*C + c]);
    shift[c] = m;
  }
}

// ---------------- scatter D[v][c] = exp(EM[v][c] - shift[c]) ----------------
__global__ __launch_bounds__(256) void k_scatter(
    const int* __restrict__ w2s, const u16* __restrict__ EM,
    const float* __restrict__ shift, u16* __restrict__ D){
  int idx = blockIdx.x*256 + threadIdx.x;   // over V*S
  int v = idx >> 7;
  const int c = w2s[idx];
  float val = bf2f(EM[(size_t)v*C + c]);
  D[(size_t)v*C + c] = f2bf(expf(val - shift[c]));
}

// ---------------- column-sum of D over row chunks ----------------
__global__ __launch_bounds__(256) void k_colsum(const u16* __restrict__ D, float* __restrict__ sumexp){
  const int c = blockIdx.x*256 + threadIdx.x;
  const int v0 = blockIdx.y*CHUNK;
  float s = 0.f;
  const u16* p = D + (size_t)v0*C + c;
  #pragma unroll 2
  for (int i=0;i<CHUNK;i++){ s += bf2f(p[0]); p += C; }
  sumexp[(size_t)blockIdx.y*C + c] = s;
}

__global__ void k_lse(const float* __restrict__ shift, const float* __restrict__ sumexp, float* __restrict__ lse){
  int c = threadIdx.x + blockIdx.x*blockDim.x;
  if (c < C){
    float s = 0.f;
    for (int r=0;r<NR;r++) s += sumexp[(size_t)r*C + c];
    lse[c] = shift[c] + logf(s);
  }
}

// ---------------- obs[b,t,s] = EM[text,c] - lse[c] ----------------
__global__ __launch_bounds__(128) void k_obs(
    const int* __restrict__ text, const int* __restrict__ w2s,
    const u16* __restrict__ EM, const float* __restrict__ lse,
    float* __restrict__ obs){
  const int bt = blockIdx.x;
  const int s = threadIdx.x;
  const int v = text[bt];
  const int c = w2s[(size_t)v*S + s];
  obs[(size_t)bt*S + s] = bf2f(EM[(size_t)v*C + c]) - lse[c];
}

// ---------------- fused level-0 gather + first pair product (row-staged, coalesced) ----------------
// out[j] = T1 . T0. T_t[sn][sp] = P[cp_t[sp], cn_t[sn]]*eo_t[sn] (*a0[sp] at t=0); t=127 -> I.
// tile0 stored as T0^T (BT role) then B-frags to regs; tile1 stored row-major (A role).
__global__ __launch_bounds__(256) void k_pair0(
    const int* __restrict__ text, const int* __restrict__ w2s,
    const float* __restrict__ start_lp, const float* __restrict__ obs,
    const u16* __restrict__ P, u16* __restrict__ out, float* __restrict__ scales){
  const int j = blockIdx.x;   // 0..63
  const int b = blockIdx.y;
  const int t0 = 2*j, t1 = 2*j+1;
  __shared__ __align__(16) u16 tile[128*128];    // 32KB swizzled (TIX)
  __shared__ __align__(16) u16 stage[8*SPITCH];  // 16.5KB row stage
  __shared__ int cp0[S], cp1[S], cn1[S];
  __shared__ float eo0[S], eo1[S], a00[S];
  __shared__ float red[4];
  const int tid = threadIdx.x;
  if (tid < 128){
    int s = tid;
    int cpv = w2s[(size_t)text[b*T + t0]*S + s];
    cp0[s] = cpv;
    cp1[s] = w2s[(size_t)text[b*T + t0+1]*S + s];
    eo0[s] = expf(obs[((size_t)b*T + t0 + 1)*S + s]);
    a00[s] = (t0==0) ? expf(start_lp[cpv] + obs[(size_t)(b*T)*S + s]) : 1.0f;
  } else if (t1 < 127){
    int s = tid-128;
    cn1[s] = w2s[(size_t)text[b*T + t1+1]*S + s];
    eo1[s] = expf(obs[((size_t)b*T + t1 + 1)*S + s]);
  }
  __syncthreads();
  const int lane = tid & 63, wave = tid >> 6;
  const int wm = wave >> 1, wn = wave & 1;
  const int lr = lane & 15, lg = lane >> 4;
  // ---- build tile0 as T0^T: row sp = P[cp0[sp], cp1[k]]*eo0[k]*a00[sp] over k ----
  for (int c8 = 0; c8 < 16; ++c8){
    // stage 8 rows of P (rows cp0[8*c8 .. +8)) coalesced
    #pragma unroll
    for (int p=0;p<4;p++){
      int idx = p*256 + tid;
      int r = idx >> 7, col16 = idx & 127;
      *(uint4*)&stage[r*SPITCH + col16*8] = *(const uint4*)&P[(size_t)cp0[c8*8 + r]*C + col16*8];
    }
    __syncthreads();
    // extract: thread -> (row r = tid>>5 of 8, k-range kh*4)
    {
      int r = tid >> 5, kh = tid & 31;
      float asp = a00[c8*8 + r];
      u16 h4[4];
      #pragma unroll
      for (int q=0;q<4;q++){
        int k = kh*4 + q;
        h4[q] = f2bf(bf2f(stage[r*SPITCH + cp1[k]]) * eo0[k] * asp);
      }
      *(uint2*)&tile[TIX(c8*8 + r, kh>>1) + (kh&1)*4] = *(uint2*)h4;
    }
    __syncthreads();
  }
  // ---- B-fragments to registers ----
  bf16x8 bfr[4][4];
  #pragma unroll
  for (int n=0;n<4;n++)
    #pragma unroll
    for (int kc=0;kc<4;kc++)
      bfr[n][kc] = *(const bf16x8*)&tile[TIX(wn*64+n*16+lr, kc*4+lg)];
  __syncthreads();
  // ---- build tile1 row-major: row sn = P[cp1[sp], cn1[sn]]*eo1[sn] over sp ----
  if (t1 < 127){
    const int sn = tid & 127, half = tid >> 7;
    const int cnv = cn1[sn];
    const float e = eo1[sn];
    for (int c8 = 0; c8 < 16; ++c8){
      #pragma unroll
      for (int p=0;p<4;p++){
        int idx = p*256 + tid;
        int r = idx >> 7, col16 = idx & 127;
        *(uint4*)&stage[r*SPITCH + col16*8] = *(const uint4*)&P[(size_t)cp1[c8*8 + r]*C + col16*8];
      }
      __syncthreads();
      {
        u16 h4[4];
        #pragma unroll
        for (int q=0;q<4;q++){
          int rr = half*4 + q;
          h4[q] = f2bf(bf2f(stage[rr*SPITCH + cnv]) * e);
        }
        *(uint2*)&tile[TIX(sn, c8) + half*4] = *(uint2*)h4;
      }
      __syncthreads();
    }
  } else {
    if (tid < 128){
      int sn = tid;
      #pragma unroll
      for (int g=0; g<16; ++g){
        u16 h8[8];
        #pragma unroll
        for (int q=0;q<8;q++) h8[q] = (g*8+q == sn) ? (u16)0x3F80u : (u16)0u;
        *(uint4*)&tile[TIX(sn, g)] = *(uint4*)h8;
      }
    }
    __syncthreads();
  }
  // ---- MFMA: A from LDS (swizzled), B from regs ----
  f32x4 acc[4][4] = {};
  #pragma unroll
  for (int kc=0; kc<4; ++kc){
    bf16x8 af[4];
    #pragma unroll
    for (int m=0;m<4;m++) af[m] = *(const bf16x8*)&tile[TIX(wm*64+m*16+lr, kc*4+lg)];
    #pragma unroll
    for (int m=0;m<4;m++)
      #pragma unroll
      for (int n=0;n<4;n++)
        acc[m][n] = __builtin_amdgcn_mfma_f32_16x16x32_bf16(af[m], bfr[n][kc], acc[m][n], 0,0,0);
  }
  float mx = 0.f;
  #pragma unroll
  for (int m=0;m<4;m++)
    #pragma unroll
    for (int n=0;n<4;n++)
      #pragma unroll
      for (int r=0;r<4;r++) mx = fmaxf(mx, acc[m][n][r]);
  for (int o=1;o<64;o<<=1) mx = fmaxf(mx, __shfl_xor(mx,o));
  if (lane==0) red[wave] = mx;
  __syncthreads();
  mx = fmaxf(fmaxf(red[0],red[1]), fmaxf(red[2],red[3]));
  const float sc = 1.0f / mx;
  if (tid==0) scales[(size_t)b*127 + j] = logf(mx);
  u16* Cg = out + ((size_t)b*64 + j)*(S*S);
  if (j & 1){
    #pragma unroll
    for (int m=0;m<4;m++){
      int rg = wm*64 + m*16 + lg*4;
      #pragma unroll
      for (int n=0;n<4;n++){
        int cg = wn*64 + n*16 + lr;
        #pragma unroll
        for (int r=0;r<4;r++) Cg[(size_t)(rg+r)*128 + cg] = f2bf(acc[m][n][r]*sc);
      }
    }
  } else {
    #pragma unroll
    for (int m=0;m<4;m++){
      int rg = wm*64 + m*16 + lg*4;
      #pragma unroll
      for (int n=0;n<4;n++){
        int cg = wn*64 + n*16 + lr;
        float v0=acc[m][n][0]*sc, v1=acc[m][n][1]*sc, v2=acc[m][n][2]*sc, v3=acc[m][n][3]*sc;
        u32 p0, p1;
        asm("v_cvt_pk_bf16_f32 %0, %1, %2" : "=v"(p0) : "v"(v0), "v"(v1));
        asm("v_cvt_pk_bf16_f32 %0, %1, %2" : "=v"(p1) : "v"(v2), "v"(v3));
        *(uint2*)(Cg + (size_t)cg*128 + rg) = make_uint2(p0, p1);
      }
    }
  }
}

// ---------------- quad product: out[q] = in[4q+3].in[4q+2].in[4q+1].in[4q+0] ----------------
// Convention: even-index tiles stored transposed (BT role), odd row-major (A role).
// P1 = in[4q+1].in[4q+0] -> ldsB as P1^T (BT); Q = in[4q+2]^T.in[4q+3]^T = P2^T -> ldsA as P2 row-major.
// C = P2.P1, written with q-parity orientation.
__global__ __launch_bounds__(256) void k_quad(
    const u16* __restrict__ in, u16* __restrict__ out,
    float* __restrict__ scales, int nin, int soff_i, int soff_o){
  const int q = blockIdx.x;
  const int b = blockIdx.y;
  const int nout = nin >> 2;
  const u16* T0 = in + ((size_t)b*nin + 4*q+0)*(S*S);
  const u16* T1 = in + ((size_t)b*nin + 4*q+1)*(S*S);
  const u16* T2 = in + ((size_t)b*nin + 4*q+2)*(S*S);
  const u16* T3 = in + ((size_t)b*nin + 4*q+3)*(S*S);
  __shared__ __align__(16) u16 ldsA[128*128];
  __shared__ __align__(16) u16 ldsB[128*128];
  __shared__ float red[4];
  const int tid = threadIdx.x;
  const int lane = tid & 63, wave = tid >> 6;
  const int wm = wave >> 1, wn = wave & 1;
  const int lr = lane & 15, lg = lane >> 4;
  f32x4 acc[4][4];
  // ---- P1 = T1 . T0 ----
  #pragma unroll
  for (int m=0;m<4;m++)
    #pragma unroll
    for (int n=0;n<4;n++) acc[m][n] = (f32x4){0.f,0.f,0.f,0.f};
  #pragma unroll
  for (int kc=0; kc<4; ++kc){
    bf16x8 af[4], bf[4];
    #pragma unroll
    for (int m=0;m<4;m++) af[m] = *(const bf16x8*)(T1 + (size_t)(wm*64+m*16+lr)*128 + kc*32 + lg*8);
    #pragma unroll
    for (int n=0;n<4;n++) bf[n] = *(const bf16x8*)(T0 + (size_t)(wn*64+n*16+lr)*128 + kc*32 + lg*8);
    #pragma unroll
    for (int m=0;m<4;m++)
      #pragma unroll
      for (int n=0;n<4;n++)
        acc[m][n] = __builtin_amdgcn_mfma_f32_16x16x32_bf16(af[m], bf[n], acc[m][n], 0,0,0);
  }
  {
    float mx = 0.f;
    #pragma unroll
    for (int m=0;m<4;m++)
      #pragma unroll
      for (int n=0;n<4;n++)
        #pragma unroll
        for (int r=0;r<4;r++) mx = fmaxf(mx, acc[m][n][r]);
    for (int o=1;o<64;o<<=1) mx = fmaxf(mx, __shfl_xor(mx,o));
    if (lane==0) red[wave] = mx;
    __syncthreads();
    mx = fmaxf(fmaxf(red[0],red[1]), fmaxf(red[2],red[3]));
    float sc = 1.0f/mx;
    if (tid==0) scales[(size_t)b*127 + soff_i + 2*q] = logf(mx);
    // stash P1^T: entry [cg][rg+reg]
    #pragma unroll
    for (int m=0;m<4;m++){
      int rg = wm*64 + m*16 + lg*4;
      #pragma unroll
      for (int n=0;n<4;n++){
        int cg = wn*64 + n*16 + lr;
        float v0=acc[m][n][0]*sc, v1=acc[m][n][1]*sc, v2=acc[m][n][2]*sc, v3=acc[m][n][3]*sc;
        u32 p0, p1;
        asm("v_cvt_pk_bf16_f32 %0, %1, %2" : "=v"(p0) : "v"(v0), "v"(v1));
        asm("v_cvt_pk_bf16_f32 %0, %1, %2" : "=v"(p1) : "v"(v2), "v"(v3));
        *(uint2*)&ldsB[TIX(cg, rg>>3) + (rg&7)] = make_uint2(p0, p1);
      }
    }
  }
  __syncthreads();
  // ---- Q = T2^T . T3^T (= P2^T); T2 stored BT -> rows of T2^T; T3 row-major -> rows of T3 = (T3^T)^T cols ----
  #pragma unroll
  for (int m=0;m<4;m++)
    #pragma unroll
    for (int n=0;n<4;n++) acc[m][n] = (f32x4){0.f,0.f,0.f,0.f};
  #pragma unroll
  for (int kc=0; kc<4; ++kc){
    bf16x8 af[4], bf[4];
    #pragma unroll
    for (int m=0;m<4;m++) af[m] = *(const bf16x8*)(T2 + (size_t)(wm*64+m*16+lr)*128 + kc*32 + lg*8);
    #pragma unroll
    for (int n=0;n<4;n++) bf[n] = *(const bf16x8*)(T3 + (size_t)(wn*64+n*16+lr)*128 + kc*32 + lg*8);
    #pragma unroll
    for (int m=0;m<4;m++)
      #pragma unroll
      for (int n=0;n<4;n++)
        acc[m][n] = __builtin_amdgcn_mfma_f32_16x16x32_bf16(af[m], bf[n], acc[m][n], 0,0,0);
  }
  {
    float mx = 0.f;
    #pragma unroll
    for (int m=0;m<4;m++)
      #pragma unroll
      for (int n=0;n<4;n++)
        #pragma unroll
        for (int r=0;r<4;r++) mx = fmaxf(mx, acc[m][n][r]);
    for (int o=1;o<64;o<<=1) mx = fmaxf(mx, __shfl_xor(mx,o));
    __syncthreads();            // red reuse guard
    if (lane==0) red[wave] = mx;
    __syncthreads();
    mx = fmaxf(fmaxf(red[0],red[1]), fmaxf(red[2],red[3]));
    float sc = 1.0f/mx;
    if (tid==0) scales[(size_t)b*127 + soff_i + 2*q + 1] = logf(mx);
    // stash Q^T = P2 row-major: entry [cg][rg+reg]
    #pragma unroll
    for (int m=0;m<4;m++){
      int rg = wm*64 + m*16 + lg*4;
      #pragma unroll
      for (int n=0;n<4;n++){
        int cg = wn*64 + n*16 + lr;
        float v0=acc[m][n][0]*sc, v1=acc[m][n][1]*sc, v2=acc[m][n][2]*sc, v3=acc[m][n][3]*sc;
        u32 p0, p1;
        asm("v_cvt_pk_bf16_f32 %0, %1, %2" : "=v"(p0) : "v"(v0), "v"(v1));
        asm("v_cvt_pk_bf16_f32 %0, %1, %2" : "=v"(p1) : "v"(v2), "v"(v3));
        *(uint2*)&ldsA[TIX(cg, rg>>3) + (rg&7)] = make_uint2(p0, p1);
      }
    }
  }
  __syncthreads();
  // ---- C = P2 . P1 ----
  #pragma unroll
  for (int m=0;m<4;m++)
    #pragma unroll
    for (int n=0;n<4;n++) acc[m][n] = (f32x4){0.f,0.f,0.f,0.f};
  #pragma unroll
  for (int kc=0; kc<4; ++kc){
    bf16x8 af[4], bf[4];
    #pragma unroll
    for (int m=0;m<4;m++) af[m] = *(const bf16x8*)&ldsA[TIX(wm*64+m*16+lr, kc*4+lg)];
    #pragma unroll
    for (int n=0;n<4;n++) bf[n] = *(const bf16x8*)&ldsB[TIX(wn*64+n*16+lr, kc*4+lg)];
    #pragma unroll
    for (int m=0;m<4;m++)
      #pragma unroll
      for (int n=0;n<4;n++)
        acc[m][n] = __builtin_amdgcn_mfma_f32_16x16x32_bf16(af[m], bf[n], acc[m][n], 0,0,0);
  }
  float mx = 0.f;
  #pragma unroll
  for (int m=0;m<4;m++)
    #pragma unroll
    for (int n=0;n<4;n++)
      #pragma unroll
      for (int r=0;r<4;r++) mx = fmaxf(mx, acc[m][n][r]);
  for (int o=1;o<64;o<<=1) mx = fmaxf(mx, __shfl_xor(mx,o));
  __syncthreads();
  if (lane==0) red[wave] = mx;
  __syncthreads();
  mx = fmaxf(fmaxf(red[0],red[1]), fmaxf(red[2],red[3]));
  const float sc = 1.0f / mx;
  if (tid==0) scales[(size_t)b*127 + soff_o + q] = logf(mx);
  u16* Cg = out + ((size_t)b*nout + q)*(S*S);
  if (q & 1){
    #pragma unroll
    for (int m=0;m<4;m++){
      int rg = wm*64 + m*16 + lg*4;
      #pragma unroll
      for (int n=0;n<4;n++){
        int cg = wn*64 + n*16 + lr;
        #pragma unroll
        for (int r=0;r<4;r++) Cg[(size_t)(rg+r)*128 + cg] = f2bf(acc[m][n][r]*sc);
      }
    }
  } else {
    #pragma unroll
    for (int m=0;m<4;m++){
      int rg = wm*64 + m*16 + lg*4;
      #pragma unroll
      for (int n=0;n<4;n++){
        int cg = wn*64 + n*16 + lr;
        float v0=acc[m][n][0]*sc, v1=acc[m][n][1]*sc, v2=acc[m][n][2]*sc, v3=acc[m][n][3]*sc;
        u32 p0, p1;
        asm("v_cvt_pk_bf16_f32 %0, %1, %2" : "=v"(p0) : "v"(v0), "v"(v1));
        asm("v_cvt_pk_bf16_f32 %0, %1, %2" : "=v"(p1) : "v"(v2), "v"(v3));
        *(uint2*)(Cg + (size_t)cg*128 + rg) = make_uint2(p0, p1);
      }
    }
  }
}

// ---------------- final quad (4 -> 1) fused with evidence readout ----------------
__global__ __launch_bounds__(256) void k_fin4(
    const u16* __restrict__ in, const float* __restrict__ scales, float* __restrict__ res){
  const int b = blockIdx.x;
  const u16* T0 = in + ((size_t)b*4 + 0)*(S*S);
  const u16* T1 = in + ((size_t)b*4 + 1)*(S*S);
  const u16* T2 = in + ((size_t)b*4 + 2)*(S*S);
  const u16* T3 = in + ((size_t)b*4 + 3)*(S*S);
  __shared__ __align__(16) u16 ldsA[128*128];
  __shared__ __align__(16) u16 ldsB[128*128];
  __shared__ float red[8];
  __shared__ float sloc[2];
  const int tid = threadIdx.x;
  const int lane = tid & 63, wave = tid >> 6;
  const int wm = wave >> 1, wn = wave & 1;
  const int lr = lane & 15, lg = lane >> 4;
  f32x4 acc[4][4];
  // P1 = T1 . T0
  #pragma unroll
  for (int m=0;m<4;m++)
    #pragma unroll
    for (int n=0;n<4;n++) acc[m][n] = (f32x4){0.f,0.f,0.f,0.f};
  #pragma unroll
  for (int kc=0; kc<4; ++kc){
    bf16x8 af[4], bf[4];
    #pragma unroll
    for (int m=0;m<4;m++) af[m] = *(const bf16x8*)(T1 + (size_t)(wm*64+m*16+lr)*128 + kc*32 + lg*8);
    #pragma unroll
    for (int n=0;n<4;n++) bf[n] = *(const bf16x8*)(T0 + (size_t)(wn*64+n*16+lr)*128 + kc*32 + lg*8);
    #pragma unroll
    for (int m=0;m<4;m++)
      #pragma unroll
      for (int n=0;n<4;n++)
        acc[m][n] = __builtin_amdgcn_mfma_f32_16x16x32_bf16(af[m], bf[n], acc[m][n], 0,0,0);
  }
  {
    float mx = 0.f;
    #pragma unroll
    for (int m=0;m<4;m++)
      #pragma unroll
      for (int n=0;n<4;n++)
        #pragma unroll
        for (int r=0;r<4;r++) mx = fmaxf(mx, acc[m][n][r]);
    for (int o=1;o<64;o<<=1) mx = fmaxf(mx, __shfl_xor(mx,o));
    if (lane==0) red[wave] = mx;
    __syncthreads();
    mx = fmaxf(fmaxf(red[0],red[1]), fmaxf(red[2],red[3]));
    float sc = 1.0f/mx;
    if (tid==0) sloc[0] = logf(mx);
    #pragma unroll
    for (int m=0;m<4;m++){
      int rg = wm*64 + m*16 + lg*4;
      #pragma unroll
      for (int n=0;n<4;n++){
        int cg = wn*64 + n*16 + lr;
        float v0=acc[m][n][0]*sc, v1=acc[m][n][1]*sc, v2=acc[m][n][2]*sc, v3=acc[m][n][3]*sc;
        u32 p0, p1;
        asm("v_cvt_pk_bf16_f32 %0, %1, %2" : "=v"(p0) : "v"(v0), "v"(v1));
        asm("v_cvt_pk_bf16_f32 %0, %1, %2" : "=v"(p1) : "v"(v2), "v"(v3));
        *(uint2*)&ldsB[TIX(cg, rg>>3) + (rg&7)] = make_uint2(p0, p1);
      }
    }
  }
  __syncthreads();
  // Q = T2^T . T3^T
  #pragma unroll
  for (int m=0;m<4;m++)
    #pragma unroll
    for (int n=0;n<4;n++) acc[m][n] = (f32x4){0.f,0.f,0.f,0.f};
  #pragma unroll
  for (int kc=0; kc<4; ++kc){
    bf16x8 af[4], bf[4];
    #pragma unroll
    for (int m=0;m<4;m++) af[m] = *(const bf16x8*)(T2 + (size_t)(wm*64+m*16+lr)*128 + kc*32 + lg*8);
    #pragma unroll
    for (int n=0;n<4;n++) bf[n] = *(const bf16x8*)(T3 + (size_t)(wn*64+n*16+lr)*128 + kc*32 + lg*8);
    #pragma unroll
    for (int m=0;m<4;m++)
      #pragma unroll
      for (int n=0;n<4;n++)
        acc[m][n] = __builtin_amdgcn_mfma_f32_16x16x32_bf16(af[m], bf[n], acc[m][n], 0,0,0);
  }
  {
    float mx = 0.f;
    #pragma unroll
    for (int m=0;m<4;m++)
      #pragma unroll
      for (int n=0;n<4;n++)
        #pragma unroll
        for (int r=0;r<4;r++) mx = fmaxf(mx, acc[m][n][r]);
    for (int o=1;o<64;o<<=1) mx = fmaxf(mx, __shfl_xor(mx,o));
    __syncthreads();
    if (lane==0) red[wave] = mx;
    __syncthreads();
    mx = fmaxf(fmaxf(red[0],red[1]), fmaxf(red[2],red[3]));
    float sc = 1.0f/mx;
    if (tid==0) sloc[1] = logf(mx);
    #pragma unroll
    for (int m=0;m<4;m++){
      int rg = wm*64 + m*16 + lg*4;
      #pragma unroll
      for (int n=0;n<4;n++){
        int cg = wn*64 + n*16 + lr;
        float v0=acc[m][n][0]*sc, v1=acc[m][n][1]*sc, v2=acc[m][n][2]*sc, v3=acc[m][n][3]*sc;
        u32 p0, p1;
        asm("v_cvt_pk_bf16_f32 %0, %1, %2" : "=v"(p0) : "v"(v0), "v"(v1));
        asm("v_cvt_pk_bf16_f32 %0, %1, %2" : "=v"(p1) : "v"(v2), "v"(v3));
        *(uint2*)&ldsA[TIX(cg, rg>>3) + (rg&7)] = make_uint2(p0, p1);
      }
    }
  }
  __syncthreads();
  // C = P2 . P1 (fp32, no rescale) + total sum
  #pragma unroll
  for (int m=0;m<4;m++)
    #pragma unroll
    for (int n=0;n<4;n++) acc[m][n] = (f32x4){0.f,0.f,0.f,0.f};
  #pragma unroll
  for (int kc=0; kc<4; ++kc){
    bf16x8 af[4], bf[4];
    #pragma unroll
    for (int m=0;m<4;m++) af[m] = *(const bf16x8*)&ldsA[TIX(wm*64+m*16+lr, kc*4+lg)];
    #pragma unroll
    for (int n=0;n<4;n++) bf[n] = *(const bf16x8*)&ldsB[TIX(wn*64+n*16+lr, kc*4+lg)];
    #pragma unroll
    for (int m=0;m<4;m++)
      #pragma unroll
      for (int n=0;n<4;n++)
        acc[m][n] = __builtin_amdgcn_mfma_f32_16x16x32_bf16(af[m], bf[n], acc[m][n], 0,0,0);
  }
  float s = 0.f;
  #pragma unroll
  for (int m=0;m<4;m++)
    #pragma unroll
    for (int n=0;n<4;n++)
      #pragma unroll
      for (int r=0;r<4;r++) s += acc[m][n][r];
  for (int o=1;o<64;o<<=1) s += __shfl_xor(s,o);
  float sl = (tid < 124) ? scales[(size_t)b*127 + tid] : 0.f;
  for (int o=1;o<64;o<<=1) sl += __shfl_xor(sl,o);
  __syncthreads();
  if (lane==0){ red[wave] = s; red[4+wave] = sl; }
  __syncthreads();
  if (tid==0){
    float tot  = red[0]+red[1]+red[2]+red[3];
    float ssum = red[4]+red[5]+red[6]+red[7];
    res[b] = logf(tot) + ssum + sloc[0] + sloc[1];
  }
}

__global__ void k_final(const float* __restrict__ res, float* __restrict__ out){
  if (threadIdx.x==0){
    float s = 0.f;
    for (int i=0;i<B;i++) s += res[i];
    out[0] = s;
  }
}

extern "C" void kernel_launch(void* const* d_in, const int* in_sizes, int n_in,
                              void* d_out, int out_size, void* d_ws, size_t ws_size,
                              hipStream_t stream){
  const int*   text      = (const int*)d_in[0];
  const int*   w2s       = (const int*)d_in[1];
  const float* start_emb = (const float*)d_in[2];
  const float* start_w1  = (const float*)d_in[3];
  const float* start_b1  = (const float*)d_in[4];
  const float* start_w2  = (const float*)d_in[5];
  const float* start_b2  = (const float*)d_in[6];
  const float* start_wo  = (const float*)d_in[7];
  const float* start_bo  = (const float*)d_in[8];
  const float* state_emb = (const float*)d_in[9];
  const float* trans_w1  = (const float*)d_in[10];
  const float* trans_b1  = (const float*)d_in[11];
  const float* trans_w2  = (const float*)d_in[12];
  const float* trans_b2  = (const float*)d_in[13];
  const float* trans_wo  = (const float*)d_in[14];
  const float* trans_bo  = (const float*)d_in[15];
  const float* pre_emb   = (const float*)d_in[16];
  const float* term_w1   = (const float*)d_in[17];
  const float* term_b1   = (const float*)d_in[18];
  const float* term_w2   = (const float*)d_in[19];
  const float* term_b2   = (const float*)d_in[20];
  const float* term_wo   = (const float*)d_in[21];
  const float* term_bo   = (const float*)d_in[22];

  char* ws = (char*)d_ws;
  size_t off = 0;
  auto alloc = [&](size_t bytes)->char*{ char* p = ws + off; off += (bytes + 255) & ~(size_t)255; return p; };
  u16*   embb     = (u16*)  alloc(sizeof(u16)*3*(size_t)C*H);
  u16*   h1b      = (u16*)  alloc(sizeof(u16)*3*(size_t)C*H);
  u16*   h2b      = (u16*)  alloc(sizeof(u16)*3*(size_t)C*H);
  u16*   wt       = (u16*)  alloc(sizeof(u16)*6*(size_t)H*H);
  float* start_lp = (float*)alloc(sizeof(float)*C);
  float* shift    = (float*)alloc(sizeof(float)*C);
  float* shiftp   = (float*)alloc(sizeof(float)*(size_t)C*NRP);
  float* sumexp   = (float*)alloc(sizeof(float)*(size_t)C*NR);
  float* lse      = (float*)alloc(sizeof(float)*C);
  float* resb     = (float*)alloc(sizeof(float)*B);
  float* scales   = (float*)alloc(sizeof(float)*(size_t)B*127);
  u16*   P        = (u16*)  alloc(sizeof(u16)*(size_t)C*C);
  u16*   wotb     = (u16*)  alloc(sizeof(u16)*(size_t)VP*H);
  u16*   wottr    = (u16*)  alloc(sizeof(u16)*(size_t)C*H);
  float* obs      = (float*)alloc(sizeof(float)*(size_t)B*T*S);
  u16*   EM       = (u16*)  alloc(sizeof(u16)*(size_t)VP*C);        // bf16 EM [VP][C]
  u16*   treeA    = (u16*)  alloc(sizeof(u16)*(size_t)B*64*S*S);    // 32MB
  u16*   treeB    = (u16*)  alloc(sizeof(u16)*(size_t)B*16*S*S);    // 8MB
  float* TL       = (float*)treeA; // f32 TL [C][C] = 4MB, dead before k_pair0 writes treeA
  u16*   D        = (u16*)((char*)treeA + sizeof(float)*(size_t)C*C); // bf16 [VP][C], treeA[4MB..24.7MB)
  (void)ws_size; (void)in_sizes; (void)n_in; (void)out_size;

  u16* embb0 = embb, *embb1 = embb + (size_t)C*H, *embb2 = embb + 2*(size_t)C*H;
  u16* h1b0 = h1b, *h1b1 = h1b + (size_t)C*H, *h1b2 = h1b + 2*(size_t)C*H;
  u16* h2b0 = h2b, *h2b1 = h2b + (size_t)C*H, *h2b2 = h2b + 2*(size_t)C*H;

  hipMemsetAsync(D, 0, sizeof(u16)*(size_t)VP*C, stream);

  Cvt3 cv; cv.s0 = start_emb; cv.s1 = state_emb; cv.s2 = pre_emb;
  cv.d0 = embb0; cv.d1 = embb1; cv.d2 = embb2;
  k_cvt3<<<dim3(C*H/(256*8), 3), dim3(256), 0, stream>>>(cv);

  T6 t6;
  t6.s[0]=start_w1; t6.s[1]=start_w2; t6.s[2]=trans_w1; t6.s[3]=trans_w2; t6.s[4]=term_w1; t6.s[5]=term_w2;
  for (int i=0;i<6;i++) t6.d[i] = wt + (size_t)i*H*H;
  k_transpose6<<<dim3(H/32, H/32, 6), dim3(32,8), 0, stream>>>(t6);

  M3 l1;
  l1.A[0]=embb0; l1.A[1]=embb1; l1.A[2]=embb2;
  l1.W[0]=wt;    l1.W[1]=wt+2*(size_t)H*H; l1.W[2]=wt+4*(size_t)H*H;
  l1.bias[0]=start_b1; l1.bias[1]=trans_b1; l1.bias[2]=term_b1;
  l1.R[0]=l1.R[1]=l1.R[2]=nullptr;
  l1.O[0]=h1b0; l1.O[1]=h1b1; l1.O[2]=h1b2;
  k_mlpg<0><<<dim3(H/128, C/128, 3), dim3(256), 0, stream>>>(l1);

  M3 l2;
  l2.A[0]=h1b0; l2.A[1]=h1b1; l2.A[2]=h1b2;
  l2.W[0]=wt+(size_t)H*H; l2.W[1]=wt+3*(size_t)H*H; l2.W[2]=wt+5*(size_t)H*H;
  l2.bias[0]=start_b2; l2.bias[1]=trans_b2; l2.bias[2]=term_b2;
  l2.R[0]=embb0; l2.R[1]=embb1; l2.R[2]=embb2;
  l2.O[0]=h2b0; l2.O[1]=h2b1; l2.O[2]=h2b2;
  k_mlpg<1><<<dim3(H/128, C/128, 3), dim3(256), 0, stream>>>(l2);

  k_start<<<dim3(1), dim3(1024), 0, stream>>>(h2b0, start_wo, start_bo, start_lp);
  k_transpose<<<dim3(VP/32, H/32), dim3(32,8), 0, stream>>>(term_wo, wotb, V);
  k_transpose<<<dim3(C/32, H/32), dim3(32,8), 0, stream>>>(trans_wo, wottr, C);
  // transition logits (f32) + row softmax -> P
  k_gemm<0,0,0><<<dim3(C/128, C/128), dim3(256), 0, stream>>>(h2b1, wottr, trans_bo, C, TL, C, nullptr);
  k_softmax<<<dim3(C), dim3(256), 0, stream>>>(TL, P);
  // emission logits EM[v][c] bf16, row bias bo[v], fused column-max partials
  k_gemm<1,1,1><<<dim3(C/128, VP/128), dim3(256), 0, stream>>>(wotb, h2b2, term_bo, V, EM, C, shiftp);
  k_shiftc<<<dim3((C+255)/256), dim3(256), 0, stream>>>(shiftp, shift);
  // masked LSE via idempotent scatter + dense colsum (no atomics)
  k_scatter<<<dim3(V*S/256), dim3(256), 0, stream>>>(w2s, EM, shift, D);
  k_colsum<<<dim3(C/256, NR), dim3(256), 0, stream>>>(D, sumexp);
  k_lse<<<dim3((C+255)/256), dim3(256), 0, stream>>>(shift, sumexp, lse);
  k_obs<<<dim3(B*T), dim3(128), 0, stream>>>(text, w2s, EM, lse, obs);

  // fused gather + level-1 product: 128 virtual tiles -> 64 tiles (treeA)
  k_pair0<<<dim3(64, B), dim3(256), 0, stream>>>(text, w2s, start_lp, obs, P, treeA, scales);
  // quad levels: 64 -> 16 (treeB), 16 -> 4 (treeA), 4 -> 1 fused with readout
  k_quad<<<dim3(16, B), dim3(256), 0, stream>>>(treeA, treeB, scales, 64, 64, 96);
  k_quad<<<dim3(4,  B), dim3(256), 0, stream>>>(treeB, treeA, scales, 16, 112, 120);
  k_fin4<<<dim3(B), dim3(256), 0, stream>>>(treeA, scales, resb);
  k_final<<<dim3(1), dim3(64), 0, stream>>>(resb, (float*)d_out);
}

// Round 13
// 255.248 us; speedup vs baseline: 1.7716x; 1.0868x over previous
//
#include <hip/hip_runtime.h>
#include <hip/hip_bf16.h>

#define V 10000
#define VP 10112
#define C 1024
#define S 128
#define H 256
#define B 16
#define T 128
#define NRP 158     // colmax partials = (VP/128)*2
#define NSB 157     // sumexp blocks = ceil(V/64)
#define LDK 40      // padded LDS row length (u16) for k_gemm
#define PITCH 136   // k_pair0 LDS tile pitch (u16): 272B = 17*16B

// swizzled tile addressing for quad/fin: group g (8 u16) of row r
#define TIX(r,g) (((r)<<7) + ((((g) ^ ((r)&7)))<<3))

typedef unsigned short u16;
typedef unsigned int u32;
typedef __bf16 bf16x8 __attribute__((ext_vector_type(8)));
typedef float f32x4 __attribute__((ext_vector_type(4)));

static __device__ __forceinline__ float bf2f(u16 x){ return __uint_as_float(((u32)x)<<16); }
static __device__ __forceinline__ u16 f2bf(float f){ u32 u=__float_as_uint(f); return (u16)((u + 0x7FFFu + ((u>>16)&1u))>>16); }

// ---------------- fused prep: 3x cvt + 6x HxH transpose + term_wo/trans_wo transpose ----------------
struct Prep {
  const float* cs[3]; u16* cd[3];          // cvt
  const float* ts[6]; u16* td[6];          // HxH transposes
  const float* wvs; u16* wvd;              // (H,V) -> (VP,H)
  const float* wcs; u16* wcd;              // (H,C) -> (C,H)
};
__global__ __launch_bounds__(256) void k_prep(Prep a){
  const int blk = blockIdx.x;
  const int tid = threadIdx.x;
  if (blk < 384){
    int z = blk >> 7, bx = blk & 127;
    const float* s = a.cs[z]; u16* d = a.cd[z];
    int i = (bx*256 + tid)*8;
    float4 x0 = *(const float4*)(s+i);
    float4 x1 = *(const float4*)(s+i+4);
    u16 h[8] = {f2bf(x0.x),f2bf(x0.y),f2bf(x0.z),f2bf(x0.w),f2bf(x1.x),f2bf(x1.y),f2bf(x1.z),f2bf(x1.w)};
    *(uint4*)(d+i) = *(uint4*)h;
    return;
  }
  __shared__ float tile[32][33];
  const int tx = tid & 31, ty = tid >> 5;   // 32 x 8
  const float* src; u16* dst; int N, ldsrc, v0, k0;
  if (blk < 768){
    int sub = blk - 384;
    int z = sub >> 6, rem = sub & 63;
    src = a.ts[z]; dst = a.td[z]; N = H; ldsrc = H;
    v0 = (rem & 7)*32; k0 = (rem >> 3)*32;
  } else if (blk < 3296){
    int sub = blk - 768;
    src = a.wvs; dst = a.wvd; N = V; ldsrc = V;
    v0 = (sub % 316)*32; k0 = (sub / 316)*32;
  } else {
    int sub = blk - 3296;
    src = a.wcs; dst = a.wcd; N = C; ldsrc = C;
    v0 = (sub & 31)*32; k0 = (sub >> 5)*32;
  }
  for (int i=0;i<32;i+=8){
    int k = k0+ty+i, v = v0+tx;
    tile[ty+i][tx] = (v < N) ? src[(size_t)k*ldsrc + v] : 0.f;
  }
  __syncthreads();
  for (int i=0;i<32;i+=8){
    int v = v0+ty+i, k = k0+tx;
    dst[(size_t)v*H + k] = f2bf(tile[tx][ty+i]);
  }
}

// ---------------- batched MLP layer (3 MLPs via blockIdx.z), 128x128 MFMA tile ----------------
struct M3 { const u16* A[3]; const u16* W[3]; const float* bias[3]; const u16* R[3]; u16* O[3]; };
template<int RESID>
__global__ __launch_bounds__(256) void k_mlpg(M3 a){
  const int z = blockIdx.z;
  const u16* A  = a.A[z];
  const u16* BT = a.W[z];
  const float* bias = a.bias[z];
  const u16* Rm = a.R[z];
  u16* O = a.O[z];
  __shared__ u16 As[128*LDK];
  __shared__ u16 Bs[128*LDK];
  const int tid = threadIdx.x;
  const int lane = tid & 63, wave = tid >> 6;
  const int wm = wave >> 1, wn = wave & 1;
  const int m0 = blockIdx.y * 128, n0 = blockIdx.x * 128;
  const int lr = lane & 15, lg = lane >> 4;
  f32x4 acc[4][4] = {};
  const int sr = tid >> 1, sh = (tid & 1) * 16;
  for (int ks = 0; ks < H; ks += 32){
    const u16* ga = A  + (size_t)(m0 + sr)*H + ks + sh;
    const u16* gb = BT + (size_t)(n0 + sr)*H + ks + sh;
    uint4 a0 = *(const uint4*)ga;
    uint4 a1 = *(const uint4*)(ga + 8);
    uint4 b0 = *(const uint4*)gb;
    uint4 b1 = *(const uint4*)(gb + 8);
    __syncthreads();
    *(uint4*)&As[sr*LDK + sh]     = a0;
    *(uint4*)&As[sr*LDK + sh + 8] = a1;
    *(uint4*)&Bs[sr*LDK + sh]     = b0;
    *(uint4*)&Bs[sr*LDK + sh + 8] = b1;
    __syncthreads();
    bf16x8 af[4], bfr[4];
    #pragma unroll
    for (int m=0;m<4;m++) af[m]  = *(const bf16x8*)&As[(wm*64 + m*16 + lr)*LDK + lg*8];
    #pragma unroll
    for (int n=0;n<4;n++) bfr[n] = *(const bf16x8*)&Bs[(wn*64 + n*16 + lr)*LDK + lg*8];
    #pragma unroll
    for (int m=0;m<4;m++)
      #pragma unroll
      for (int n=0;n<4;n++)
        acc[m][n] = __builtin_amdgcn_mfma_f32_16x16x32_bf16(af[m], bfr[n], acc[m][n], 0,0,0);
  }
  #pragma unroll
  for (int m=0;m<4;m++){
    int r_g = m0 + wm*64 + m*16 + lg*4;
    #pragma unroll
    for (int n=0;n<4;n++){
      int n_g = n0 + wn*64 + n*16 + lr;
      float bv = bias[n_g];
      #pragma unroll
      for (int reg=0; reg<4; reg++){
        int r = r_g + reg;
        float val = acc[m][n][reg] + bv;
        if (RESID) val += bf2f(Rm[(size_t)r*H + n_g]);
        val = fmaxf(val, 0.f);
        O[(size_t)r*H + n_g] = f2bf(val);
      }
    }
  }
}

// ---------------- start head + log_softmax over C (bf16 h2) ----------------
__global__ __launch_bounds__(1024) void k_start(
    const u16* __restrict__ h2, const float* __restrict__ wo, const float* __restrict__ bo,
    float* __restrict__ start_lp){
  const int c = threadIdx.x;
  const int lane = c & 63, wid = c >> 6;
  __shared__ float red[16];
  __shared__ float Ms, Zs;
  float acc = bo[0];
  const u16* row = h2 + (size_t)c*H;
  for (int k=0;k<H;k+=8){
    uint4 hv = *(const uint4*)(row+k);
    float4 w0 = *(const float4*)(wo+k);
    float4 w1 = *(const float4*)(wo+k+4);
    acc = fmaf(bf2f((u16)(hv.x&0xFFFFu)), w0.x, acc);
    acc = fmaf(bf2f((u16)(hv.x>>16)),     w0.y, acc);
    acc = fmaf(bf2f((u16)(hv.y&0xFFFFu)), w0.z, acc);
    acc = fmaf(bf2f((u16)(hv.y>>16)),     w0.w, acc);
    acc = fmaf(bf2f((u16)(hv.z&0xFFFFu)), w1.x, acc);
    acc = fmaf(bf2f((u16)(hv.z>>16)),     w1.y, acc);
    acc = fmaf(bf2f((u16)(hv.w&0xFFFFu)), w1.z, acc);
    acc = fmaf(bf2f((u16)(hv.w>>16)),     w1.w, acc);
  }
  float m = acc;
  for (int o=1;o<64;o<<=1) m = fmaxf(m, __shfl_xor(m,o));
  if (lane==0) red[wid]=m;
  __syncthreads();
  if (c==0){ float t=red[0]; for(int i=1;i<16;i++) t=fmaxf(t,red[i]); Ms=t; }
  __syncthreads();
  float M = Ms;
  float e = expf(acc - M);
  float sum = e;
  for (int o=1;o<64;o<<=1) sum += __shfl_xor(sum,o);
  __syncthreads();
  if (lane==0) red[wid]=sum;
  __syncthreads();
  if (c==0){ float t=0.f; for(int i=0;i<16;i++) t+=red[i]; Zs=t; }
  __syncthreads();
  start_lp[c] = acc - (M + logf(Zs));
}

// ---------------- generic 128x128-tile MFMA GEMM ----------------
template<int BIAS_ROW, int BF16OUT, int COLMAX>
__global__ __launch_bounds__(256) void k_gemm(
    const u16* __restrict__ A, const u16* __restrict__ BT,
    const float* __restrict__ bias, int biasBound,
    void* __restrict__ outp, int ldout, float* __restrict__ cmax){
  __shared__ u16 As[128*LDK];
  __shared__ u16 Bs[128*LDK];
  const int tid = threadIdx.x;
  const int lane = tid & 63, wave = tid >> 6;
  const int wm = wave >> 1, wn = wave & 1;
  const int m0 = blockIdx.y * 128, n0 = blockIdx.x * 128;
  const int lr = lane & 15, lg = lane >> 4;
  f32x4 acc[4][4] = {};
  const int sr = tid >> 1, sh = (tid & 1) * 16;
  for (int ks = 0; ks < H; ks += 32){
    const u16* ga = A  + (size_t)(m0 + sr)*H + ks + sh;
    const u16* gb = BT + (size_t)(n0 + sr)*H + ks + sh;
    uint4 a0 = *(const uint4*)ga;
    uint4 a1 = *(const uint4*)(ga + 8);
    uint4 b0 = *(const uint4*)gb;
    uint4 b1 = *(const uint4*)(gb + 8);
    __syncthreads();
    *(uint4*)&As[sr*LDK + sh]     = a0;
    *(uint4*)&As[sr*LDK + sh + 8] = a1;
    *(uint4*)&Bs[sr*LDK + sh]     = b0;
    *(uint4*)&Bs[sr*LDK + sh + 8] = b1;
    __syncthreads();
    bf16x8 af[4], bfr[4];
    #pragma unroll
    for (int m=0;m<4;m++) af[m]  = *(const bf16x8*)&As[(wm*64 + m*16 + lr)*LDK + lg*8];
    #pragma unroll
    for (int n=0;n<4;n++) bfr[n] = *(const bf16x8*)&Bs[(wn*64 + n*16 + lr)*LDK + lg*8];
    #pragma unroll
    for (int m=0;m<4;m++)
      #pragma unroll
      for (int n=0;n<4;n++)
        acc[m][n] = __builtin_amdgcn_mfma_f32_16x16x32_bf16(af[m], bfr[n], acc[m][n], 0,0,0);
  }
  float cmx[4] = {-1e30f,-1e30f,-1e30f,-1e30f};
  #pragma unroll
  for (int m=0;m<4;m++){
    int r_g = m0 + wm*64 + m*16 + lg*4;
    #pragma unroll
    for (int n=0;n<4;n++){
      int n_g = n0 + wn*64 + n*16 + lr;
      float bcol = BIAS_ROW ? 0.f : bias[n_g];
      #pragma unroll
      for (int reg=0; reg<4; reg++){
        int r = r_g + reg;
        float bv = BIAS_ROW ? ((r < biasBound) ? bias[r] : 0.f) : bcol;
        float val = acc[m][n][reg] + bv;
        if (COLMAX) cmx[n] = fmaxf(cmx[n], val);
        if (BF16OUT) ((u16*)outp)[(size_t)r*ldout + n_g] = f2bf(val);
        else         ((float*)outp)[(size_t)r*ldout + n_g] = val;
      }
    }
  }
  if (COLMAX){
    #pragma unroll
    for (int n=0;n<4;n++){
      float m_ = cmx[n];
      m_ = fmaxf(m_, __shfl_xor(m_,16));
      m_ = fmaxf(m_, __shfl_xor(m_,32));
      if (lg==0) cmax[((size_t)(blockIdx.y*2 + wm))*C + n0 + wn*64 + n*16 + lr] = m_;
    }
  }
}

// ---------------- row softmax: TL (C,C) f32 -> P (C,C) bf16 ----------------
__global__ __launch_bounds__(256) void k_softmax(const float* __restrict__ TL, u16* __restrict__ P){
  const int c = blockIdx.x;
  const int tid = threadIdx.x, lane = tid & 63, wid = tid >> 6;
  __shared__ float red[4];
  __shared__ float Ms, Zs;
  float4 v = ((const float4*)(TL + (size_t)c*C))[tid];
  float m = fmaxf(fmaxf(v.x,v.y), fmaxf(v.z,v.w));
  for (int o=1;o<64;o<<=1) m = fmaxf(m, __shfl_xor(m,o));
  if (lane==0) red[wid] = m;
  __syncthreads();
  if (tid==0) Ms = fmaxf(fmaxf(red[0],red[1]), fmaxf(red[2],red[3]));
  __syncthreads();
  float M = Ms;
  float e0 = expf(v.x-M), e1 = expf(v.y-M), e2 = expf(v.z-M), e3 = expf(v.w-M);
  float s = (e0+e1)+(e2+e3);
  for (int o=1;o<64;o<<=1) s += __shfl_xor(s,o);
  if (lane==0) red[wid] = s;
  __syncthreads();
  if (tid==0) Zs = red[0]+red[1]+red[2]+red[3];
  __syncthreads();
  float inv = 1.f/Zs;
  u32 lo = (u32)f2bf(e0*inv) | ((u32)f2bf(e1*inv)<<16);
  u32 hi = (u32)f2bf(e2*inv) | ((u32)f2bf(e3*inv)<<16);
  *(uint2*)(P + (size_t)c*C + tid*4) = make_uint2(lo, hi);
}

// ---------------- combine partials: shift[c] = max_r cmax[r][c] ----------------
__global__ void k_shiftc(const float* __restrict__ shiftp, float* __restrict__ shift){
  int c = threadIdx.x + blockIdx.x*blockDim.x;
  if (c < C){
    float m = -1e30f;
    for (int r=0;r<NRP;r++) m = fmaxf(m, shiftp[(size_t)r*C + c]);
    shift[c] = m;
  }
}

// ---------------- masked LSE partials: 64 words/block, LDS bitmap dedupe + LDS fp32 acc ----------------
__global__ __launch_bounds__(256) void k_sumexp(
    const int* __restrict__ w2s, const u16* __restrict__ EM,
    const float* __restrict__ shift, float* __restrict__ sumexp){
  __shared__ float accL[C];
  __shared__ u32 bm[64*32];
  const int tid = threadIdx.x;
  const int v0 = blockIdx.x*64;
  #pragma unroll
  for (int i=0;i<4;i++) accL[tid + i*256] = 0.f;
  #pragma unroll
  for (int i=0;i<8;i++) bm[tid + i*256] = 0u;
  __syncthreads();
  #pragma unroll 2
  for (int it=0; it<32; ++it){
    int e = it*256 + tid;
    int vl = e >> 7, s = e & 127;
    int v = v0 + vl;
    if (v < V){
      int c = w2s[(size_t)v*S + s];
      u32 old = atomicOr(&bm[(vl<<5) + (c>>5)], 1u << (c&31));
      if (!((old >> (c&31)) & 1u))
        atomicAdd(&accL[c], expf(bf2f(EM[(size_t)v*C + c]) - shift[c]));
    }
  }
  __syncthreads();
  float* dst = sumexp + (size_t)blockIdx.x*C;
  #pragma unroll
  for (int i=0;i<4;i++) dst[tid + i*256] = accL[tid + i*256];
}

__global__ void k_lse(const float* __restrict__ shift, const float* __restrict__ sumexp, float* __restrict__ lse){
  int c = threadIdx.x + blockIdx.x*blockDim.x;
  if (c < C){
    float s = 0.f;
    for (int r=0;r<NSB;r++) s += sumexp[(size_t)r*C + c];
    lse[c] = shift[c] + logf(s);
  }
}

// ---------------- fused level-0 gather + first pair product (R11 structure, eo inline) ----------------
// out[j] = T1 . T0; tile buffer time-shared: gather T0^T -> B-frags to regs -> gather T1 -> MFMA.
// cp1 == cn0 == w2s[text[b,t0+1]] (shared array cs1).
__global__ __launch_bounds__(256) void k_pair0(
    const int* __restrict__ text, const int* __restrict__ w2s,
    const float* __restrict__ start_lp, const float* __restrict__ lse,
    const u16* __restrict__ EM, const u16* __restrict__ P,
    u16* __restrict__ out, float* __restrict__ scales){
  const int j = blockIdx.x;   // 0..63
  const int b = blockIdx.y;
  const int t0 = 2*j, t1 = 2*j+1;
  __shared__ __align__(16) u16 tile[128*PITCH];
  __shared__ int cp0[S], cs1[S], cn1[S];
  __shared__ float eo0[S], eo1[S], a00[S];
  __shared__ float red[4];
  const int tid = threadIdx.x;
  if (tid < 128){
    int s = tid;
    int v0 = text[b*T + t0], v1 = text[b*T + t0 + 1];
    int c0 = w2s[(size_t)v0*S + s];
    int c1 = w2s[(size_t)v1*S + s];
    cp0[s] = c0;
    cs1[s] = c1;
    eo0[s] = expf(bf2f(EM[(size_t)v1*C + c1]) - lse[c1]);
    a00[s] = (t0==0) ? expf(start_lp[c0] + bf2f(EM[(size_t)v0*C + c0]) - lse[c0]) : 1.0f;
  } else if (t1 < 127){
    int s = tid-128;
    int v2 = text[b*T + t1 + 1];
    int c2 = w2s[(size_t)v2*S + s];
    cn1[s] = c2;
    eo1[s] = expf(bf2f(EM[(size_t)v2*C + c2]) - lse[c2]);
  }
  __syncthreads();
  const int sn = tid & 127, half = tid >> 7;
  const int lane = tid & 63, wave = tid >> 6;
  const int wm = wave >> 1, wn = wave & 1;
  const int lr = lane & 15, lg = lane >> 4;
  // ---- phase 1: T0^T[sp][sn] = P[cp0[sp], cs1[sn]]*eo0[sn]*a00[sp] ----
  {
    const float e = eo0[sn];
    const int cnv = cs1[sn];
    for (int it=0; it<64; ++it){
      int sp = it*2 + half;
      float v = bf2f(P[(size_t)cp0[sp]*C + cnv]) * e * a00[sp];
      tile[sp*PITCH + sn] = f2bf(v);
    }
  }
  __syncthreads();
  // ---- B fragments to registers ----
  bf16x8 bfr[4][4];
  #pragma unroll
  for (int n=0;n<4;n++)
    #pragma unroll
    for (int kc=0;kc<4;kc++)
      bfr[n][kc] = *(const bf16x8*)&tile[(wn*64+n*16+lr)*PITCH + kc*32 + lg*8];
  __syncthreads();
  // ---- phase 2: T1[sn][sp] = P[cs1[sp], cn1[sn]]*eo1[sn], packed b128 writes ----
  if (t1 < 127){
    const float e = eo1[sn];
    const int cnv = cn1[sn];
    #pragma unroll
    for (int g=0; g<8; ++g){
      u16 h[8];
      #pragma unroll
      for (int q=0; q<8; ++q){
        int sp = half*64 + g*8 + q;
        h[q] = f2bf(bf2f(P[(size_t)cs1[sp]*C + cnv]) * e);
      }
      *(uint4*)&tile[sn*PITCH + half*64 + g*8] = *(uint4*)h;
    }
  } else {
    #pragma unroll
    for (int g=0; g<8; ++g){
      u16 h[8];
      #pragma unroll
      for (int q=0; q<8; ++q){
        int sp = half*64 + g*8 + q;
        h[q] = (sn == sp) ? (u16)0x3F80u : (u16)0u;
      }
      *(uint4*)&tile[sn*PITCH + half*64 + g*8] = *(uint4*)h;
    }
  }
  __syncthreads();
  // ---- MFMA: A from LDS, B from regs ----
  f32x4 acc[4][4] = {};
  #pragma unroll
  for (int kc=0; kc<4; ++kc){
    bf16x8 af[4];
    #pragma unroll
    for (int m=0;m<4;m++) af[m] = *(const bf16x8*)&tile[(wm*64+m*16+lr)*PITCH + kc*32 + lg*8];
    #pragma unroll
    for (int m=0;m<4;m++)
      #pragma unroll
      for (int n=0;n<4;n++)
        acc[m][n] = __builtin_amdgcn_mfma_f32_16x16x32_bf16(af[m], bfr[n][kc], acc[m][n], 0,0,0);
  }
  float mx = 0.f;
  #pragma unroll
  for (int m=0;m<4;m++)
    #pragma unroll
    for (int n=0;n<4;n++)
      #pragma unroll
      for (int r=0;r<4;r++) mx = fmaxf(mx, acc[m][n][r]);
  for (int o=1;o<64;o<<=1) mx = fmaxf(mx, __shfl_xor(mx,o));
  if (lane==0) red[wave] = mx;
  __syncthreads();
  mx = fmaxf(fmaxf(red[0],red[1]), fmaxf(red[2],red[3]));
  const float sc = 1.0f / mx;
  if (tid==0) scales[(size_t)b*127 + j] = logf(mx);
  u16* Cg = out + ((size_t)b*64 + j)*(S*S);
  if (j & 1){
    #pragma unroll
    for (int m=0;m<4;m++){
      int rg = wm*64 + m*16 + lg*4;
      #pragma unroll
      for (int n=0;n<4;n++){
        int cg = wn*64 + n*16 + lr;
        #pragma unroll
        for (int r=0;r<4;r++) Cg[(size_t)(rg+r)*128 + cg] = f2bf(acc[m][n][r]*sc);
      }
    }
  } else {
    #pragma unroll
    for (int m=0;m<4;m++){
      int rg = wm*64 + m*16 + lg*4;
      #pragma unroll
      for (int n=0;n<4;n++){
        int cg = wn*64 + n*16 + lr;
        float v0=acc[m][n][0]*sc, v1=acc[m][n][1]*sc, v2=acc[m][n][2]*sc, v3=acc[m][n][3]*sc;
        u32 p0, p1;
        asm("v_cvt_pk_bf16_f32 %0, %1, %2" : "=v"(p0) : "v"(v0), "v"(v1));
        asm("v_cvt_pk_bf16_f32 %0, %1, %2" : "=v"(p1) : "v"(v2), "v"(v3));
        *(uint2*)(Cg + (size_t)cg*128 + rg) = make_uint2(p0, p1);
      }
    }
  }
}

// ---------------- quad product: out[q] = in[4q+3].in[4q+2].in[4q+1].in[4q+0] ----------------
__global__ __launch_bounds__(256) void k_quad(
    const u16* __restrict__ in, u16* __restrict__ out,
    float* __restrict__ scales, int nin, int soff_i, int soff_o){
  const int q = blockIdx.x;
  const int b = blockIdx.y;
  const int nout = nin >> 2;
  const u16* T0 = in + ((size_t)b*nin + 4*q+0)*(S*S);
  const u16* T1 = in + ((size_t)b*nin + 4*q+1)*(S*S);
  const u16* T2 = in + ((size_t)b*nin + 4*q+2)*(S*S);
  const u16* T3 = in + ((size_t)b*nin + 4*q+3)*(S*S);
  __shared__ __align__(16) u16 ldsA[128*128];
  __shared__ __align__(16) u16 ldsB[128*128];
  __shared__ float red[4];
  const int tid = threadIdx.x;
  const int lane = tid & 63, wave = tid >> 6;
  const int wm = wave >> 1, wn = wave & 1;
  const int lr = lane & 15, lg = lane >> 4;
  f32x4 acc[4][4];
  // P1 = T1 . T0
  #pragma unroll
  for (int m=0;m<4;m++)
    #pragma unroll
    for (int n=0;n<4;n++) acc[m][n] = (f32x4){0.f,0.f,0.f,0.f};
  #pragma unroll
  for (int kc=0; kc<4; ++kc){
    bf16x8 af[4], bf[4];
    #pragma unroll
    for (int m=0;m<4;m++) af[m] = *(const bf16x8*)(T1 + (size_t)(wm*64+m*16+lr)*128 + kc*32 + lg*8);
    #pragma unroll
    for (int n=0;n<4;n++) bf[n] = *(const bf16x8*)(T0 + (size_t)(wn*64+n*16+lr)*128 + kc*32 + lg*8);
    #pragma unroll
    for (int m=0;m<4;m++)
      #pragma unroll
      for (int n=0;n<4;n++)
        acc[m][n] = __builtin_amdgcn_mfma_f32_16x16x32_bf16(af[m], bf[n], acc[m][n], 0,0,0);
  }
  {
    float mx = 0.f;
    #pragma unroll
    for (int m=0;m<4;m++)
      #pragma unroll
      for (int n=0;n<4;n++)
        #pragma unroll
        for (int r=0;r<4;r++) mx = fmaxf(mx, acc[m][n][r]);
    for (int o=1;o<64;o<<=1) mx = fmaxf(mx, __shfl_xor(mx,o));
    if (lane==0) red[wave] = mx;
    __syncthreads();
    mx = fmaxf(fmaxf(red[0],red[1]), fmaxf(red[2],red[3]));
    float sc = 1.0f/mx;
    if (tid==0) scales[(size_t)b*127 + soff_i + 2*q] = logf(mx);
    #pragma unroll
    for (int m=0;m<4;m++){
      int rg = wm*64 + m*16 + lg*4;
      #pragma unroll
      for (int n=0;n<4;n++){
        int cg = wn*64 + n*16 + lr;
        float v0=acc[m][n][0]*sc, v1=acc[m][n][1]*sc, v2=acc[m][n][2]*sc, v3=acc[m][n][3]*sc;
        u32 p0, p1;
        asm("v_cvt_pk_bf16_f32 %0, %1, %2" : "=v"(p0) : "v"(v0), "v"(v1));
        asm("v_cvt_pk_bf16_f32 %0, %1, %2" : "=v"(p1) : "v"(v2), "v"(v3));
        *(uint2*)&ldsB[TIX(cg, rg>>3) + (rg&7)] = make_uint2(p0, p1);
      }
    }
  }
  __syncthreads();
  // Q = T2^T . T3^T (= P2^T)
  #pragma unroll
  for (int m=0;m<4;m++)
    #pragma unroll
    for (int n=0;n<4;n++) acc[m][n] = (f32x4){0.f,0.f,0.f,0.f};
  #pragma unroll
  for (int kc=0; kc<4; ++kc){
    bf16x8 af[4], bf[4];
    #pragma unroll
    for (int m=0;m<4;m++) af[m] = *(const bf16x8*)(T2 + (size_t)(wm*64+m*16+lr)*128 + kc*32 + lg*8);
    #pragma unroll
    for (int n=0;n<4;n++) bf[n] = *(const bf16x8*)(T3 + (size_t)(wn*64+n*16+lr)*128 + kc*32 + lg*8);
    #pragma unroll
    for (int m=0;m<4;m++)
      #pragma unroll
      for (int n=0;n<4;n++)
        acc[m][n] = __builtin_amdgcn_mfma_f32_16x16x32_bf16(af[m], bf[n], acc[m][n], 0,0,0);
  }
  {
    float mx = 0.f;
    #pragma unroll
    for (int m=0;m<4;m++)
      #pragma unroll
      for (int n=0;n<4;n++)
        #pragma unroll
        for (int r=0;r<4;r++) mx = fmaxf(mx, acc[m][n][r]);
    for (int o=1;o<64;o<<=1) mx = fmaxf(mx, __shfl_xor(mx,o));
    __syncthreads();
    if (lane==0) red[wave] = mx;
    __syncthreads();
    mx = fmaxf(fmaxf(red[0],red[1]), fmaxf(red[2],red[3]));
    float sc = 1.0f/mx;
    if (tid==0) scales[(size_t)b*127 + soff_i + 2*q + 1] = logf(mx);
    #pragma unroll
    for (int m=0;m<4;m++){
      int rg = wm*64 + m*16 + lg*4;
      #pragma unroll
      for (int n=0;n<4;n++){
        int cg = wn*64 + n*16 + lr;
        float v0=acc[m][n][0]*sc, v1=acc[m][n][1]*sc, v2=acc[m][n][2]*sc, v3=acc[m][n][3]*sc;
        u32 p0, p1;
        asm("v_cvt_pk_bf16_f32 %0, %1, %2" : "=v"(p0) : "v"(v0), "v"(v1));
        asm("v_cvt_pk_bf16_f32 %0, %1, %2" : "=v"(p1) : "v"(v2), "v"(v3));
        *(uint2*)&ldsA[TIX(cg, rg>>3) + (rg&7)] = make_uint2(p0, p1);
      }
    }
  }
  __syncthreads();
  // C = P2 . P1
  #pragma unroll
  for (int m=0;m<4;m++)
    #pragma unroll
    for (int n=0;n<4;n++) acc[m][n] = (f32x4){0.f,0.f,0.f,0.f};
  #pragma unroll
  for (int kc=0; kc<4; ++kc){
    bf16x8 af[4], bf[4];
    #pragma unroll
    for (int m=0;m<4;m++) af[m] = *(const bf16x8*)&ldsA[TIX(wm*64+m*16+lr, kc*4+lg)];
    #pragma unroll
    for (int n=0;n<4;n++) bf[n] = *(const bf16x8*)&ldsB[TIX(wn*64+n*16+lr, kc*4+lg)];
    #pragma unroll
    for (int m=0;m<4;m++)
      #pragma unroll
      for (int n=0;n<4;n++)
        acc[m][n] = __builtin_amdgcn_mfma_f32_16x16x32_bf16(af[m], bf[n], acc[m][n], 0,0,0);
  }
  float mx = 0.f;
  #pragma unroll
  for (int m=0;m<4;m++)
    #pragma unroll
    for (int n=0;n<4;n++)
      #pragma unroll
      for (int r=0;r<4;r++) mx = fmaxf(mx, acc[m][n][r]);
  for (int o=1;o<64;o<<=1) mx = fmaxf(mx, __shfl_xor(mx,o));
  __syncthreads();
  if (lane==0) red[wave] = mx;
  __syncthreads();
  mx = fmaxf(fmaxf(red[0],red[1]), fmaxf(red[2],red[3]));
  const float sc = 1.0f / mx;
  if (tid==0) scales[(size_t)b*127 + soff_o + q] = logf(mx);
  u16* Cg = out + ((size_t)b*nout + q)*(S*S);
  if (q & 1){
    #pragma unroll
    for (int m=0;m<4;m++){
      int rg = wm*64 + m*16 + lg*4;
      #pragma unroll
      for (int n=0;n<4;n++){
        int cg = wn*64 + n*16 + lr;
        #pragma unroll
        for (int r=0;r<4;r++) Cg[(size_t)(rg+r)*128 + cg] = f2bf(acc[m][n][r]*sc);
      }
    }
  } else {
    #pragma unroll
    for (int m=0;m<4;m++){
      int rg = wm*64 + m*16 + lg*4;
      #pragma unroll
      for (int n=0;n<4;n++){
        int cg = wn*64 + n*16 + lr;
        float v0=acc[m][n][0]*sc, v1=acc[m][n][1]*sc, v2=acc[m][n][2]*sc, v3=acc[m][n][3]*sc;
        u32 p0, p1;
        asm("v_cvt_pk_bf16_f32 %0, %1, %2" : "=v"(p0) : "v"(v0), "v"(v1));
        asm("v_cvt_pk_bf16_f32 %0, %1, %2" : "=v"(p1) : "v"(v2), "v"(v3));
        *(uint2*)(Cg + (size_t)cg*128 + rg) = make_uint2(p0, p1);
      }
    }
  }
}

// ---------------- final quad (4 -> 1) fused with evidence readout ----------------
__global__ __launch_bounds__(256) void k_fin4(
    const u16* __restrict__ in, const float* __restrict__ scales, float* __restrict__ res){
  const int b = blockIdx.x;
  const u16* T0 = in + ((size_t)b*4 + 0)*(S*S);
  const u16* T1 = in + ((size_t)b*4 + 1)*(S*S);
  const u16* T2 = in + ((size_t)b*4 + 2)*(S*S);
  const u16* T3 = in + ((size_t)b*4 + 3)*(S*S);
  __shared__ __align__(16) u16 ldsA[128*128];
  __shared__ __align__(16) u16 ldsB[128*128];
  __shared__ float red[8];
  __shared__ float sloc[2];
  const int tid = threadIdx.x;
  const int lane = tid & 63, wave = tid >> 6;
  const int wm = wave >> 1, wn = wave & 1;
  const int lr = lane & 15, lg = lane >> 4;
  f32x4 acc[4][4];
  #pragma unroll
  for (int m=0;m<4;m++)
    #pragma unroll
    for (int n=0;n<4;n++) acc[m][n] = (f32x4){0.f,0.f,0.f,0.f};
  #pragma unroll
  for (int kc=0; kc<4; ++kc){
    bf16x8 af[4], bf[4];
    #pragma unroll
    for (int m=0;m<4;m++) af[m] = *(const bf16x8*)(T1 + (size_t)(wm*64+m*16+lr)*128 + kc*32 + lg*8);
    #pragma unroll
    for (int n=0;n<4;n++) bf[n] = *(const bf16x8*)(T0 + (size_t)(wn*64+n*16+lr)*128 + kc*32 + lg*8);
    #pragma unroll
    for (int m=0;m<4;m++)
      #pragma unroll
      for (int n=0;n<4;n++)
        acc[m][n] = __builtin_amdgcn_mfma_f32_16x16x32_bf16(af[m], bf[n], acc[m][n], 0,0,0);
  }
  {
    float mx = 0.f;
    #pragma unroll
    for (int m=0;m<4;m++)
      #pragma unroll
      for (int n=0;n<4;n++)
        #pragma unroll
        for (int r=0;r<4;r++) mx = fmaxf(mx, acc[m][n][r]);
    for (int o=1;o<64;o<<=1) mx = fmaxf(mx, __shfl_xor(mx,o));
    if (lane==0) red[wave] = mx;
    __syncthreads();
    mx = fmaxf(fmaxf(red[0],red[1]), fmaxf(red[2],red[3]));
    float sc = 1.0f/mx;
    if (tid==0) sloc[0] = logf(mx);
    #pragma unroll
    for (int m=0;m<4;m++){
      int rg = wm*64 + m*16 + lg*4;
      #pragma unroll
      for (int n=0;n<4;n++){
        int cg = wn*64 + n*16 + lr;
        float v0=acc[m][n][0]*sc, v1=acc[m][n][1]*sc, v2=acc[m][n][2]*sc, v3=acc[m][n][3]*sc;
        u32 p0, p1;
        asm("v_cvt_pk_bf16_f32 %0, %1, %2" : "=v"(p0) : "v"(v0), "v"(v1));
        asm("v_cvt_pk_bf16_f32 %0, %1, %2" : "=v"(p1) : "v"(v2), "v"(v3));
        *(uint2*)&ldsB[TIX(cg, rg>>3) + (rg&7)] = make_uint2(p0, p1);
      }
    }
  }
  __syncthreads();
  #pragma unroll
  for (int m=0;m<4;m++)
    #pragma unroll
    for (int n=0;n<4;n++) acc[m][n] = (f32x4){0.f,0.f,0.f,0.f};
  #pragma unroll
  for (int kc=0; kc<4; ++kc){
    bf16x8 af[4], bf[4];
    #pragma unroll
    for (int m=0;m<4;m++) af[m] = *(const bf16x8*)(T2 + (size_t)(wm*64+m*16+lr)*128 + kc*32 + lg*8);
    #pragma unroll
    for (int n=0;n<4;n++) bf[n] = *(const bf16x8*)(T3 + (size_t)(wn*64+n*16+lr)*128 + kc*32 + lg*8);
    #pragma unroll
    for (int m=0;m<4;m++)
      #pragma unroll
      for (int n=0;n<4;n++)
        acc[m][n] = __builtin_amdgcn_mfma_f32_16x16x32_bf16(af[m], bf[n], acc[m][n], 0,0,0);
  }
  {
    float mx = 0.f;
    #pragma unroll
    for (int m=0;m<4;m++)
      #pragma unroll
      for (int n=0;n<4;n++)
        #pragma unroll
        for (int r=0;r<4;r++) mx = fmaxf(mx, acc[m][n][r]);
    for (int o=1;o<64;o<<=1) mx = fmaxf(mx, __shfl_xor(mx,o));
    __syncthreads();
    if (lane==0) red[wave] = mx;
    __syncthreads();
    mx = fmaxf(fmaxf(red[0],red[1]), fmaxf(red[2],red[3]));
    float sc = 1.0f/mx;
    if (tid==0) sloc[1] = logf(mx);
    #pragma unroll
    for (int m=0;m<4;m++){
      int rg = wm*64 + m*16 + lg*4;
      #pragma unroll
      for (int n=0;n<4;n++){
        int cg = wn*64 + n*16 + lr;
        float v0=acc[m][n][0]*sc, v1=acc[m][n][1]*sc, v2=acc[m][n][2]*sc, v3=acc[m][n][3]*sc;
        u32 p0, p1;
        asm("v_cvt_pk_bf16_f32 %0, %1, %2" : "=v"(p0) : "v"(v0), "v"(v1));
        asm("v_cvt_pk_bf16_f32 %0, %1, %2" : "=v"(p1) : "v"(v2), "v"(v3));
        *(uint2*)&ldsA[TIX(cg, rg>>3) + (rg&7)] = make_uint2(p0, p1);
      }
    }
  }
  __syncthreads();
  #pragma unroll
  for (int m=0;m<4;m++)
    #pragma unroll
    for (int n=0;n<4;n++) acc[m][n] = (f32x4){0.f,0.f,0.f,0.f};
  #pragma unroll
  for (int kc=0; kc<4; ++kc){
    bf16x8 af[4], bf[4];
    #pragma unroll
    for (int m=0;m<4;m++) af[m] = *(const bf16x8*)&ldsA[TIX(wm*64+m*16+lr, kc*4+lg)];
    #pragma unroll
    for (int n=0;n<4;n++) bf[n] = *(const bf16x8*)&ldsB[TIX(wn*64+n*16+lr, kc*4+lg)];
    #pragma unroll
    for (int m=0;m<4;m++)
      #pragma unroll
      for (int n=0;n<4;n++)
        acc[m][n] = __builtin_amdgcn_mfma_f32_16x16x32_bf16(af[m], bf[n], acc[m][n], 0,0,0);
  }
  float s = 0.f;
  #pragma unroll
  for (int m=0;m<4;m++)
    #pragma unroll
    for (int n=0;n<4;n++)
      #pragma unroll
      for (int r=0;r<4;r++) s += acc[m][n][r];
  for (int o=1;o<64;o<<=1) s += __shfl_xor(s,o);
  float sl = (tid < 124) ? scales[(size_t)b*127 + tid] : 0.f;
  for (int o=1;o<64;o<<=1) sl += __shfl_xor(sl,o);
  __syncthreads();
  if (lane==0){ red[wave] = s; red[4+wave] = sl; }
  __syncthreads();
  if (tid==0){
    float tot  = red[0]+red[1]+red[2]+red[3];
    float ssum = red[4]+red[5]+red[6]+red[7];
    res[b] = logf(tot) + ssum + sloc[0] + sloc[1];
  }
}

__global__ void k_final(const float* __restrict__ res, float* __restrict__ out){
  if (threadIdx.x==0){
    float s = 0.f;
    for (int i=0;i<B;i++) s += res[i];
    out[0] = s;
  }
}

extern "C" void kernel_launch(void* const* d_in, const int* in_sizes, int n_in,
                              void* d_out, int out_size, void* d_ws, size_t ws_size,
                              hipStream_t stream){
  const int*   text      = (const int*)d_in[0];
  const int*   w2s       = (const int*)d_in[1];
  const float* start_emb = (const float*)d_in[2];
  const float* start_w1  = (const float*)d_in[3];
  const float* start_b1  = (const float*)d_in[4];
  const float* start_w2  = (const float*)d_in[5];
  const float* start_b2  = (const float*)d_in[6];
  const float* start_wo  = (const float*)d_in[7];
  const float* start_bo  = (const float*)d_in[8];
  const float* state_emb = (const float*)d_in[9];
  const float* trans_w1  = (const float*)d_in[10];
  const float* trans_b1  = (const float*)d_in[11];
  const float* trans_w2  = (const float*)d_in[12];
  const float* trans_b2  = (const float*)d_in[13];
  const float* trans_wo  = (const float*)d_in[14];
  const float* trans_bo  = (const float*)d_in[15];
  const float* pre_emb   = (const float*)d_in[16];
  const float* term_w1   = (const float*)d_in[17];
  const float* term_b1   = (const float*)d_in[18];
  const float* term_w2   = (const float*)d_in[19];
  const float* term_b2   = (const float*)d_in[20];
  const float* term_wo   = (const float*)d_in[21];
  const float* term_bo   = (const float*)d_in[22];

  char* ws = (char*)d_ws;
  size_t off = 0;
  auto alloc = [&](size_t bytes)->char*{ char* p = ws + off; off += (bytes + 255) & ~(size_t)255; return p; };
  u16*   embb     = (u16*)  alloc(sizeof(u16)*3*(size_t)C*H);
  u16*   h1b      = (u16*)  alloc(sizeof(u16)*3*(size_t)C*H);
  u16*   h2b      = (u16*)  alloc(sizeof(u16)*3*(size_t)C*H);
  u16*   wt       = (u16*)  alloc(sizeof(u16)*6*(size_t)H*H);
  float* start_lp = (float*)alloc(sizeof(float)*C);
  float* shift    = (float*)alloc(sizeof(float)*C);
  float* shiftp   = (float*)alloc(sizeof(float)*(size_t)C*NRP);
  float* sumexp   = (float*)alloc(sizeof(float)*(size_t)C*NSB);
  float* lse      = (float*)alloc(sizeof(float)*C);
  float* resb     = (float*)alloc(sizeof(float)*B);
  float* scales   = (float*)alloc(sizeof(float)*(size_t)B*127);
  u16*   P        = (u16*)  alloc(sizeof(u16)*(size_t)C*C);
  u16*   wotb     = (u16*)  alloc(sizeof(u16)*(size_t)VP*H);
  u16*   wottr    = (u16*)  alloc(sizeof(u16)*(size_t)C*H);
  u16*   EM       = (u16*)  alloc(sizeof(u16)*(size_t)VP*C);        // bf16 EM [VP][C]
  u16*   treeA    = (u16*)  alloc(sizeof(u16)*(size_t)B*64*S*S);    // 32MB
  u16*   treeB    = (u16*)  alloc(sizeof(u16)*(size_t)B*16*S*S);    // 8MB
  float* TL       = (float*)treeA; // f32 TL [C][C] = 4MB, dead before k_pair0 writes treeA
  (void)ws_size; (void)in_sizes; (void)n_in; (void)out_size;

  u16* embb0 = embb, *embb1 = embb + (size_t)C*H, *embb2 = embb + 2*(size_t)C*H;
  u16* h1b0 = h1b, *h1b1 = h1b + (size_t)C*H, *h1b2 = h1b + 2*(size_t)C*H;
  u16* h2b0 = h2b, *h2b1 = h2b + (size_t)C*H, *h2b2 = h2b + 2*(size_t)C*H;

  Prep pr;
  pr.cs[0]=start_emb; pr.cs[1]=state_emb; pr.cs[2]=pre_emb;
  pr.cd[0]=embb0; pr.cd[1]=embb1; pr.cd[2]=embb2;
  pr.ts[0]=start_w1; pr.ts[1]=start_w2; pr.ts[2]=trans_w1; pr.ts[3]=trans_w2; pr.ts[4]=term_w1; pr.ts[5]=term_w2;
  for (int i=0;i<6;i++) pr.td[i] = wt + (size_t)i*H*H;
  pr.wvs = term_wo; pr.wvd = wotb;
  pr.wcs = trans_wo; pr.wcd = wottr;
  k_prep<<<dim3(3552), dim3(256), 0, stream>>>(pr);

  M3 l1;
  l1.A[0]=embb0; l1.A[1]=embb1; l1.A[2]=embb2;
  l1.W[0]=wt;    l1.W[1]=wt+2*(size_t)H*H; l1.W[2]=wt+4*(size_t)H*H;
  l1.bias[0]=start_b1; l1.bias[1]=trans_b1; l1.bias[2]=term_b1;
  l1.R[0]=l1.R[1]=l1.R[2]=nullptr;
  l1.O[0]=h1b0; l1.O[1]=h1b1; l1.O[2]=h1b2;
  k_mlpg<0><<<dim3(H/128, C/128, 3), dim3(256), 0, stream>>>(l1);

  M3 l2;
  l2.A[0]=h1b0; l2.A[1]=h1b1; l2.A[2]=h1b2;
  l2.W[0]=wt+(size_t)H*H; l2.W[1]=wt+3*(size_t)H*H; l2.W[2]=wt+5*(size_t)H*H;
  l2.bias[0]=start_b2; l2.bias[1]=trans_b2; l2.bias[2]=term_b2;
  l2.R[0]=embb0; l2.R[1]=embb1; l2.R[2]=embb2;
  l2.O[0]=h2b0; l2.O[1]=h2b1; l2.O[2]=h2b2;
  k_mlpg<1><<<dim3(H/128, C/128, 3), dim3(256), 0, stream>>>(l2);

  k_start<<<dim3(1), dim3(1024), 0, stream>>>(h2b0, start_wo, start_bo, start_lp);
  // transition logits (f32) + row softmax -> P
  k_gemm<0,0,0><<<dim3(C/128, C/128), dim3(256), 0, stream>>>(h2b1, wottr, trans_bo, C, TL, C, nullptr);
  k_softmax<<<dim3(C), dim3(256), 0, stream>>>(TL, P);
  // emission logits EM[v][c] bf16, row bias bo[v], fused column-max partials
  k_gemm<1,1,1><<<dim3(C/128, VP/128), dim3(256), 0, stream>>>(wotb, h2b2, term_bo, V, EM, C, shiftp);
  k_shiftc<<<dim3((C+255)/256), dim3(256), 0, stream>>>(shiftp, shift);
  // masked LSE: LDS-bitmap dedupe + LDS fp32 accumulation, one partial row per block
  k_sumexp<<<dim3(NSB), dim3(256), 0, stream>>>(w2s, EM, shift, sumexp);
  k_lse<<<dim3((C+255)/256), dim3(256), 0, stream>>>(shift, sumexp, lse);

  // fused gather + level-1 product: 128 virtual tiles -> 64 tiles (treeA)
  k_pair0<<<dim3(64, B), dim3(256), 0, stream>>>(text, w2s, start_lp, lse, EM, P, treeA, scales);
  // quad levels: 64 -> 16 (treeB), 16 -> 4 (treeA), 4 -> 1 fused with readout
  k_quad<<<dim3(16, B), dim3(256), 0, stream>>>(treeA, treeB, scales, 64, 64, 96);
  k_quad<<<dim3(4,  B), dim3(256), 0, stream>>>(treeB, treeA, scales, 16, 112, 120);
  k_fin4<<<dim3(B), dim3(256), 0, stream>>>(treeA, scales, resb);
  k_final<<<dim3(1), dim3(64), 0, stream>>>(resb, (float*)d_out);
}